// Round 2
// baseline (572.466 us; speedup 1.0000x reference)
//
#include <hip/hip_runtime.h>

#define NUSERS 100000
#define NITEMS 50000
#define NTOT   150000
#define NEDGE  1000000
#define NTILE  9375   // NTOT / 16

typedef unsigned int uint32;
typedef __attribute__((ext_vector_type(8))) short short8;
typedef __attribute__((ext_vector_type(4))) float f32x4;

__device__ __forceinline__ unsigned short f2bf(float f) {
  unsigned int u = __float_as_uint(f);
  u += 0x7FFFu + ((u >> 16) & 1u);   // round-to-nearest-even
  return (unsigned short)(u >> 16);
}
__device__ __forceinline__ uint32 pack2bf(float a, float b) {
  return (uint32)f2bf(a) | ((uint32)f2bf(b) << 16);
}
__device__ __forceinline__ float bf_lo(uint32 u) { return __uint_as_float(u << 16); }
__device__ __forceinline__ float bf_hi(uint32 u) { return __uint_as_float(u & 0xFFFF0000u); }

// ---- init: embb0 = bf16-pair packed copy of concat(user,item). ----
__global__ void k_init(const float* __restrict__ ue, const float* __restrict__ ie,
                       uint32* __restrict__ embb) {
  int i = blockIdx.x * 256 + threadIdx.x;  // float4 index
  if (i >= NTOT * 16) return;
  float4 v = (i < NUSERS * 16) ? ((const float4*)ue)[i]
                               : ((const float4*)ie)[i - NUSERS * 16];
  uint2 pk;
  pk.x = pack2bf(v.x, v.y);
  pk.y = pack2bf(v.z, v.w);
  ((uint2*)embb)[i] = pk;
}

// ---- W pack: Wbg[l*6144 + mat*2048 + n*32 + k2] = bf16(W[2k2][n], W[2k2+1][n]) ----
__global__ void k_wpack(const float* __restrict__ Wq, const float* __restrict__ Wk,
                        const float* __restrict__ Wv, uint32* __restrict__ Wbg) {
  int t = blockIdx.x * 256 + threadIdx.x;
  if (t >= 12288) return;
  int l = t / 6144, rem = t % 6144, mat = rem / 2048, j = rem % 2048;
  int n = j >> 5, k2 = j & 31;
  const float* W = (mat == 0 ? Wq : mat == 1 ? Wk : Wv) + l * 4096;
  Wbg[t] = pack2bf(W[k2 * 128 + n], W[k2 * 128 + 64 + n]);
}

// ---- CSR build: histogram -> scan -> fill ----
__global__ void k_hist(const int* __restrict__ rows, int* __restrict__ cnt) {
  int e = blockIdx.x * 256 + threadIdx.x;
  if (e < NEDGE) atomicAdd(&cnt[rows[e]], 1);
}

__global__ void k_scan1(const int* __restrict__ cnt, int* __restrict__ partial,
                        int* __restrict__ blocksums) {
  __shared__ int s[256];
  int t = threadIdx.x, b = blockIdx.x;
  int base = b * 2048 + t * 8;
  int pre[8]; int sum = 0;
  #pragma unroll
  for (int j = 0; j < 8; ++j) {
    int idx = base + j;
    int x = (idx < NTOT) ? cnt[idx] : 0;
    pre[j] = sum; sum += x;
  }
  s[t] = sum; __syncthreads();
  for (int off = 1; off < 256; off <<= 1) {
    int x = (t >= off) ? s[t - off] : 0;
    __syncthreads(); s[t] += x; __syncthreads();
  }
  int excl = s[t] - sum;
  #pragma unroll
  for (int j = 0; j < 8; ++j) {
    int idx = base + j;
    if (idx < NTOT) partial[idx] = excl + pre[j];
  }
  if (t == 255) blocksums[b] = s[255];
}

__global__ void k_scan2(const int* __restrict__ blocksums, int* __restrict__ blockoffs, int nblk) {
  __shared__ int s[128];
  int t = threadIdx.x;
  int x = (t < nblk) ? blocksums[t] : 0;
  s[t] = x; __syncthreads();
  for (int off = 1; off < 128; off <<= 1) {
    int y = (t >= off) ? s[t - off] : 0;
    __syncthreads(); s[t] += y; __syncthreads();
  }
  if (t < nblk) blockoffs[t] = s[t] - x;
}

__global__ void k_scan3(int* __restrict__ row_ptr, const int* __restrict__ blockoffs,
                        int* __restrict__ cursor) {
  int i = blockIdx.x * 256 + threadIdx.x;
  if (i < NTOT) {
    int v = row_ptr[i] + blockoffs[i >> 11];
    row_ptr[i] = v; cursor[i] = v;
  }
  if (i == 0) row_ptr[NTOT] = NEDGE;
}

__global__ void k_fill(const int* __restrict__ rows, const int* __restrict__ cols,
                       const float* __restrict__ vals, int* __restrict__ cursor,
                       int* __restrict__ ecols, float* __restrict__ evals) {
  int e = blockIdx.x * 256 + threadIdx.x;
  if (e >= NEDGE) return;
  int r = rows[e];
  int pos = atomicAdd(&cursor[r], 1);
  ecols[pos] = cols[e];
  evals[pos] = vals[e];
}

// ---- QKV v5: MFMA. wave = 16-node tile. No LDS in main loop. ----
__global__ void __launch_bounds__(256) k_qkv(const uint32* __restrict__ embb,
    const uint32* __restrict__ Wbg, float* __restrict__ Q, uint32* __restrict__ KVb) {
  __shared__ float scr[4][2][16][68];  // [wave][K/V][node][dim(+pad)] = 34816 B
  int t = threadIdx.x;
  int wave = t >> 6, lane = t & 63;
  int tile = blockIdx.x * 4 + wave;
  if (tile >= NTILE) return;
  int c = lane & 15, quad = lane >> 4;
  int nodeBase = tile * 16;
  const uint32* arow = embb + (nodeBase + c) * 32 + quad * 4;
  uint4 a0u = *(const uint4*)arow;          // dims quad*8 .. +7
  uint4 a1u = *(const uint4*)(arow + 16);   // dims 32+quad*8 .. +7
  short8 a0 = *(short8*)&a0u;
  short8 a1 = *(short8*)&a1u;
  float (*SK)[68] = scr[wave][0];
  float (*SV)[68] = scr[wave][1];
  const uint32* wbase = Wbg + c * 32 + quad * 4;
  #pragma unroll
  for (int mat = 0; mat < 3; ++mat) {
    f32x4 acc[4];
    #pragma unroll
    for (int nt = 0; nt < 4; ++nt) acc[nt] = (f32x4){0.f, 0.f, 0.f, 0.f};
    const uint32* wb = wbase + mat * 2048;
    #pragma unroll
    for (int nt = 0; nt < 4; ++nt) {
      uint4 b0u = *(const uint4*)(wb + nt * 512);        // kh=0
      uint4 b1u = *(const uint4*)(wb + nt * 512 + 16);   // kh=1
      short8 b0 = *(short8*)&b0u;
      short8 b1 = *(short8*)&b1u;
      acc[nt] = __builtin_amdgcn_mfma_f32_16x16x32_bf16(a0, b0, acc[nt], 0, 0, 0);
      acc[nt] = __builtin_amdgcn_mfma_f32_16x16x32_bf16(a1, b1, acc[nt], 0, 0, 0);
    }
    float (*S)[68] = (mat == 2) ? SV : SK;   // Q and K reuse SK
    #pragma unroll
    for (int nt = 0; nt < 4; ++nt)
      #pragma unroll
      for (int r = 0; r < 4; ++r)
        S[quad * 4 + r][nt * 16 + c] = acc[nt][r];
    if (mat == 0) {
      #pragma unroll
      for (int i = 0; i < 4; ++i) {
        int node = i * 4 + quad;
        f32x4 q4 = *(f32x4*)&SK[node][c * 4];
        *(f32x4*)&Q[(nodeBase + node) * 64 + c * 4] = q4;
      }
    } else if (mat == 2) {
      #pragma unroll
      for (int i = 0; i < 4; ++i) {
        int node = i * 4 + quad;
        f32x4 K4 = *(f32x4*)&SK[node][c * 4];
        f32x4 V4 = *(f32x4*)&SV[node][c * 4];
        uint4 o;
        o.x = pack2bf(K4[0], K4[1]);
        o.y = pack2bf(K4[2], K4[3]);
        o.z = pack2bf(V4[0], V4[1]);
        o.w = pack2bf(V4[2], V4[3]);
        *(uint4*)&KVb[(nodeBase + node) * 64 + c * 4] = o;
      }
    }
  }
}

// ---- GT layer: wave = node; 4 edge-slots x 16 lanes; coalesced 64-edge
// preload + __shfl removes the ecols global round-trip from the chain. ----
__global__ void __launch_bounds__(256) k_gt(const float* __restrict__ Q,
    const uint32* __restrict__ KVb, const int* __restrict__ row_ptr,
    const int* __restrict__ ecols, float* __restrict__ emb_out,
    uint32* __restrict__ embb_out) {
  int t = threadIdx.x;
  int n = blockIdx.x * 4 + (t >> 6);
  if (n >= NTOT) return;
  int lane = t & 63;
  int es = lane >> 4;
  int dl = lane & 15;
  float4 q4 = *(const float4*)&Q[n * 64 + dl * 4];
  int s     = __builtin_amdgcn_readfirstlane(row_ptr[n]);
  int e_end = __builtin_amdgcn_readfirstlane(row_ptr[n + 1]);
  int cnt = e_end - s;
  int li = s + lane;
  int cv = ecols[li < NEDGE ? li : NEDGE - 1];
  float den = 0.f;
  float4 acc = make_float4(0.f, 0.f, 0.f, 0.f);
  #pragma unroll 2
  for (int base = 0; base < cnt; base += 4) {
    int i = base + es;
    int cc;
    if (base < 64) cc = __shfl(cv, i & 63);
    else           cc = (i < cnt) ? ecols[s + i] : 0;
    float ex = 0.f;
    float4 v4 = make_float4(0.f, 0.f, 0.f, 0.f);
    if (i < cnt) {
      uint4 w = *(const uint4*)&KVb[cc * 64 + dl * 4];
      float kx = bf_lo(w.x), ky = bf_hi(w.x);
      float kz = bf_lo(w.y), kw = bf_hi(w.y);
      v4.x = bf_lo(w.z); v4.y = bf_hi(w.z);
      v4.z = bf_lo(w.w); v4.w = bf_hi(w.w);
      float x = q4.x * kx + q4.y * ky + q4.z * kz + q4.w * kw;
      x += __shfl_xor(x, 1);
      x += __shfl_xor(x, 2);
      x = fminf(fmaxf(x, -10.f), 10.f);
      ex = __expf(x);
    }
    den += ex;
    acc.x = fmaf(ex, v4.x, acc.x);
    acc.y = fmaf(ex, v4.y, acc.y);
    acc.z = fmaf(ex, v4.z, acc.z);
    acc.w = fmaf(ex, v4.w, acc.w);
  }
  #pragma unroll
  for (int off = 16; off <= 32; off <<= 1) {
    den  += __shfl_xor(den, off);
    acc.x += __shfl_xor(acc.x, off);
    acc.y += __shfl_xor(acc.y, off);
    acc.z += __shfl_xor(acc.z, off);
    acc.w += __shfl_xor(acc.w, off);
  }
  float inv = 1.f / (den + 1e-8f);
  float4 r = make_float4(acc.x * inv, acc.y * inv, acc.z * inv, acc.w * inv);
  if (es == 0) {
    *(float4*)&emb_out[n * 64 + dl * 4] = r;
  } else if (es == 1) {
    uint2 pk;
    pk.x = pack2bf(r.x, r.y);
    pk.y = pack2bf(r.z, r.w);
    *(uint2*)&embb_out[n * 32 + dl * 2] = pk;
  }
}

// ---- GCN layer (spmm), bf16 gather edition. ----
// Half-wave per edge: eh = lane>>5 picks even/odd edge slot, dl = lane&31 is
// the dim-pair (dims 2dl, 2dl+1). One uint (bf16-pair) load per lane = 128 B
// coalesced per edge, 16 edges in flight per 8-wide unroll (same cache lines
// in flight as the old fp32 8-wide scheme, half the bytes). Dead slots clamp
// to edge 0 (L1 hit, weight zeroed). Edge metadata: one coalesced 64-edge
// preload + __shfl.
// FINAL=0: writes fp32 out + bf16 copy (for next layer's gather).
// FINAL=1: fuses the 5-term sum: out = cat(ue,ie)+GT1+GT2+GCN1+own.
template<int FINAL>
__global__ void __launch_bounds__(256) k_gcn(const uint32* __restrict__ src,
    const int* __restrict__ row_ptr, const int* __restrict__ ecols,
    const float* __restrict__ evals, float* __restrict__ emb_out,
    uint32* __restrict__ embb_out,
    const float* __restrict__ ue, const float* __restrict__ ie,
    const float* __restrict__ add1, const float* __restrict__ add2,
    const float* __restrict__ addG) {
  int t = threadIdx.x;
  int n = blockIdx.x * 4 + (t >> 6);
  if (n >= NTOT) return;
  int lane = t & 63;
  int eh = lane >> 5;
  int dl = lane & 31;
  int s     = __builtin_amdgcn_readfirstlane(row_ptr[n]);
  int e_end = __builtin_amdgcn_readfirstlane(row_ptr[n + 1]);
  int cnt = e_end - s;
  int li = s + lane;
  int pli = li < NEDGE ? li : NEDGE - 1;
  int   cv = ecols[pli];
  float wv = evals[pli];
  float ax[8], ay[8];
  #pragma unroll
  for (int j = 0; j < 8; ++j) { ax[j] = 0.f; ay[j] = 0.f; }
  for (int p = 0; p < cnt; p += 16) {
    #pragma unroll
    for (int j = 0; j < 8; ++j) {
      int i = p + 2 * j + eh;
      bool ok = i < cnt;
      int ii = ok ? i : 0;            // clamp: dead slots re-hit edge 0 (L1)
      int cc; float w;
      if (ii < 64) { cc = __shfl(cv, ii); w = __shfl(wv, ii); }
      else         { cc = ecols[s + ii];  w = evals[s + ii]; }
      if (!ok) w = 0.f;
      uint32 g = src[cc * 32 + dl];
      ax[j] = fmaf(w, bf_lo(g), ax[j]);
      ay[j] = fmaf(w, bf_hi(g), ay[j]);
    }
  }
  float sx = ((ax[0] + ax[1]) + (ax[2] + ax[3])) + ((ax[4] + ax[5]) + (ax[6] + ax[7]));
  float sy = ((ay[0] + ay[1]) + (ay[2] + ay[3])) + ((ay[4] + ay[5]) + (ay[6] + ay[7]));
  sx += __shfl_xor(sx, 32);
  sy += __shfl_xor(sy, 32);
  if (FINAL) {
    const float* p1 = (eh == 0)
        ? ((n < NUSERS) ? ue + (size_t)n * 64 : ie + (size_t)(n - NUSERS) * 64)
        : add2 + (size_t)n * 64;
    const float* p2 = (eh == 0) ? add1 + (size_t)n * 64 : addG + (size_t)n * 64;
    float2 u = *(const float2*)&p1[dl * 2];
    float2 v = *(const float2*)&p2[dl * 2];
    float px = u.x + v.x, py = u.y + v.y;
    px += __shfl_xor(px, 32);
    py += __shfl_xor(py, 32);
    sx += px; sy += py;
    if (eh == 0) *(float2*)&emb_out[(size_t)n * 64 + dl * 2] = make_float2(sx, sy);
  } else {
    if (eh == 0) *(float2*)&emb_out[(size_t)n * 64 + dl * 2] = make_float2(sx, sy);
    else         embb_out[n * 32 + dl] = pack2bf(sx, sy);
  }
}

extern "C" void kernel_launch(void* const* d_in, const int* in_sizes, int n_in,
                              void* d_out, int out_size, void* d_ws, size_t ws_size,
                              hipStream_t stream) {
  const int*   rows = (const int*)d_in[0];
  const int*   cols = (const int*)d_in[1];
  const float* vals = (const float*)d_in[2];
  const float* ue   = (const float*)d_in[3];
  const float* ie   = (const float*)d_in[4];
  const float* Wq   = (const float*)d_in[5];
  const float* Wk   = (const float*)d_in[6];
  const float* Wv   = (const float*)d_in[7];
  float* out = (float*)d_out;

  char* p = (char*)d_ws;
  auto alloc = [&](size_t b) { char* r = p; p += (b + 255) & ~(size_t)255; return (void*)r; };
  int*   cnt     = (int*)alloc((size_t)NTOT * 4);
  int*   row_ptr = (int*)alloc((size_t)(NTOT + 1) * 4);
  int*   cursor  = (int*)alloc((size_t)NTOT * 4);
  int*   bsums   = (int*)alloc(128 * 4);
  int*   boffs   = (int*)alloc(128 * 4);
  int*   ecols   = (int*)alloc((size_t)NEDGE * 4);
  float* evals   = (float*)alloc((size_t)NEDGE * 4);
  uint32* Wbg  = (uint32*)alloc((size_t)12288 * 4);
  float*  Q    = (float*)alloc((size_t)NTOT * 64 * 4);   // QKV Q; reused as GCN1 fp32 out
  uint32* KVb  = (uint32*)alloc((size_t)NTOT * 64 * 4);  // 256 B/node
  float*  embA = (float*)alloc((size_t)NTOT * 64 * 4);   // GT1 fp32 out (final sum)
  float*  embB = (float*)alloc((size_t)NTOT * 64 * 4);   // GT2 fp32 out (final sum)
  uint32* embb0 = (uint32*)alloc((size_t)NTOT * 32 * 4); // bf16 pairs
  uint32* embb1 = (uint32*)alloc((size_t)NTOT * 32 * 4);

  hipMemsetAsync(cnt, 0, (size_t)NTOT * 4, stream);
  k_hist<<<(NEDGE + 255) / 256, 256, 0, stream>>>(rows, cnt);
  int nblk = (NTOT + 2047) / 2048;  // 74
  k_scan1<<<nblk, 256, 0, stream>>>(cnt, row_ptr, bsums);
  k_scan2<<<1, 128, 0, stream>>>(bsums, boffs, nblk);
  k_scan3<<<(NTOT + 255) / 256, 256, 0, stream>>>(row_ptr, boffs, cursor);
  k_fill<<<(NEDGE + 255) / 256, 256, 0, stream>>>(rows, cols, vals, cursor, ecols, evals);
  k_wpack<<<48, 256, 0, stream>>>(Wq, Wk, Wv, Wbg);
  k_init<<<(NTOT * 16 + 255) / 256, 256, 0, stream>>>(ue, ie, embb0);

  // GT layer 1: writes embA (fp32, final sum) + embb1 (bf16, feeds GT2 QKV)
  k_qkv<<<(NTILE + 3) / 4, 256, 0, stream>>>(embb0, Wbg, Q, KVb);
  k_gt<<<(NTOT + 3) / 4, 256, 0, stream>>>(Q, KVb, row_ptr, ecols, embA, embb1);
  // GT layer 2: writes embB (fp32, final sum) + embb0 (bf16, feeds GCN1 gather)
  k_qkv<<<(NTILE + 3) / 4, 256, 0, stream>>>(embb1, Wbg + 6144, Q, KVb);
  k_gt<<<(NTOT + 3) / 4, 256, 0, stream>>>(Q, KVb, row_ptr, ecols, embB, embb0);
  // GCN1: bf16 gather of GT2-out -> Q (fp32, for final-sum term) + embb1 (bf16, for GCN2 gather)
  k_gcn<0><<<(NTOT + 3) / 4, 256, 0, stream>>>(embb0, row_ptr, ecols, evals, Q, embb1,
                                               nullptr, nullptr, nullptr, nullptr, nullptr);
  // GCN2: bf16 gather of GCN1-out, fused 5-term final sum -> out
  k_gcn<1><<<(NTOT + 3) / 4, 256, 0, stream>>>(embb1, row_ptr, ecols, evals, out, nullptr,
                                               ue, ie, embA, embB, Q);
}

// Round 3
// 511.188 us; speedup vs baseline: 1.1199x; 1.1199x over previous
//
#include <hip/hip_runtime.h>

#define NUSERS 100000
#define NITEMS 50000
#define NTOT   150000
#define NEDGE  1000000
#define NTILE  9375   // NTOT / 16

typedef unsigned int uint32;
typedef unsigned short ushort16;
typedef __attribute__((ext_vector_type(8))) short short8;
typedef __attribute__((ext_vector_type(4))) float f32x4;

__device__ __forceinline__ unsigned short f2bf(float f) {
  unsigned int u = __float_as_uint(f);
  u += 0x7FFFu + ((u >> 16) & 1u);   // round-to-nearest-even
  return (unsigned short)(u >> 16);
}
__device__ __forceinline__ uint32 pack2bf(float a, float b) {
  return (uint32)f2bf(a) | ((uint32)f2bf(b) << 16);
}
__device__ __forceinline__ float bf_lo(uint32 u) { return __uint_as_float(u << 16); }
__device__ __forceinline__ float bf_hi(uint32 u) { return __uint_as_float(u & 0xFFFF0000u); }

// ---- init: embb0 = bf16-pair packed copy of concat(user,item). ----
// NOTE: the uint32-pair layout is bit-identical to ushort[node][64] row-major.
__global__ void k_init(const float* __restrict__ ue, const float* __restrict__ ie,
                       uint32* __restrict__ embb) {
  int i = blockIdx.x * 256 + threadIdx.x;  // float4 index
  if (i >= NTOT * 16) return;
  float4 v = (i < NUSERS * 16) ? ((const float4*)ue)[i]
                               : ((const float4*)ie)[i - NUSERS * 16];
  uint2 pk;
  pk.x = pack2bf(v.x, v.y);
  pk.y = pack2bf(v.z, v.w);
  ((uint2*)embb)[i] = pk;
}

// ---- W pack: Wbg[l*6144 + mat*2048 + n*32 + k2] = bf16(W[2k2][n], W[2k2+1][n]) ----
__global__ void k_wpack(const float* __restrict__ Wq, const float* __restrict__ Wk,
                        const float* __restrict__ Wv, uint32* __restrict__ Wbg) {
  int t = blockIdx.x * 256 + threadIdx.x;
  if (t >= 12288) return;
  int l = t / 6144, rem = t % 6144, mat = rem / 2048, j = rem % 2048;
  int n = j >> 5, k2 = j & 31;
  const float* W = (mat == 0 ? Wq : mat == 1 ? Wk : Wv) + l * 4096;
  Wbg[t] = pack2bf(W[k2 * 128 + n], W[k2 * 128 + 64 + n]);
}

// ---- CSR build: histogram -> scan -> fill ----
__global__ void k_hist(const int* __restrict__ rows, int* __restrict__ cnt) {
  int e = blockIdx.x * 256 + threadIdx.x;
  if (e < NEDGE) atomicAdd(&cnt[rows[e]], 1);
}

__global__ void k_scan1(const int* __restrict__ cnt, int* __restrict__ partial,
                        int* __restrict__ blocksums) {
  __shared__ int s[256];
  int t = threadIdx.x, b = blockIdx.x;
  int base = b * 2048 + t * 8;
  int pre[8]; int sum = 0;
  #pragma unroll
  for (int j = 0; j < 8; ++j) {
    int idx = base + j;
    int x = (idx < NTOT) ? cnt[idx] : 0;
    pre[j] = sum; sum += x;
  }
  s[t] = sum; __syncthreads();
  for (int off = 1; off < 256; off <<= 1) {
    int x = (t >= off) ? s[t - off] : 0;
    __syncthreads(); s[t] += x; __syncthreads();
  }
  int excl = s[t] - sum;
  #pragma unroll
  for (int j = 0; j < 8; ++j) {
    int idx = base + j;
    if (idx < NTOT) partial[idx] = excl + pre[j];
  }
  if (t == 255) blocksums[b] = s[255];
}

__global__ void k_scan2(const int* __restrict__ blocksums, int* __restrict__ blockoffs, int nblk) {
  __shared__ int s[128];
  int t = threadIdx.x;
  int x = (t < nblk) ? blocksums[t] : 0;
  s[t] = x; __syncthreads();
  for (int off = 1; off < 128; off <<= 1) {
    int y = (t >= off) ? s[t - off] : 0;
    __syncthreads(); s[t] += y; __syncthreads();
  }
  if (t < nblk) blockoffs[t] = s[t] - x;
}

__global__ void k_scan3(int* __restrict__ row_ptr, const int* __restrict__ blockoffs,
                        int* __restrict__ cursor) {
  int i = blockIdx.x * 256 + threadIdx.x;
  if (i < NTOT) {
    int v = row_ptr[i] + blockoffs[i >> 11];
    row_ptr[i] = v; cursor[i] = v;
  }
  if (i == 0) row_ptr[NTOT] = NEDGE;
}

__global__ void k_fill(const int* __restrict__ rows, const int* __restrict__ cols,
                       const float* __restrict__ vals, int* __restrict__ cursor,
                       int* __restrict__ ecols, float* __restrict__ evals) {
  int e = blockIdx.x * 256 + threadIdx.x;
  if (e >= NEDGE) return;
  int r = rows[e];
  int pos = atomicAdd(&cursor[r], 1);
  ecols[pos] = cols[e];
  evals[pos] = vals[e];
}

// ---- QKV v5: MFMA. wave = 16-node tile. No LDS in main loop. ----
__global__ void __launch_bounds__(256) k_qkv(const uint32* __restrict__ embb,
    const uint32* __restrict__ Wbg, float* __restrict__ Q, uint32* __restrict__ KVb) {
  __shared__ float scr[4][2][16][68];  // [wave][K/V][node][dim(+pad)] = 34816 B
  int t = threadIdx.x;
  int wave = t >> 6, lane = t & 63;
  int tile = blockIdx.x * 4 + wave;
  if (tile >= NTILE) return;
  int c = lane & 15, quad = lane >> 4;
  int nodeBase = tile * 16;
  const uint32* arow = embb + (nodeBase + c) * 32 + quad * 4;
  uint4 a0u = *(const uint4*)arow;          // dims quad*8 .. +7
  uint4 a1u = *(const uint4*)(arow + 16);   // dims 32+quad*8 .. +7
  short8 a0 = *(short8*)&a0u;
  short8 a1 = *(short8*)&a1u;
  float (*SK)[68] = scr[wave][0];
  float (*SV)[68] = scr[wave][1];
  const uint32* wbase = Wbg + c * 32 + quad * 4;
  #pragma unroll
  for (int mat = 0; mat < 3; ++mat) {
    f32x4 acc[4];
    #pragma unroll
    for (int nt = 0; nt < 4; ++nt) acc[nt] = (f32x4){0.f, 0.f, 0.f, 0.f};
    const uint32* wb = wbase + mat * 2048;
    #pragma unroll
    for (int nt = 0; nt < 4; ++nt) {
      uint4 b0u = *(const uint4*)(wb + nt * 512);        // kh=0
      uint4 b1u = *(const uint4*)(wb + nt * 512 + 16);   // kh=1
      short8 b0 = *(short8*)&b0u;
      short8 b1 = *(short8*)&b1u;
      acc[nt] = __builtin_amdgcn_mfma_f32_16x16x32_bf16(a0, b0, acc[nt], 0, 0, 0);
      acc[nt] = __builtin_amdgcn_mfma_f32_16x16x32_bf16(a1, b1, acc[nt], 0, 0, 0);
    }
    float (*S)[68] = (mat == 2) ? SV : SK;   // Q and K reuse SK
    #pragma unroll
    for (int nt = 0; nt < 4; ++nt)
      #pragma unroll
      for (int r = 0; r < 4; ++r)
        S[quad * 4 + r][nt * 16 + c] = acc[nt][r];
    if (mat == 0) {
      #pragma unroll
      for (int i = 0; i < 4; ++i) {
        int node = i * 4 + quad;
        f32x4 q4 = *(f32x4*)&SK[node][c * 4];
        *(f32x4*)&Q[(nodeBase + node) * 64 + c * 4] = q4;
      }
    } else if (mat == 2) {
      #pragma unroll
      for (int i = 0; i < 4; ++i) {
        int node = i * 4 + quad;
        f32x4 K4 = *(f32x4*)&SK[node][c * 4];
        f32x4 V4 = *(f32x4*)&SV[node][c * 4];
        uint4 o;
        o.x = pack2bf(K4[0], K4[1]);
        o.y = pack2bf(K4[2], K4[3]);
        o.z = pack2bf(V4[0], V4[1]);
        o.w = pack2bf(V4[2], V4[3]);
        *(uint4*)&KVb[(nodeBase + node) * 64 + c * 4] = o;
      }
    }
  }
}

// ---- GT layer: wave = node; 4 edge-slots x 16 lanes; coalesced 64-edge
// preload + __shfl removes the ecols global round-trip from the chain. ----
__global__ void __launch_bounds__(256) k_gt(const float* __restrict__ Q,
    const uint32* __restrict__ KVb, const int* __restrict__ row_ptr,
    const int* __restrict__ ecols, float* __restrict__ emb_out,
    uint32* __restrict__ embb_out) {
  int t = threadIdx.x;
  int n = blockIdx.x * 4 + (t >> 6);
  if (n >= NTOT) return;
  int lane = t & 63;
  int es = lane >> 4;
  int dl = lane & 15;
  float4 q4 = *(const float4*)&Q[n * 64 + dl * 4];
  int s     = __builtin_amdgcn_readfirstlane(row_ptr[n]);
  int e_end = __builtin_amdgcn_readfirstlane(row_ptr[n + 1]);
  int cnt = e_end - s;
  int li = s + lane;
  int cv = ecols[li < NEDGE ? li : NEDGE - 1];
  float den = 0.f;
  float4 acc = make_float4(0.f, 0.f, 0.f, 0.f);
  #pragma unroll 2
  for (int base = 0; base < cnt; base += 4) {
    int i = base + es;
    int cc;
    if (base < 64) cc = __shfl(cv, i & 63);
    else           cc = (i < cnt) ? ecols[s + i] : 0;
    float ex = 0.f;
    float4 v4 = make_float4(0.f, 0.f, 0.f, 0.f);
    if (i < cnt) {
      uint4 w = *(const uint4*)&KVb[cc * 64 + dl * 4];
      float kx = bf_lo(w.x), ky = bf_hi(w.x);
      float kz = bf_lo(w.y), kw = bf_hi(w.y);
      v4.x = bf_lo(w.z); v4.y = bf_hi(w.z);
      v4.z = bf_lo(w.w); v4.w = bf_hi(w.w);
      float x = q4.x * kx + q4.y * ky + q4.z * kz + q4.w * kw;
      x += __shfl_xor(x, 1);
      x += __shfl_xor(x, 2);
      x = fminf(fmaxf(x, -10.f), 10.f);
      ex = __expf(x);
    }
    den += ex;
    acc.x = fmaf(ex, v4.x, acc.x);
    acc.y = fmaf(ex, v4.y, acc.y);
    acc.z = fmaf(ex, v4.z, acc.z);
    acc.w = fmaf(ex, v4.w, acc.w);
  }
  #pragma unroll
  for (int off = 16; off <= 32; off <<= 1) {
    den  += __shfl_xor(den, off);
    acc.x += __shfl_xor(acc.x, off);
    acc.y += __shfl_xor(acc.y, off);
    acc.z += __shfl_xor(acc.z, off);
    acc.w += __shfl_xor(acc.w, off);
  }
  float inv = 1.f / (den + 1e-8f);
  float4 r = make_float4(acc.x * inv, acc.y * inv, acc.z * inv, acc.w * inv);
  if (es == 0) {
    *(float4*)&emb_out[n * 64 + dl * 4] = r;
  } else if (es == 1) {
    uint2 pk;
    pk.x = pack2bf(r.x, r.y);
    pk.y = pack2bf(r.z, r.w);
    *(uint2*)&embb_out[n * 32 + dl * 2] = pk;
  }
}

// ---- GCN layer (spmm): R1's proven structure (wave per node, lane = dim,
// direct ecols/evals loads, 8-wide predicated unroll, clamp-to-s dead slots)
// with the ONLY change being the gather width: ushort bf16 (128 B/edge row)
// instead of fp32 (256 B). Address chain identical to R1's 68.5 µs version.
// FINAL=0: writes fp32 out + bf16 ushort copy (next layer's gather source).
// FINAL=1: fuses final sum: out = cat(ue,ie)+GT1+GT2+GCN1(addG)+own. ----
template<int FINAL>
__global__ void __launch_bounds__(256) k_gcn(const ushort16* __restrict__ src,
    const int* __restrict__ row_ptr, const int* __restrict__ ecols,
    const float* __restrict__ evals, float* __restrict__ emb_out,
    ushort16* __restrict__ embb_out,
    const float* __restrict__ ue, const float* __restrict__ ie,
    const float* __restrict__ add1, const float* __restrict__ add2,
    const float* __restrict__ addG) {
  int t = threadIdx.x;
  int n = blockIdx.x * 4 + (t >> 6);
  if (n >= NTOT) return;
  int lane = t & 63;
  int s     = __builtin_amdgcn_readfirstlane(row_ptr[n]);
  int e_end = __builtin_amdgcn_readfirstlane(row_ptr[n + 1]);
  float a[8];
  #pragma unroll
  for (int j = 0; j < 8; ++j) a[j] = 0.f;
  for (int p = s; p < e_end; p += 8) {
    #pragma unroll
    for (int j = 0; j < 8; ++j) {
      int pj = p + j;
      int pc = (pj < e_end) ? pj : s;          // clamp: dead slots re-hit edge s (L1)
      float w = (pj < e_end) ? evals[pc] : 0.f;
      int c = ecols[pc];
      float m = __uint_as_float((uint32)src[c * 64 + lane] << 16);
      a[j] = fmaf(w, m, a[j]);
    }
  }
  float acc = ((a[0] + a[1]) + (a[2] + a[3])) + ((a[4] + a[5]) + (a[6] + a[7]));
  int base = n * 64 + lane;
  if (FINAL) {
    float b = (n < NUSERS) ? ue[base] : ie[base - NUSERS * 64];
    acc += b + add1[base] + add2[base] + addG[base];
    emb_out[base] = acc;
  } else {
    emb_out[base] = acc;
    embb_out[base] = f2bf(acc);
  }
}

extern "C" void kernel_launch(void* const* d_in, const int* in_sizes, int n_in,
                              void* d_out, int out_size, void* d_ws, size_t ws_size,
                              hipStream_t stream) {
  const int*   rows = (const int*)d_in[0];
  const int*   cols = (const int*)d_in[1];
  const float* vals = (const float*)d_in[2];
  const float* ue   = (const float*)d_in[3];
  const float* ie   = (const float*)d_in[4];
  const float* Wq   = (const float*)d_in[5];
  const float* Wk   = (const float*)d_in[6];
  const float* Wv   = (const float*)d_in[7];
  float* out = (float*)d_out;

  char* p = (char*)d_ws;
  auto alloc = [&](size_t b) { char* r = p; p += (b + 255) & ~(size_t)255; return (void*)r; };
  int*   cnt     = (int*)alloc((size_t)NTOT * 4);
  int*   row_ptr = (int*)alloc((size_t)(NTOT + 1) * 4);
  int*   cursor  = (int*)alloc((size_t)NTOT * 4);
  int*   bsums   = (int*)alloc(128 * 4);
  int*   boffs   = (int*)alloc(128 * 4);
  int*   ecols   = (int*)alloc((size_t)NEDGE * 4);
  float* evals   = (float*)alloc((size_t)NEDGE * 4);
  uint32* Wbg  = (uint32*)alloc((size_t)12288 * 4);
  float*  Q    = (float*)alloc((size_t)NTOT * 64 * 4);   // QKV Q; reused as GCN1 fp32 out
  uint32* KVb  = (uint32*)alloc((size_t)NTOT * 64 * 4);  // 256 B/node
  float*  embA = (float*)alloc((size_t)NTOT * 64 * 4);   // GT1 fp32 out (final sum)
  float*  embB = (float*)alloc((size_t)NTOT * 64 * 4);   // GT2 fp32 out (final sum)
  uint32* embb0 = (uint32*)alloc((size_t)NTOT * 32 * 4); // bf16, == ushort[n][64]
  uint32* embb1 = (uint32*)alloc((size_t)NTOT * 32 * 4);

  hipMemsetAsync(cnt, 0, (size_t)NTOT * 4, stream);
  k_hist<<<(NEDGE + 255) / 256, 256, 0, stream>>>(rows, cnt);
  int nblk = (NTOT + 2047) / 2048;  // 74
  k_scan1<<<nblk, 256, 0, stream>>>(cnt, row_ptr, bsums);
  k_scan2<<<1, 128, 0, stream>>>(bsums, boffs, nblk);
  k_scan3<<<(NTOT + 255) / 256, 256, 0, stream>>>(row_ptr, boffs, cursor);
  k_fill<<<(NEDGE + 255) / 256, 256, 0, stream>>>(rows, cols, vals, cursor, ecols, evals);
  k_wpack<<<48, 256, 0, stream>>>(Wq, Wk, Wv, Wbg);
  k_init<<<(NTOT * 16 + 255) / 256, 256, 0, stream>>>(ue, ie, embb0);

  // GT layer 1: writes embA (fp32, final sum) + embb1 (bf16, feeds GT2 QKV)
  k_qkv<<<(NTILE + 3) / 4, 256, 0, stream>>>(embb0, Wbg, Q, KVb);
  k_gt<<<(NTOT + 3) / 4, 256, 0, stream>>>(Q, KVb, row_ptr, ecols, embA, embb1);
  // GT layer 2: writes embB (fp32, final sum) + embb0 (bf16, feeds GCN1 gather)
  k_qkv<<<(NTILE + 3) / 4, 256, 0, stream>>>(embb1, Wbg + 6144, Q, KVb);
  k_gt<<<(NTOT + 3) / 4, 256, 0, stream>>>(Q, KVb, row_ptr, ecols, embB, embb0);
  // GCN1: bf16 gather of GT2-out -> Q (fp32, final-sum term) + embb1 (bf16, GCN2 gather src)
  k_gcn<0><<<(NTOT + 3) / 4, 256, 0, stream>>>((const ushort16*)embb0, row_ptr, ecols, evals,
                                               Q, (ushort16*)embb1,
                                               nullptr, nullptr, nullptr, nullptr, nullptr);
  // GCN2: bf16 gather of GCN1-out, fused 5-term final sum -> out
  k_gcn<1><<<(NTOT + 3) / 4, 256, 0, stream>>>((const ushort16*)embb1, row_ptr, ecols, evals,
                                               out, nullptr,
                                               ue, ie, embA, embB, Q);
}

// Round 4
// 477.509 us; speedup vs baseline: 1.1989x; 1.0705x over previous
//
#include <hip/hip_runtime.h>

#define NUSERS 100000
#define NITEMS 50000
#define NTOT   150000
#define NEDGE  1000000
#define NTILE  9375   // NTOT / 16

typedef unsigned int uint32;
typedef unsigned short ushort16;
typedef __attribute__((ext_vector_type(8))) short short8;
typedef __attribute__((ext_vector_type(4))) float f32x4;

__device__ __forceinline__ unsigned short f2bf(float f) {
  unsigned int u = __float_as_uint(f);
  u += 0x7FFFu + ((u >> 16) & 1u);   // round-to-nearest-even
  return (unsigned short)(u >> 16);
}
__device__ __forceinline__ uint32 pack2bf(float a, float b) {
  return (uint32)f2bf(a) | ((uint32)f2bf(b) << 16);
}
__device__ __forceinline__ float bf_lo(uint32 u) { return __uint_as_float(u << 16); }
__device__ __forceinline__ float bf_hi(uint32 u) { return __uint_as_float(u & 0xFFFF0000u); }

// ---- init: embb0 = bf16-pair packed copy of concat(user,item). ----
// NOTE: the uint32-pair layout is bit-identical to ushort[node][64] row-major.
__global__ void k_init(const float* __restrict__ ue, const float* __restrict__ ie,
                       uint32* __restrict__ embb) {
  int i = blockIdx.x * 256 + threadIdx.x;  // float4 index
  if (i >= NTOT * 16) return;
  float4 v = (i < NUSERS * 16) ? ((const float4*)ue)[i]
                               : ((const float4*)ie)[i - NUSERS * 16];
  uint2 pk;
  pk.x = pack2bf(v.x, v.y);
  pk.y = pack2bf(v.z, v.w);
  ((uint2*)embb)[i] = pk;
}

// ---- W pack: Wbg[l*6144 + mat*2048 + n*32 + k2] = bf16(W[2k2][n], W[2k2+1][n]) ----
__global__ void k_wpack(const float* __restrict__ Wq, const float* __restrict__ Wk,
                        const float* __restrict__ Wv, uint32* __restrict__ Wbg) {
  int t = blockIdx.x * 256 + threadIdx.x;
  if (t >= 12288) return;
  int l = t / 6144, rem = t % 6144, mat = rem / 2048, j = rem % 2048;
  int n = j >> 5, k2 = j & 31;
  const float* W = (mat == 0 ? Wq : mat == 1 ? Wk : Wv) + l * 4096;
  Wbg[t] = pack2bf(W[k2 * 128 + n], W[k2 * 128 + 64 + n]);
}

// ---- CSR build: histogram(+rank) -> scan -> packed fill ----
// rank[e] = this edge's arrival order within its row; removes the atomic
// round-trip from k_fill's store-address critical path.
__global__ void k_hist(const int* __restrict__ rows, int* __restrict__ cnt,
                       int* __restrict__ rank) {
  int e = blockIdx.x * 256 + threadIdx.x;
  if (e < NEDGE) rank[e] = atomicAdd(&cnt[rows[e]], 1);
}

__global__ void k_scan1(const int* __restrict__ cnt, int* __restrict__ partial,
                        int* __restrict__ blocksums) {
  __shared__ int s[256];
  int t = threadIdx.x, b = blockIdx.x;
  int base = b * 2048 + t * 8;
  int pre[8]; int sum = 0;
  #pragma unroll
  for (int j = 0; j < 8; ++j) {
    int idx = base + j;
    int x = (idx < NTOT) ? cnt[idx] : 0;
    pre[j] = sum; sum += x;
  }
  s[t] = sum; __syncthreads();
  for (int off = 1; off < 256; off <<= 1) {
    int x = (t >= off) ? s[t - off] : 0;
    __syncthreads(); s[t] += x; __syncthreads();
  }
  int excl = s[t] - sum;
  #pragma unroll
  for (int j = 0; j < 8; ++j) {
    int idx = base + j;
    if (idx < NTOT) partial[idx] = excl + pre[j];
  }
  if (t == 255) blocksums[b] = s[255];
}

__global__ void k_scan2(const int* __restrict__ blocksums, int* __restrict__ blockoffs, int nblk) {
  __shared__ int s[128];
  int t = threadIdx.x;
  int x = (t < nblk) ? blocksums[t] : 0;
  s[t] = x; __syncthreads();
  for (int off = 1; off < 128; off <<= 1) {
    int y = (t >= off) ? s[t - off] : 0;
    __syncthreads(); s[t] += y; __syncthreads();
  }
  if (t < nblk) blockoffs[t] = s[t] - x;
}

__global__ void k_scan3(int* __restrict__ row_ptr, const int* __restrict__ blockoffs) {
  int i = blockIdx.x * 256 + threadIdx.x;
  if (i < NTOT) row_ptr[i] += blockoffs[i >> 11];
  if (i == 0) row_ptr[NTOT] = NEDGE;
}

// ---- fill: one packed 8 B store per edge (half the scattered lines of the
// old two-array 4 B+4 B scheme), no atomic on the address path. ----
__global__ void k_fill(const int* __restrict__ rows, const int* __restrict__ cols,
                       const float* __restrict__ vals, const int* __restrict__ rank,
                       const int* __restrict__ row_ptr, uint2* __restrict__ epack) {
  int e = blockIdx.x * 256 + threadIdx.x;
  if (e >= NEDGE) return;
  int r = rows[e];
  int pos = row_ptr[r] + rank[e];
  uint2 pk;
  pk.x = (uint32)cols[e];
  pk.y = __float_as_uint(vals[e]);
  epack[pos] = pk;
}

// ---- QKV v5: MFMA. wave = 16-node tile. No LDS in main loop. ----
__global__ void __launch_bounds__(256) k_qkv(const uint32* __restrict__ embb,
    const uint32* __restrict__ Wbg, float* __restrict__ Q, uint32* __restrict__ KVb) {
  __shared__ float scr[4][2][16][68];  // [wave][K/V][node][dim(+pad)] = 34816 B
  int t = threadIdx.x;
  int wave = t >> 6, lane = t & 63;
  int tile = blockIdx.x * 4 + wave;
  if (tile >= NTILE) return;
  int c = lane & 15, quad = lane >> 4;
  int nodeBase = tile * 16;
  const uint32* arow = embb + (nodeBase + c) * 32 + quad * 4;
  uint4 a0u = *(const uint4*)arow;          // dims quad*8 .. +7
  uint4 a1u = *(const uint4*)(arow + 16);   // dims 32+quad*8 .. +7
  short8 a0 = *(short8*)&a0u;
  short8 a1 = *(short8*)&a1u;
  float (*SK)[68] = scr[wave][0];
  float (*SV)[68] = scr[wave][1];
  const uint32* wbase = Wbg + c * 32 + quad * 4;
  #pragma unroll
  for (int mat = 0; mat < 3; ++mat) {
    f32x4 acc[4];
    #pragma unroll
    for (int nt = 0; nt < 4; ++nt) acc[nt] = (f32x4){0.f, 0.f, 0.f, 0.f};
    const uint32* wb = wbase + mat * 2048;
    #pragma unroll
    for (int nt = 0; nt < 4; ++nt) {
      uint4 b0u = *(const uint4*)(wb + nt * 512);        // kh=0
      uint4 b1u = *(const uint4*)(wb + nt * 512 + 16);   // kh=1
      short8 b0 = *(short8*)&b0u;
      short8 b1 = *(short8*)&b1u;
      acc[nt] = __builtin_amdgcn_mfma_f32_16x16x32_bf16(a0, b0, acc[nt], 0, 0, 0);
      acc[nt] = __builtin_amdgcn_mfma_f32_16x16x32_bf16(a1, b1, acc[nt], 0, 0, 0);
    }
    float (*S)[68] = (mat == 2) ? SV : SK;   // Q and K reuse SK
    #pragma unroll
    for (int nt = 0; nt < 4; ++nt)
      #pragma unroll
      for (int r = 0; r < 4; ++r)
        S[quad * 4 + r][nt * 16 + c] = acc[nt][r];
    if (mat == 0) {
      #pragma unroll
      for (int i = 0; i < 4; ++i) {
        int node = i * 4 + quad;
        f32x4 q4 = *(f32x4*)&SK[node][c * 4];
        *(f32x4*)&Q[(nodeBase + node) * 64 + c * 4] = q4;
      }
    } else if (mat == 2) {
      #pragma unroll
      for (int i = 0; i < 4; ++i) {
        int node = i * 4 + quad;
        f32x4 K4 = *(f32x4*)&SK[node][c * 4];
        f32x4 V4 = *(f32x4*)&SV[node][c * 4];
        uint4 o;
        o.x = pack2bf(K4[0], K4[1]);
        o.y = pack2bf(K4[2], K4[3]);
        o.z = pack2bf(V4[0], V4[1]);
        o.w = pack2bf(V4[2], V4[3]);
        *(uint4*)&KVb[(nodeBase + node) * 64 + c * 4] = o;
      }
    }
  }
}

// ---- GT layer: wave = node; 4 edge-slots x 16 lanes; coalesced 64-edge
// preload (epack.x) + __shfl removes the metadata round-trip from the chain. ----
__global__ void __launch_bounds__(256) k_gt(const float* __restrict__ Q,
    const uint32* __restrict__ KVb, const int* __restrict__ row_ptr,
    const uint2* __restrict__ epack, float* __restrict__ emb_out,
    uint32* __restrict__ embb_out) {
  int t = threadIdx.x;
  int n = blockIdx.x * 4 + (t >> 6);
  if (n >= NTOT) return;
  int lane = t & 63;
  int es = lane >> 4;
  int dl = lane & 15;
  float4 q4 = *(const float4*)&Q[n * 64 + dl * 4];
  int s     = __builtin_amdgcn_readfirstlane(row_ptr[n]);
  int e_end = __builtin_amdgcn_readfirstlane(row_ptr[n + 1]);
  int cnt = e_end - s;
  int li = s + lane;
  int cv = (int)epack[li < NEDGE ? li : NEDGE - 1].x;
  float den = 0.f;
  float4 acc = make_float4(0.f, 0.f, 0.f, 0.f);
  #pragma unroll 2
  for (int base = 0; base < cnt; base += 4) {
    int i = base + es;
    int cc;
    if (base < 64) cc = __shfl(cv, i & 63);
    else           cc = (i < cnt) ? (int)epack[s + i].x : 0;
    float ex = 0.f;
    float4 v4 = make_float4(0.f, 0.f, 0.f, 0.f);
    if (i < cnt) {
      uint4 w = *(const uint4*)&KVb[cc * 64 + dl * 4];
      float kx = bf_lo(w.x), ky = bf_hi(w.x);
      float kz = bf_lo(w.y), kw = bf_hi(w.y);
      v4.x = bf_lo(w.z); v4.y = bf_hi(w.z);
      v4.z = bf_lo(w.w); v4.w = bf_hi(w.w);
      float x = q4.x * kx + q4.y * ky + q4.z * kz + q4.w * kw;
      x += __shfl_xor(x, 1);
      x += __shfl_xor(x, 2);
      x = fminf(fmaxf(x, -10.f), 10.f);
      ex = __expf(x);
    }
    den += ex;
    acc.x = fmaf(ex, v4.x, acc.x);
    acc.y = fmaf(ex, v4.y, acc.y);
    acc.z = fmaf(ex, v4.z, acc.z);
    acc.w = fmaf(ex, v4.w, acc.w);
  }
  #pragma unroll
  for (int off = 16; off <= 32; off <<= 1) {
    den  += __shfl_xor(den, off);
    acc.x += __shfl_xor(acc.x, off);
    acc.y += __shfl_xor(acc.y, off);
    acc.z += __shfl_xor(acc.z, off);
    acc.w += __shfl_xor(acc.w, off);
  }
  float inv = 1.f / (den + 1e-8f);
  float4 r = make_float4(acc.x * inv, acc.y * inv, acc.z * inv, acc.w * inv);
  if (es == 0) {
    *(float4*)&emb_out[n * 64 + dl * 4] = r;
  } else if (es == 1) {
    uint2 pk;
    pk.x = pack2bf(r.x, r.y);
    pk.y = pack2bf(r.z, r.w);
    *(uint2*)&embb_out[n * 32 + dl * 2] = pk;
  }
}

// ---- GCN layer (spmm): wave per node, lane = dim, 8-wide predicated unroll,
// clamp-to-s dead slots. bf16 ushort gather (128 B/edge row). Edge metadata is
// now one 8 B load (same line) instead of two 4 B loads from separate arrays.
// FINAL=0: writes fp32 out + bf16 ushort copy (next layer's gather source).
// FINAL=1: fuses final sum: out = cat(ue,ie)+GT1+GT2+GCN1(addG)+own. ----
template<int FINAL>
__global__ void __launch_bounds__(256) k_gcn(const ushort16* __restrict__ src,
    const int* __restrict__ row_ptr, const uint2* __restrict__ epack,
    float* __restrict__ emb_out, ushort16* __restrict__ embb_out,
    const float* __restrict__ ue, const float* __restrict__ ie,
    const float* __restrict__ add1, const float* __restrict__ add2,
    const float* __restrict__ addG) {
  int t = threadIdx.x;
  int n = blockIdx.x * 4 + (t >> 6);
  if (n >= NTOT) return;
  int lane = t & 63;
  int s     = __builtin_amdgcn_readfirstlane(row_ptr[n]);
  int e_end = __builtin_amdgcn_readfirstlane(row_ptr[n + 1]);
  float a[8];
  #pragma unroll
  for (int j = 0; j < 8; ++j) a[j] = 0.f;
  for (int p = s; p < e_end; p += 8) {
    #pragma unroll
    for (int j = 0; j < 8; ++j) {
      int pj = p + j;
      int pc = (pj < e_end) ? pj : s;          // clamp: dead slots re-hit edge s (L1)
      uint2 ev = epack[pc];
      float w = (pj < e_end) ? __uint_as_float(ev.y) : 0.f;
      int c = (int)ev.x;
      float m = __uint_as_float((uint32)src[c * 64 + lane] << 16);
      a[j] = fmaf(w, m, a[j]);
    }
  }
  float acc = ((a[0] + a[1]) + (a[2] + a[3])) + ((a[4] + a[5]) + (a[6] + a[7]));
  int base = n * 64 + lane;
  if (FINAL) {
    float b = (n < NUSERS) ? ue[base] : ie[base - NUSERS * 64];
    acc += b + add1[base] + add2[base] + addG[base];
    emb_out[base] = acc;
  } else {
    emb_out[base] = acc;
    embb_out[base] = f2bf(acc);
  }
}

extern "C" void kernel_launch(void* const* d_in, const int* in_sizes, int n_in,
                              void* d_out, int out_size, void* d_ws, size_t ws_size,
                              hipStream_t stream) {
  const int*   rows = (const int*)d_in[0];
  const int*   cols = (const int*)d_in[1];
  const float* vals = (const float*)d_in[2];
  const float* ue   = (const float*)d_in[3];
  const float* ie   = (const float*)d_in[4];
  const float* Wq   = (const float*)d_in[5];
  const float* Wk   = (const float*)d_in[6];
  const float* Wv   = (const float*)d_in[7];
  float* out = (float*)d_out;

  char* p = (char*)d_ws;
  auto alloc = [&](size_t b) { char* r = p; p += (b + 255) & ~(size_t)255; return (void*)r; };
  int*   cnt     = (int*)alloc((size_t)NTOT * 4);
  int*   row_ptr = (int*)alloc((size_t)(NTOT + 1) * 4);
  int*   rank    = (int*)alloc((size_t)NEDGE * 4);
  int*   bsums   = (int*)alloc(128 * 4);
  int*   boffs   = (int*)alloc(128 * 4);
  uint2* epack   = (uint2*)alloc((size_t)NEDGE * 8);     // {col, val bits}
  uint32* Wbg  = (uint32*)alloc((size_t)12288 * 4);
  float*  Q    = (float*)alloc((size_t)NTOT * 64 * 4);   // QKV Q; reused as GCN1 fp32 out
  uint32* KVb  = (uint32*)alloc((size_t)NTOT * 64 * 4);  // 256 B/node
  float*  embA = (float*)alloc((size_t)NTOT * 64 * 4);   // GT1 fp32 out (final sum)
  float*  embB = (float*)alloc((size_t)NTOT * 64 * 4);   // GT2 fp32 out (final sum)
  uint32* embb0 = (uint32*)alloc((size_t)NTOT * 32 * 4); // bf16, == ushort[n][64]
  uint32* embb1 = (uint32*)alloc((size_t)NTOT * 32 * 4);

  hipMemsetAsync(cnt, 0, (size_t)NTOT * 4, stream);
  k_hist<<<(NEDGE + 255) / 256, 256, 0, stream>>>(rows, cnt, rank);
  int nblk = (NTOT + 2047) / 2048;  // 74
  k_scan1<<<nblk, 256, 0, stream>>>(cnt, row_ptr, bsums);
  k_scan2<<<1, 128, 0, stream>>>(bsums, boffs, nblk);
  k_scan3<<<(NTOT + 255) / 256, 256, 0, stream>>>(row_ptr, boffs);
  k_fill<<<(NEDGE + 255) / 256, 256, 0, stream>>>(rows, cols, vals, rank, row_ptr, epack);
  k_wpack<<<48, 256, 0, stream>>>(Wq, Wk, Wv, Wbg);
  k_init<<<(NTOT * 16 + 255) / 256, 256, 0, stream>>>(ue, ie, embb0);

  // GT layer 1: writes embA (fp32, final sum) + embb1 (bf16, feeds GT2 QKV)
  k_qkv<<<(NTILE + 3) / 4, 256, 0, stream>>>(embb0, Wbg, Q, KVb);
  k_gt<<<(NTOT + 3) / 4, 256, 0, stream>>>(Q, KVb, row_ptr, epack, embA, embb1);
  // GT layer 2: writes embB (fp32, final sum) + embb0 (bf16, feeds GCN1 gather)
  k_qkv<<<(NTILE + 3) / 4, 256, 0, stream>>>(embb1, Wbg + 6144, Q, KVb);
  k_gt<<<(NTOT + 3) / 4, 256, 0, stream>>>(Q, KVb, row_ptr, epack, embB, embb0);
  // GCN1: bf16 gather of GT2-out -> Q (fp32, final-sum term) + embb1 (bf16, GCN2 gather src)
  k_gcn<0><<<(NTOT + 3) / 4, 256, 0, stream>>>((const ushort16*)embb0, row_ptr, epack,
                                               Q, (ushort16*)embb1,
                                               nullptr, nullptr, nullptr, nullptr, nullptr);
  // GCN2: bf16 gather of GCN1-out, fused 5-term final sum -> out
  k_gcn<1><<<(NTOT + 3) / 4, 256, 0, stream>>>((const ushort16*)embb1, row_ptr, epack,
                                               out, nullptr,
                                               ue, ie, embA, embB, Q);
}

// Round 5
// 458.102 us; speedup vs baseline: 1.2496x; 1.0424x over previous
//
#include <hip/hip_runtime.h>

#define NUSERS 100000
#define NITEMS 50000
#define NTOT   150000
#define NEDGE  1000000
#define NTILE  9375   // NTOT / 16

typedef unsigned int uint32;
typedef unsigned short bf16u;
typedef __attribute__((ext_vector_type(8))) short short8;
typedef __attribute__((ext_vector_type(4))) float f32x4;

__device__ __forceinline__ unsigned short f2bf(float f) {
  unsigned int u = __float_as_uint(f);
  u += 0x7FFFu + ((u >> 16) & 1u);   // round-to-nearest-even
  return (unsigned short)(u >> 16);
}
__device__ __forceinline__ uint32 pack2bf(float a, float b) {
  return (uint32)f2bf(a) | ((uint32)f2bf(b) << 16);
}
__device__ __forceinline__ float bf_lo(uint32 u) { return __uint_as_float(u << 16); }
__device__ __forceinline__ float bf_hi(uint32 u) { return __uint_as_float(u & 0xFFFF0000u); }
__device__ __forceinline__ float bf2f(bf16u v) { return __uint_as_float((uint32)v << 16); }

// ---- combo setup: [0,9375) init embb0; [9375,9423) wpack; [9423,13330) hist ----
// init: embb0 = bf16-pair packed copy of concat(user,item)
//       (uint32-pair layout is bit-identical to ushort[node][64] row-major)
// wpack: Wbg[l*6144 + mat*2048 + n*32 + k2] = bf16(W[2k2][n], W[2k2+1][n])
// hist:  rank[e] = arrival order within row (kills the atomic round-trip in k_fill)
__global__ void k_combo(const float* __restrict__ ue, const float* __restrict__ ie,
                        uint32* __restrict__ embb,
                        const float* __restrict__ Wq, const float* __restrict__ Wk,
                        const float* __restrict__ Wv, uint32* __restrict__ Wbg,
                        const int* __restrict__ rows, int* __restrict__ cnt,
                        int* __restrict__ rank) {
  int b = blockIdx.x, t = threadIdx.x;
  if (b < 9375) {            // init: 9375*256 == NTOT*16 exactly
    int i = b * 256 + t;     // float4 index
    float4 v = (i < NUSERS * 16) ? ((const float4*)ue)[i]
                                 : ((const float4*)ie)[i - NUSERS * 16];
    uint2 pk;
    pk.x = pack2bf(v.x, v.y);
    pk.y = pack2bf(v.z, v.w);
    ((uint2*)embb)[i] = pk;
  } else if (b < 9423) {     // wpack: 48*256 == 12288 exactly
    int i = (b - 9375) * 256 + t;
    int l = i / 6144, rem = i % 6144, mat = rem / 2048, j = rem % 2048;
    int n = j >> 5, k2 = j & 31;
    const float* W = (mat == 0 ? Wq : mat == 1 ? Wk : Wv) + l * 4096;
    Wbg[i] = pack2bf(W[k2 * 128 + n], W[k2 * 128 + 64 + n]);
  } else {                   // hist
    int e = (b - 9423) * 256 + t;
    if (e < NEDGE) rank[e] = atomicAdd(&cnt[rows[e]], 1);
  }
}

__global__ void k_scan1(const int* __restrict__ cnt, int* __restrict__ partial,
                        int* __restrict__ blocksums) {
  __shared__ int s[256];
  int t = threadIdx.x, b = blockIdx.x;
  int base = b * 2048 + t * 8;
  int pre[8]; int sum = 0;
  #pragma unroll
  for (int j = 0; j < 8; ++j) {
    int idx = base + j;
    int x = (idx < NTOT) ? cnt[idx] : 0;
    pre[j] = sum; sum += x;
  }
  s[t] = sum; __syncthreads();
  for (int off = 1; off < 256; off <<= 1) {
    int x = (t >= off) ? s[t - off] : 0;
    __syncthreads(); s[t] += x; __syncthreads();
  }
  int excl = s[t] - sum;
  #pragma unroll
  for (int j = 0; j < 8; ++j) {
    int idx = base + j;
    if (idx < NTOT) partial[idx] = excl + pre[j];
  }
  if (t == 255) blocksums[b] = s[255];
}

__global__ void k_scan2(const int* __restrict__ blocksums, int* __restrict__ blockoffs, int nblk) {
  __shared__ int s[128];
  int t = threadIdx.x;
  int x = (t < nblk) ? blocksums[t] : 0;
  s[t] = x; __syncthreads();
  for (int off = 1; off < 128; off <<= 1) {
    int y = (t >= off) ? s[t - off] : 0;
    __syncthreads(); s[t] += y; __syncthreads();
  }
  if (t < nblk) blockoffs[t] = s[t] - x;
}

__global__ void k_scan3(int* __restrict__ row_ptr, const int* __restrict__ blockoffs) {
  int i = blockIdx.x * 256 + threadIdx.x;
  if (i < NTOT) row_ptr[i] += blockoffs[i >> 11];
  if (i == 0) row_ptr[NTOT] = NEDGE;
}

// ---- fill: one packed 8 B store per edge, no atomic on the address path ----
__global__ void k_fill(const int* __restrict__ rows, const int* __restrict__ cols,
                       const float* __restrict__ vals, const int* __restrict__ rank,
                       const int* __restrict__ row_ptr, uint2* __restrict__ epack) {
  int e = blockIdx.x * 256 + threadIdx.x;
  if (e >= NEDGE) return;
  int r = rows[e];
  int pos = row_ptr[r] + rank[e];
  uint2 pk;
  pk.x = (uint32)cols[e];
  pk.y = __float_as_uint(vals[e]);
  epack[pos] = pk;
}

// ---- QKV v5: MFMA. wave = 16-node tile. No LDS in main loop. ----
__global__ void __launch_bounds__(256) k_qkv(const uint32* __restrict__ embb,
    const uint32* __restrict__ Wbg, float* __restrict__ Q, uint32* __restrict__ KVb) {
  __shared__ float scr[4][2][16][68];  // [wave][K/V][node][dim(+pad)] = 34816 B
  int t = threadIdx.x;
  int wave = t >> 6, lane = t & 63;
  int tile = blockIdx.x * 4 + wave;
  if (tile >= NTILE) return;
  int c = lane & 15, quad = lane >> 4;
  int nodeBase = tile * 16;
  const uint32* arow = embb + (nodeBase + c) * 32 + quad * 4;
  uint4 a0u = *(const uint4*)arow;          // dims quad*8 .. +7
  uint4 a1u = *(const uint4*)(arow + 16);   // dims 32+quad*8 .. +7
  short8 a0 = *(short8*)&a0u;
  short8 a1 = *(short8*)&a1u;
  float (*SK)[68] = scr[wave][0];
  float (*SV)[68] = scr[wave][1];
  const uint32* wbase = Wbg + c * 32 + quad * 4;
  #pragma unroll
  for (int mat = 0; mat < 3; ++mat) {
    f32x4 acc[4];
    #pragma unroll
    for (int nt = 0; nt < 4; ++nt) acc[nt] = (f32x4){0.f, 0.f, 0.f, 0.f};
    const uint32* wb = wbase + mat * 2048;
    #pragma unroll
    for (int nt = 0; nt < 4; ++nt) {
      uint4 b0u = *(const uint4*)(wb + nt * 512);        // kh=0
      uint4 b1u = *(const uint4*)(wb + nt * 512 + 16);   // kh=1
      short8 b0 = *(short8*)&b0u;
      short8 b1 = *(short8*)&b1u;
      acc[nt] = __builtin_amdgcn_mfma_f32_16x16x32_bf16(a0, b0, acc[nt], 0, 0, 0);
      acc[nt] = __builtin_amdgcn_mfma_f32_16x16x32_bf16(a1, b1, acc[nt], 0, 0, 0);
    }
    float (*S)[68] = (mat == 2) ? SV : SK;   // Q and K reuse SK
    #pragma unroll
    for (int nt = 0; nt < 4; ++nt)
      #pragma unroll
      for (int r = 0; r < 4; ++r)
        S[quad * 4 + r][nt * 16 + c] = acc[nt][r];
    if (mat == 0) {
      #pragma unroll
      for (int i = 0; i < 4; ++i) {
        int node = i * 4 + quad;
        f32x4 q4 = *(f32x4*)&SK[node][c * 4];
        *(f32x4*)&Q[(nodeBase + node) * 64 + c * 4] = q4;
      }
    } else if (mat == 2) {
      #pragma unroll
      for (int i = 0; i < 4; ++i) {
        int node = i * 4 + quad;
        f32x4 K4 = *(f32x4*)&SK[node][c * 4];
        f32x4 V4 = *(f32x4*)&SV[node][c * 4];
        uint4 o;
        o.x = pack2bf(K4[0], K4[1]);
        o.y = pack2bf(K4[2], K4[3]);
        o.z = pack2bf(V4[0], V4[1]);
        o.w = pack2bf(V4[2], V4[3]);
        *(uint4*)&KVb[(nodeBase + node) * 64 + c * 4] = o;
      }
    }
  }
}

// ---- GT layer: wave = node; 4 edge-slots x 16 lanes; coalesced 64-edge
// preload (epack.x) + __shfl. Output is bf16-ONLY now (19.2 MB instead of
// 38.4+19.2): the fp32 copy existed solely for the final sum, which now
// consumes the bf16 buffer directly. ----
__global__ void __launch_bounds__(256) k_gt(const float* __restrict__ Q,
    const uint32* __restrict__ KVb, const int* __restrict__ row_ptr,
    const uint2* __restrict__ epack, uint32* __restrict__ embb_out) {
  int t = threadIdx.x;
  int n = blockIdx.x * 4 + (t >> 6);
  if (n >= NTOT) return;
  int lane = t & 63;
  int es = lane >> 4;
  int dl = lane & 15;
  float4 q4 = *(const float4*)&Q[n * 64 + dl * 4];
  int s     = __builtin_amdgcn_readfirstlane(row_ptr[n]);
  int e_end = __builtin_amdgcn_readfirstlane(row_ptr[n + 1]);
  int cnt = e_end - s;
  int li = s + lane;
  int cv = (int)epack[li < NEDGE ? li : NEDGE - 1].x;
  float den = 0.f;
  float4 acc = make_float4(0.f, 0.f, 0.f, 0.f);
  #pragma unroll 2
  for (int base = 0; base < cnt; base += 4) {
    int i = base + es;
    int cc;
    if (base < 64) cc = __shfl(cv, i & 63);
    else           cc = (i < cnt) ? (int)epack[s + i].x : 0;
    float ex = 0.f;
    float4 v4 = make_float4(0.f, 0.f, 0.f, 0.f);
    if (i < cnt) {
      uint4 w = *(const uint4*)&KVb[cc * 64 + dl * 4];
      float kx = bf_lo(w.x), ky = bf_hi(w.x);
      float kz = bf_lo(w.y), kw = bf_hi(w.y);
      v4.x = bf_lo(w.z); v4.y = bf_hi(w.z);
      v4.z = bf_lo(w.w); v4.w = bf_hi(w.w);
      float x = q4.x * kx + q4.y * ky + q4.z * kz + q4.w * kw;
      x += __shfl_xor(x, 1);
      x += __shfl_xor(x, 2);
      x = fminf(fmaxf(x, -10.f), 10.f);
      ex = __expf(x);
    }
    den += ex;
    acc.x = fmaf(ex, v4.x, acc.x);
    acc.y = fmaf(ex, v4.y, acc.y);
    acc.z = fmaf(ex, v4.z, acc.z);
    acc.w = fmaf(ex, v4.w, acc.w);
  }
  #pragma unroll
  for (int off = 16; off <= 32; off <<= 1) {
    den  += __shfl_xor(den, off);
    acc.x += __shfl_xor(acc.x, off);
    acc.y += __shfl_xor(acc.y, off);
    acc.z += __shfl_xor(acc.z, off);
    acc.w += __shfl_xor(acc.w, off);
  }
  float inv = 1.f / (den + 1e-8f);
  if (es == 0) {
    uint2 pk;
    pk.x = pack2bf(acc.x * inv, acc.y * inv);
    pk.y = pack2bf(acc.z * inv, acc.w * inv);
    *(uint2*)&embb_out[n * 32 + dl * 2] = pk;
  }
}

// ---- GCN layer (spmm): wave per node, lane = dim, 8-wide predicated unroll,
// clamp-to-s dead slots, bf16 ushort gather (128 B/edge row).
// FINAL=0: writes bf16 out ONLY (next layer's gather source + final-sum term).
// FINAL=1: fused 5-term sum, all layer terms read from their bf16 buffers:
//          out = cat(ue,ie) + B1(GT1) + B2(GT2) + B3(GCN1,=src own row) + own spmm. ----
template<int FINAL>
__global__ void __launch_bounds__(256) k_gcn(const bf16u* __restrict__ src,
    const int* __restrict__ row_ptr, const uint2* __restrict__ epack,
    bf16u* __restrict__ embb_out, float* __restrict__ out,
    const float* __restrict__ ue, const float* __restrict__ ie,
    const bf16u* __restrict__ add1, const bf16u* __restrict__ add2) {
  int t = threadIdx.x;
  int n = blockIdx.x * 4 + (t >> 6);
  if (n >= NTOT) return;
  int lane = t & 63;
  int s     = __builtin_amdgcn_readfirstlane(row_ptr[n]);
  int e_end = __builtin_amdgcn_readfirstlane(row_ptr[n + 1]);
  int base = n * 64 + lane;
  // FINAL: issue the coalesced stream loads early; they drain under the gathers.
  float sum_extra = 0.f;
  if (FINAL) {
    float b = (n < NUSERS) ? ue[base] : ie[base - NUSERS * 64];
    float t1 = bf2f(add1[base]);
    float t2 = bf2f(add2[base]);
    float t3 = bf2f(src[base]);     // GCN1's own row (same buffer we gather)
    sum_extra = (b + t1) + (t2 + t3);
  }
  float a[8];
  #pragma unroll
  for (int j = 0; j < 8; ++j) a[j] = 0.f;
  for (int p = s; p < e_end; p += 8) {
    #pragma unroll
    for (int j = 0; j < 8; ++j) {
      int pj = p + j;
      int pc = (pj < e_end) ? pj : s;          // clamp: dead slots re-hit edge s (L1)
      uint2 ev = epack[pc];
      float w = (pj < e_end) ? __uint_as_float(ev.y) : 0.f;
      int c = (int)ev.x;
      a[j] = fmaf(w, bf2f(src[c * 64 + lane]), a[j]);
    }
  }
  float acc = ((a[0] + a[1]) + (a[2] + a[3])) + ((a[4] + a[5]) + (a[6] + a[7]));
  if (FINAL) {
    out[base] = acc + sum_extra;
  } else {
    embb_out[base] = f2bf(acc);
  }
}

extern "C" void kernel_launch(void* const* d_in, const int* in_sizes, int n_in,
                              void* d_out, int out_size, void* d_ws, size_t ws_size,
                              hipStream_t stream) {
  const int*   rows = (const int*)d_in[0];
  const int*   cols = (const int*)d_in[1];
  const float* vals = (const float*)d_in[2];
  const float* ue   = (const float*)d_in[3];
  const float* ie   = (const float*)d_in[4];
  const float* Wq   = (const float*)d_in[5];
  const float* Wk   = (const float*)d_in[6];
  const float* Wv   = (const float*)d_in[7];
  float* out = (float*)d_out;

  char* p = (char*)d_ws;
  auto alloc = [&](size_t b) { char* r = p; p += (b + 255) & ~(size_t)255; return (void*)r; };
  int*   cnt     = (int*)alloc((size_t)NTOT * 4);
  int*   row_ptr = (int*)alloc((size_t)(NTOT + 1) * 4);
  int*   rank    = (int*)alloc((size_t)NEDGE * 4);
  int*   bsums   = (int*)alloc(128 * 4);
  int*   boffs   = (int*)alloc(128 * 4);
  uint2* epack   = (uint2*)alloc((size_t)NEDGE * 8);     // {col, val bits}
  uint32* Wbg  = (uint32*)alloc((size_t)12288 * 4);
  float*  Q    = (float*)alloc((size_t)NTOT * 64 * 4);   // fp32 Q (per GT layer)
  uint32* KVb  = (uint32*)alloc((size_t)NTOT * 64 * 4);  // 256 B/node packed K|V
  uint32* B0   = (uint32*)alloc((size_t)NTOT * 32 * 4);  // bf16 rows == ushort[n][64]
  uint32* B1   = (uint32*)alloc((size_t)NTOT * 32 * 4);  // GT1 out
  uint32* B2   = (uint32*)alloc((size_t)NTOT * 32 * 4);  // GT2 out
  uint32* B3   = (uint32*)alloc((size_t)NTOT * 32 * 4);  // GCN1 out

  hipMemsetAsync(cnt, 0, (size_t)NTOT * 4, stream);
  // fused init + wpack + hist
  k_combo<<<13330, 256, 0, stream>>>(ue, ie, B0, Wq, Wk, Wv, Wbg, rows, cnt, rank);
  int nblk = (NTOT + 2047) / 2048;  // 74
  k_scan1<<<nblk, 256, 0, stream>>>(cnt, row_ptr, bsums);
  k_scan2<<<1, 128, 0, stream>>>(bsums, boffs, nblk);
  k_scan3<<<(NTOT + 255) / 256, 256, 0, stream>>>(row_ptr, boffs);
  k_fill<<<(NEDGE + 255) / 256, 256, 0, stream>>>(rows, cols, vals, rank, row_ptr, epack);

  // GT layer 1: B0 -> B1 (bf16 only)
  k_qkv<<<(NTILE + 3) / 4, 256, 0, stream>>>(B0, Wbg, Q, KVb);
  k_gt<<<(NTOT + 3) / 4, 256, 0, stream>>>(Q, KVb, row_ptr, epack, B1);
  // GT layer 2: B1 -> B2 (bf16 only)
  k_qkv<<<(NTILE + 3) / 4, 256, 0, stream>>>(B1, Wbg + 6144, Q, KVb);
  k_gt<<<(NTOT + 3) / 4, 256, 0, stream>>>(Q, KVb, row_ptr, epack, B2);
  // GCN1: gather B2 -> B3 (bf16 only)
  k_gcn<0><<<(NTOT + 3) / 4, 256, 0, stream>>>((const bf16u*)B2, row_ptr, epack,
                                               (bf16u*)B3, nullptr,
                                               nullptr, nullptr, nullptr, nullptr);
  // GCN2 + fused final sum: gather B3; out = cat(ue,ie)+B1+B2+B3+own
  k_gcn<1><<<(NTOT + 3) / 4, 256, 0, stream>>>((const bf16u*)B3, row_ptr, epack,
                                               nullptr, out,
                                               ue, ie, (const bf16u*)B1, (const bf16u*)B2);
}

// Round 7
// 439.881 us; speedup vs baseline: 1.3014x; 1.0414x over previous
//
#include <hip/hip_runtime.h>

#define NUSERS 100000
#define NITEMS 50000
#define NTOT   150000
#define NEDGE  1000000
#define NTILE  9375   // NTOT / 16

typedef unsigned int uint32;
typedef unsigned short bf16u;
typedef __attribute__((ext_vector_type(8))) short short8;
typedef __attribute__((ext_vector_type(4))) float f32x4;

__device__ __forceinline__ unsigned short f2bf(float f) {
  unsigned int u = __float_as_uint(f);
  u += 0x7FFFu + ((u >> 16) & 1u);   // round-to-nearest-even
  return (unsigned short)(u >> 16);
}
__device__ __forceinline__ uint32 pack2bf(float a, float b) {
  return (uint32)f2bf(a) | ((uint32)f2bf(b) << 16);
}
__device__ __forceinline__ float bf_lo(uint32 u) { return __uint_as_float(u << 16); }
__device__ __forceinline__ float bf_hi(uint32 u) { return __uint_as_float(u & 0xFFFF0000u); }
__device__ __forceinline__ float bf2f(bf16u v) { return __uint_as_float((uint32)v << 16); }

// ---- combo setup: [0,9375) init embb0; [9375,9423) wpack; [9423,13330) hist ----
__global__ void k_combo(const float* __restrict__ ue, const float* __restrict__ ie,
                        uint32* __restrict__ embb,
                        const float* __restrict__ Wq, const float* __restrict__ Wk,
                        const float* __restrict__ Wv, uint32* __restrict__ Wbg,
                        const int* __restrict__ rows, int* __restrict__ cnt,
                        int* __restrict__ rank) {
  int b = blockIdx.x, t = threadIdx.x;
  if (b < 9375) {            // init: 9375*256 == NTOT*16 exactly
    int i = b * 256 + t;     // float4 index
    float4 v = (i < NUSERS * 16) ? ((const float4*)ue)[i]
                                 : ((const float4*)ie)[i - NUSERS * 16];
    uint2 pk;
    pk.x = pack2bf(v.x, v.y);
    pk.y = pack2bf(v.z, v.w);
    ((uint2*)embb)[i] = pk;
  } else if (b < 9423) {     // wpack: 48*256 == 12288 exactly
    int i = (b - 9375) * 256 + t;
    int l = i / 6144, rem = i % 6144, mat = rem / 2048, j = rem % 2048;
    int n = j >> 5, k2 = j & 31;
    const float* W = (mat == 0 ? Wq : mat == 1 ? Wk : Wv) + l * 4096;
    Wbg[i] = pack2bf(W[k2 * 128 + n], W[k2 * 128 + 64 + n]);
  } else {                   // hist
    int e = (b - 9423) * 256 + t;
    if (e < NEDGE) rank[e] = atomicAdd(&cnt[rows[e]], 1);
  }
}

__global__ void k_scan1(const int* __restrict__ cnt, int* __restrict__ partial,
                        int* __restrict__ blocksums) {
  __shared__ int s[256];
  int t = threadIdx.x, b = blockIdx.x;
  int base = b * 2048 + t * 8;
  int pre[8]; int sum = 0;
  #pragma unroll
  for (int j = 0; j < 8; ++j) {
    int idx = base + j;
    int x = (idx < NTOT) ? cnt[idx] : 0;
    pre[j] = sum; sum += x;
  }
  s[t] = sum; __syncthreads();
  for (int off = 1; off < 256; off <<= 1) {
    int x = (t >= off) ? s[t - off] : 0;
    __syncthreads(); s[t] += x; __syncthreads();
  }
  int excl = s[t] - sum;
  #pragma unroll
  for (int j = 0; j < 8; ++j) {
    int idx = base + j;
    if (idx < NTOT) partial[idx] = excl + pre[j];
  }
  if (t == 255) blocksums[b] = s[255];
}

__global__ void k_scan2(const int* __restrict__ blocksums, int* __restrict__ blockoffs, int nblk) {
  __shared__ int s[128];
  int t = threadIdx.x;
  int x = (t < nblk) ? blocksums[t] : 0;
  s[t] = x; __syncthreads();
  for (int off = 1; off < 128; off <<= 1) {
    int y = (t >= off) ? s[t - off] : 0;
    __syncthreads(); s[t] += y; __syncthreads();
  }
  if (t < nblk) blockoffs[t] = s[t] - x;
}

__global__ void k_scan3(int* __restrict__ row_ptr, const int* __restrict__ blockoffs) {
  int i = blockIdx.x * 256 + threadIdx.x;
  if (i < NTOT) row_ptr[i] += blockoffs[i >> 11];
  if (i == 0) row_ptr[NTOT] = NEDGE;
}

// ---- fill: one packed 8 B store per edge, no atomic on the address path ----
__global__ void k_fill(const int* __restrict__ rows, const int* __restrict__ cols,
                       const float* __restrict__ vals, const int* __restrict__ rank,
                       const int* __restrict__ row_ptr, uint2* __restrict__ epack) {
  int e = blockIdx.x * 256 + threadIdx.x;
  if (e >= NEDGE) return;
  int r = rows[e];
  int pos = row_ptr[r] + rank[e];
  uint2 pk;
  pk.x = (uint32)cols[e];
  pk.y = __float_as_uint(vals[e]);
  epack[pos] = pk;
}

// ---- QKV: MFMA. wave = 16-node tile. Q stays fp32 (R6 lesson: bf16 Q
// shifts exp(q·k) by ~4% -> absmax 0.04 > threshold; score path needs fp32). ----
__global__ void __launch_bounds__(256) k_qkv(const uint32* __restrict__ embb,
    const uint32* __restrict__ Wbg, float* __restrict__ Q, uint32* __restrict__ KVb) {
  __shared__ float scr[4][2][16][68];  // [wave][K/V][node][dim(+pad)] = 34816 B
  int t = threadIdx.x;
  int wave = t >> 6, lane = t & 63;
  int tile = blockIdx.x * 4 + wave;
  if (tile >= NTILE) return;
  int c = lane & 15, quad = lane >> 4;
  int nodeBase = tile * 16;
  const uint32* arow = embb + (nodeBase + c) * 32 + quad * 4;
  uint4 a0u = *(const uint4*)arow;          // dims quad*8 .. +7
  uint4 a1u = *(const uint4*)(arow + 16);   // dims 32+quad*8 .. +7
  short8 a0 = *(short8*)&a0u;
  short8 a1 = *(short8*)&a1u;
  float (*SK)[68] = scr[wave][0];
  float (*SV)[68] = scr[wave][1];
  const uint32* wbase = Wbg + c * 32 + quad * 4;
  #pragma unroll
  for (int mat = 0; mat < 3; ++mat) {
    f32x4 acc[4];
    #pragma unroll
    for (int nt = 0; nt < 4; ++nt) acc[nt] = (f32x4){0.f, 0.f, 0.f, 0.f};
    const uint32* wb = wbase + mat * 2048;
    #pragma unroll
    for (int nt = 0; nt < 4; ++nt) {
      uint4 b0u = *(const uint4*)(wb + nt * 512);        // kh=0
      uint4 b1u = *(const uint4*)(wb + nt * 512 + 16);   // kh=1
      short8 b0 = *(short8*)&b0u;
      short8 b1 = *(short8*)&b1u;
      acc[nt] = __builtin_amdgcn_mfma_f32_16x16x32_bf16(a0, b0, acc[nt], 0, 0, 0);
      acc[nt] = __builtin_amdgcn_mfma_f32_16x16x32_bf16(a1, b1, acc[nt], 0, 0, 0);
    }
    float (*S)[68] = (mat == 2) ? SV : SK;   // Q and K reuse SK
    #pragma unroll
    for (int nt = 0; nt < 4; ++nt)
      #pragma unroll
      for (int r = 0; r < 4; ++r)
        S[quad * 4 + r][nt * 16 + c] = acc[nt][r];
    if (mat == 0) {
      #pragma unroll
      for (int i = 0; i < 4; ++i) {
        int node = i * 4 + quad;
        f32x4 q4 = *(f32x4*)&SK[node][c * 4];
        *(f32x4*)&Q[(nodeBase + node) * 64 + c * 4] = q4;
      }
    } else if (mat == 2) {
      #pragma unroll
      for (int i = 0; i < 4; ++i) {
        int node = i * 4 + quad;
        f32x4 K4 = *(f32x4*)&SK[node][c * 4];
        f32x4 V4 = *(f32x4*)&SV[node][c * 4];
        uint4 o;
        o.x = pack2bf(K4[0], K4[1]);
        o.y = pack2bf(K4[2], K4[3]);
        o.z = pack2bf(V4[0], V4[1]);
        o.w = pack2bf(V4[2], V4[3]);
        *(uint4*)&KVb[(nodeBase + node) * 64 + c * 4] = o;
      }
    }
  }
}

// ---- GT layer: wave = node; 4 edge-slots x 16 lanes. Unguarded main loop
// (all 4 slots valid: no cndmask chains, no zero-fill) + one guarded tail. ----
__global__ void __launch_bounds__(256) k_gt(const float* __restrict__ Q,
    const uint32* __restrict__ KVb, const int* __restrict__ row_ptr,
    const uint2* __restrict__ epack, uint32* __restrict__ embb_out) {
  int t = threadIdx.x;
  int n = blockIdx.x * 4 + (t >> 6);
  if (n >= NTOT) return;
  int lane = t & 63;
  int es = lane >> 4;
  int dl = lane & 15;
  float4 q4 = *(const float4*)&Q[n * 64 + dl * 4];
  int s     = __builtin_amdgcn_readfirstlane(row_ptr[n]);
  int e_end = __builtin_amdgcn_readfirstlane(row_ptr[n + 1]);
  int cnt = e_end - s;
  int li = s + lane;
  int cv = (int)epack[li < NEDGE ? li : NEDGE - 1].x;
  float den = 0.f;
  float4 acc = make_float4(0.f, 0.f, 0.f, 0.f);
  int base = 0;
  for (; base + 4 <= cnt; base += 4) {      // unguarded: all slots valid
    int i = base + es;
    int cc;
    if (base < 64) cc = __shfl(cv, i & 63);  // i <= 63 here (base <= 60)
    else           cc = (int)epack[s + i].x;
    uint4 w = *(const uint4*)&KVb[cc * 64 + dl * 4];
    float x = q4.x * bf_lo(w.x) + q4.y * bf_hi(w.x)
            + q4.z * bf_lo(w.y) + q4.w * bf_hi(w.y);
    x += __shfl_xor(x, 1);
    x += __shfl_xor(x, 2);
    x = fminf(fmaxf(x, -10.f), 10.f);
    float ex = __expf(x);
    den += ex;
    acc.x = fmaf(ex, bf_lo(w.z), acc.x);
    acc.y = fmaf(ex, bf_hi(w.z), acc.y);
    acc.z = fmaf(ex, bf_lo(w.w), acc.z);
    acc.w = fmaf(ex, bf_hi(w.w), acc.w);
  }
  if (base < cnt) {                          // guarded tail (1-3 live slots)
    int i = base + es;
    int cc;
    if (base < 64) cc = __shfl(cv, i & 63);
    else           cc = (i < cnt) ? (int)epack[s + i].x : 0;
    float ex = 0.f;
    float4 v4 = make_float4(0.f, 0.f, 0.f, 0.f);
    if (i < cnt) {
      uint4 w = *(const uint4*)&KVb[cc * 64 + dl * 4];
      float x = q4.x * bf_lo(w.x) + q4.y * bf_hi(w.x)
              + q4.z * bf_lo(w.y) + q4.w * bf_hi(w.y);
      v4.x = bf_lo(w.z); v4.y = bf_hi(w.z);
      v4.z = bf_lo(w.w); v4.w = bf_hi(w.w);
      x += __shfl_xor(x, 1);
      x += __shfl_xor(x, 2);
      x = fminf(fmaxf(x, -10.f), 10.f);
      ex = __expf(x);
    } else {
      float x = 0.f;
      x += __shfl_xor(x, 1);   // keep shuffle pattern wave-uniform
      x += __shfl_xor(x, 2);
    }
    den += ex;
    acc.x = fmaf(ex, v4.x, acc.x);
    acc.y = fmaf(ex, v4.y, acc.y);
    acc.z = fmaf(ex, v4.z, acc.z);
    acc.w = fmaf(ex, v4.w, acc.w);
  }
  #pragma unroll
  for (int off = 16; off <= 32; off <<= 1) {
    den  += __shfl_xor(den, off);
    acc.x += __shfl_xor(acc.x, off);
    acc.y += __shfl_xor(acc.y, off);
    acc.z += __shfl_xor(acc.z, off);
    acc.w += __shfl_xor(acc.w, off);
  }
  float inv = 1.f / (den + 1e-8f);
  if (es == 0) {
    uint2 pk;
    pk.x = pack2bf(acc.x * inv, acc.y * inv);
    pk.y = pack2bf(acc.z * inv, acc.w * inv);
    *(uint2*)&embb_out[n * 32 + dl * 2] = pk;
  }
}

// ---- GCN layer (spmm): wave per node, lane = dim, 8-wide body split into
// unguarded main loop + one guarded tail. bf16 ushort gather (128 B/edge).
// FINAL=0: writes bf16 out only. FINAL=1: fused 5-term final sum. ----
template<int FINAL>
__global__ void __launch_bounds__(256) k_gcn(const bf16u* __restrict__ src,
    const int* __restrict__ row_ptr, const uint2* __restrict__ epack,
    bf16u* __restrict__ embb_out, float* __restrict__ out,
    const float* __restrict__ ue, const float* __restrict__ ie,
    const bf16u* __restrict__ add1, const bf16u* __restrict__ add2) {
  int t = threadIdx.x;
  int n = blockIdx.x * 4 + (t >> 6);
  if (n >= NTOT) return;
  int lane = t & 63;
  int s     = __builtin_amdgcn_readfirstlane(row_ptr[n]);
  int e_end = __builtin_amdgcn_readfirstlane(row_ptr[n + 1]);
  int base = n * 64 + lane;
  // FINAL: issue the coalesced stream loads early; they drain under the gathers.
  float sum_extra = 0.f;
  if (FINAL) {
    float b = (n < NUSERS) ? ue[base] : ie[base - NUSERS * 64];
    float t1 = bf2f(add1[base]);
    float t2 = bf2f(add2[base]);
    float t3 = bf2f(src[base]);     // GCN1's own row (same buffer we gather)
    sum_extra = (b + t1) + (t2 + t3);
  }
  float a[8];
  #pragma unroll
  for (int j = 0; j < 8; ++j) a[j] = 0.f;
  int p = s;
  for (; p + 8 <= e_end; p += 8) {           // unguarded: all 8 slots valid
    #pragma unroll
    for (int j = 0; j < 8; ++j) {
      uint2 ev = epack[p + j];
      a[j] = fmaf(__uint_as_float(ev.y), bf2f(src[(int)ev.x * 64 + lane]), a[j]);
    }
  }
  if (p < e_end) {                           // guarded tail (1-7 live slots)
    #pragma unroll
    for (int j = 0; j < 8; ++j) {
      int pj = p + j;
      int pc = (pj < e_end) ? pj : s;        // clamp: dead slots re-hit edge s (L1)
      uint2 ev = epack[pc];
      float w = (pj < e_end) ? __uint_as_float(ev.y) : 0.f;
      a[j] = fmaf(w, bf2f(src[(int)ev.x * 64 + lane]), a[j]);
    }
  }
  float acc = ((a[0] + a[1]) + (a[2] + a[3])) + ((a[4] + a[5]) + (a[6] + a[7]));
  if (FINAL) {
    out[base] = acc + sum_extra;
  } else {
    embb_out[base] = f2bf(acc);
  }
}

extern "C" void kernel_launch(void* const* d_in, const int* in_sizes, int n_in,
                              void* d_out, int out_size, void* d_ws, size_t ws_size,
                              hipStream_t stream) {
  const int*   rows = (const int*)d_in[0];
  const int*   cols = (const int*)d_in[1];
  const float* vals = (const float*)d_in[2];
  const float* ue   = (const float*)d_in[3];
  const float* ie   = (const float*)d_in[4];
  const float* Wq   = (const float*)d_in[5];
  const float* Wk   = (const float*)d_in[6];
  const float* Wv   = (const float*)d_in[7];
  float* out = (float*)d_out;

  char* p = (char*)d_ws;
  auto alloc = [&](size_t b) { char* r = p; p += (b + 255) & ~(size_t)255; return (void*)r; };
  int*   cnt     = (int*)alloc((size_t)NTOT * 4);
  int*   row_ptr = (int*)alloc((size_t)(NTOT + 1) * 4);
  int*   rank    = (int*)alloc((size_t)NEDGE * 4);
  int*   bsums   = (int*)alloc(128 * 4);
  int*   boffs   = (int*)alloc(128 * 4);
  uint2* epack   = (uint2*)alloc((size_t)NEDGE * 8);     // {col, val bits}
  uint32* Wbg  = (uint32*)alloc((size_t)12288 * 4);
  float*  Q    = (float*)alloc((size_t)NTOT * 64 * 4);   // fp32 Q (256 B/node)
  uint32* KVb  = (uint32*)alloc((size_t)NTOT * 64 * 4);  // 256 B/node packed K|V
  uint32* B0   = (uint32*)alloc((size_t)NTOT * 32 * 4);  // bf16 rows == ushort[n][64]
  uint32* B1   = (uint32*)alloc((size_t)NTOT * 32 * 4);  // GT1 out
  uint32* B2   = (uint32*)alloc((size_t)NTOT * 32 * 4);  // GT2 out
  uint32* B3   = (uint32*)alloc((size_t)NTOT * 32 * 4);  // GCN1 out

  hipMemsetAsync(cnt, 0, (size_t)NTOT * 4, stream);
  // fused init + wpack + hist
  k_combo<<<13330, 256, 0, stream>>>(ue, ie, B0, Wq, Wk, Wv, Wbg, rows, cnt, rank);
  int nblk = (NTOT + 2047) / 2048;  // 74
  k_scan1<<<nblk, 256, 0, stream>>>(cnt, row_ptr, bsums);
  k_scan2<<<1, 128, 0, stream>>>(bsums, boffs, nblk);
  k_scan3<<<(NTOT + 255) / 256, 256, 0, stream>>>(row_ptr, boffs);
  k_fill<<<(NEDGE + 255) / 256, 256, 0, stream>>>(rows, cols, vals, rank, row_ptr, epack);

  // GT layer 1: B0 -> B1 (bf16 only)
  k_qkv<<<(NTILE + 3) / 4, 256, 0, stream>>>(B0, Wbg, Q, KVb);
  k_gt<<<(NTOT + 3) / 4, 256, 0, stream>>>(Q, KVb, row_ptr, epack, B1);
  // GT layer 2: B1 -> B2 (bf16 only)
  k_qkv<<<(NTILE + 3) / 4, 256, 0, stream>>>(B1, Wbg + 6144, Q, KVb);
  k_gt<<<(NTOT + 3) / 4, 256, 0, stream>>>(Q, KVb, row_ptr, epack, B2);
  // GCN1: gather B2 -> B3 (bf16 only)
  k_gcn<0><<<(NTOT + 3) / 4, 256, 0, stream>>>((const bf16u*)B2, row_ptr, epack,
                                               (bf16u*)B3, nullptr,
                                               nullptr, nullptr, nullptr, nullptr);
  // GCN2 + fused final sum: gather B3; out = cat(ue,ie)+B1+B2+B3+own
  k_gcn<1><<<(NTOT + 3) / 4, 256, 0, stream>>>((const bf16u*)B3, row_ptr, epack,
                                               nullptr, out,
                                               ue, ie, (const bf16u*)B1, (const bf16u*)B2);
}

// Round 8
// 437.745 us; speedup vs baseline: 1.3078x; 1.0049x over previous
//
#include <hip/hip_runtime.h>

#define NUSERS 100000
#define NITEMS 50000
#define NTOT   150000
#define NEDGE  1000000
#define NTILE  9375   // NTOT / 16
#define NE4    250000 // NEDGE / 4

typedef unsigned int uint32;
typedef unsigned short bf16u;
typedef __attribute__((ext_vector_type(8))) short short8;
typedef __attribute__((ext_vector_type(4))) float f32x4;

__device__ __forceinline__ unsigned short f2bf(float f) {
  unsigned int u = __float_as_uint(f);
  u += 0x7FFFu + ((u >> 16) & 1u);   // round-to-nearest-even
  return (unsigned short)(u >> 16);
}
__device__ __forceinline__ uint32 pack2bf(float a, float b) {
  return (uint32)f2bf(a) | ((uint32)f2bf(b) << 16);
}
__device__ __forceinline__ float bf_lo(uint32 u) { return __uint_as_float(u << 16); }
__device__ __forceinline__ float bf_hi(uint32 u) { return __uint_as_float(u & 0xFFFF0000u); }
__device__ __forceinline__ float bf2f(bf16u v) { return __uint_as_float((uint32)v << 16); }

// ---- combo setup: [0,9375) init embb0; [9375,9423) wpack; [9423,10400) hist ----
// hist: 4 edges/thread -> 4 independent atomic round-trips in flight per lane
// (the single-atomic version was pure latency: VALUBusy 2.4%, 60 us).
__global__ void k_combo(const float* __restrict__ ue, const float* __restrict__ ie,
                        uint32* __restrict__ embb,
                        const float* __restrict__ Wq, const float* __restrict__ Wk,
                        const float* __restrict__ Wv, uint32* __restrict__ Wbg,
                        const int* __restrict__ rows, int* __restrict__ cnt,
                        int* __restrict__ rank) {
  int b = blockIdx.x, t = threadIdx.x;
  if (b < 9375) {            // init: 9375*256 == NTOT*16 exactly
    int i = b * 256 + t;     // float4 index
    float4 v = (i < NUSERS * 16) ? ((const float4*)ue)[i]
                                 : ((const float4*)ie)[i - NUSERS * 16];
    uint2 pk;
    pk.x = pack2bf(v.x, v.y);
    pk.y = pack2bf(v.z, v.w);
    ((uint2*)embb)[i] = pk;
  } else if (b < 9423) {     // wpack: 48*256 == 12288 exactly
    int i = (b - 9375) * 256 + t;
    int l = i / 6144, rem = i % 6144, mat = rem / 2048, j = rem % 2048;
    int n = j >> 5, k2 = j & 31;
    const float* W = (mat == 0 ? Wq : mat == 1 ? Wk : Wv) + l * 4096;
    Wbg[i] = pack2bf(W[k2 * 128 + n], W[k2 * 128 + 64 + n]);
  } else {                   // hist: 4 edges/thread, NEDGE % 4 == 0
    int q = (b - 9423) * 256 + t;
    if (q < NE4) {
      int4 r4 = ((const int4*)rows)[q];
      int4 k4;
      k4.x = atomicAdd(&cnt[r4.x], 1);
      k4.y = atomicAdd(&cnt[r4.y], 1);
      k4.z = atomicAdd(&cnt[r4.z], 1);
      k4.w = atomicAdd(&cnt[r4.w], 1);
      ((int4*)rank)[q] = k4;
    }
  }
}

__global__ void k_scan1(const int* __restrict__ cnt, int* __restrict__ partial,
                        int* __restrict__ blocksums) {
  __shared__ int s[256];
  int t = threadIdx.x, b = blockIdx.x;
  int base = b * 2048 + t * 8;
  int pre[8]; int sum = 0;
  #pragma unroll
  for (int j = 0; j < 8; ++j) {
    int idx = base + j;
    int x = (idx < NTOT) ? cnt[idx] : 0;
    pre[j] = sum; sum += x;
  }
  s[t] = sum; __syncthreads();
  for (int off = 1; off < 256; off <<= 1) {
    int x = (t >= off) ? s[t - off] : 0;
    __syncthreads(); s[t] += x; __syncthreads();
  }
  int excl = s[t] - sum;
  #pragma unroll
  for (int j = 0; j < 8; ++j) {
    int idx = base + j;
    if (idx < NTOT) partial[idx] = excl + pre[j];
  }
  if (t == 255) blocksums[b] = s[255];
}

__global__ void k_scan2(const int* __restrict__ blocksums, int* __restrict__ blockoffs, int nblk) {
  __shared__ int s[128];
  int t = threadIdx.x;
  int x = (t < nblk) ? blocksums[t] : 0;
  s[t] = x; __syncthreads();
  for (int off = 1; off < 128; off <<= 1) {
    int y = (t >= off) ? s[t - off] : 0;
    __syncthreads(); s[t] += y; __syncthreads();
  }
  if (t < nblk) blockoffs[t] = s[t] - x;
}

__global__ void k_scan3(int* __restrict__ row_ptr, const int* __restrict__ blockoffs) {
  int i = blockIdx.x * 256 + threadIdx.x;
  if (i < NTOT) row_ptr[i] += blockoffs[i >> 11];
  if (i == 0) row_ptr[NTOT] = NEDGE;
}

// ---- fill: 4 edges/thread, coalesced int4/float4 metadata loads, 4
// independent scattered 8 B stores in flight; no atomic on the address path ----
__global__ void k_fill(const int* __restrict__ rows, const int* __restrict__ cols,
                       const float* __restrict__ vals, const int* __restrict__ rank,
                       const int* __restrict__ row_ptr, uint2* __restrict__ epack) {
  int q = blockIdx.x * 256 + threadIdx.x;
  if (q >= NE4) return;
  int4   r4 = ((const int4*)rows)[q];
  int4   k4 = ((const int4*)rank)[q];
  int4   c4 = ((const int4*)cols)[q];
  float4 v4 = ((const float4*)vals)[q];
  uint2 pk;
  pk.x = (uint32)c4.x; pk.y = __float_as_uint(v4.x);
  epack[row_ptr[r4.x] + k4.x] = pk;
  pk.x = (uint32)c4.y; pk.y = __float_as_uint(v4.y);
  epack[row_ptr[r4.y] + k4.y] = pk;
  pk.x = (uint32)c4.z; pk.y = __float_as_uint(v4.z);
  epack[row_ptr[r4.z] + k4.z] = pk;
  pk.x = (uint32)c4.w; pk.y = __float_as_uint(v4.w);
  epack[row_ptr[r4.w] + k4.w] = pk;
}

// ---- QKV: MFMA. wave = 16-node tile. Q stays fp32 (R6 lesson: bf16 Q
// shifts exp(q·k) by ~4% -> absmax 0.04 > threshold; score path needs fp32). ----
__global__ void __launch_bounds__(256) k_qkv(const uint32* __restrict__ embb,
    const uint32* __restrict__ Wbg, float* __restrict__ Q, uint32* __restrict__ KVb) {
  __shared__ float scr[4][2][16][68];  // [wave][K/V][node][dim(+pad)] = 34816 B
  int t = threadIdx.x;
  int wave = t >> 6, lane = t & 63;
  int tile = blockIdx.x * 4 + wave;
  if (tile >= NTILE) return;
  int c = lane & 15, quad = lane >> 4;
  int nodeBase = tile * 16;
  const uint32* arow = embb + (nodeBase + c) * 32 + quad * 4;
  uint4 a0u = *(const uint4*)arow;          // dims quad*8 .. +7
  uint4 a1u = *(const uint4*)(arow + 16);   // dims 32+quad*8 .. +7
  short8 a0 = *(short8*)&a0u;
  short8 a1 = *(short8*)&a1u;
  float (*SK)[68] = scr[wave][0];
  float (*SV)[68] = scr[wave][1];
  const uint32* wbase = Wbg + c * 32 + quad * 4;
  #pragma unroll
  for (int mat = 0; mat < 3; ++mat) {
    f32x4 acc[4];
    #pragma unroll
    for (int nt = 0; nt < 4; ++nt) acc[nt] = (f32x4){0.f, 0.f, 0.f, 0.f};
    const uint32* wb = wbase + mat * 2048;
    #pragma unroll
    for (int nt = 0; nt < 4; ++nt) {
      uint4 b0u = *(const uint4*)(wb + nt * 512);        // kh=0
      uint4 b1u = *(const uint4*)(wb + nt * 512 + 16);   // kh=1
      short8 b0 = *(short8*)&b0u;
      short8 b1 = *(short8*)&b1u;
      acc[nt] = __builtin_amdgcn_mfma_f32_16x16x32_bf16(a0, b0, acc[nt], 0, 0, 0);
      acc[nt] = __builtin_amdgcn_mfma_f32_16x16x32_bf16(a1, b1, acc[nt], 0, 0, 0);
    }
    float (*S)[68] = (mat == 2) ? SV : SK;   // Q and K reuse SK
    #pragma unroll
    for (int nt = 0; nt < 4; ++nt)
      #pragma unroll
      for (int r = 0; r < 4; ++r)
        S[quad * 4 + r][nt * 16 + c] = acc[nt][r];
    if (mat == 0) {
      #pragma unroll
      for (int i = 0; i < 4; ++i) {
        int node = i * 4 + quad;
        f32x4 q4 = *(f32x4*)&SK[node][c * 4];
        *(f32x4*)&Q[(nodeBase + node) * 64 + c * 4] = q4;
      }
    } else if (mat == 2) {
      #pragma unroll
      for (int i = 0; i < 4; ++i) {
        int node = i * 4 + quad;
        f32x4 K4 = *(f32x4*)&SK[node][c * 4];
        f32x4 V4 = *(f32x4*)&SV[node][c * 4];
        uint4 o;
        o.x = pack2bf(K4[0], K4[1]);
        o.y = pack2bf(K4[2], K4[3]);
        o.z = pack2bf(V4[0], V4[1]);
        o.w = pack2bf(V4[2], V4[3]);
        *(uint4*)&KVb[(nodeBase + node) * 64 + c * 4] = o;
      }
    }
  }
}

// ---- GT layer: wave = node; 4 edge-slots x 16 lanes. Unguarded main loop
// (all 4 slots valid: no cndmask chains, no zero-fill) + one guarded tail. ----
__global__ void __launch_bounds__(256) k_gt(const float* __restrict__ Q,
    const uint32* __restrict__ KVb, const int* __restrict__ row_ptr,
    const uint2* __restrict__ epack, uint32* __restrict__ embb_out) {
  int t = threadIdx.x;
  int n = blockIdx.x * 4 + (t >> 6);
  if (n >= NTOT) return;
  int lane = t & 63;
  int es = lane >> 4;
  int dl = lane & 15;
  float4 q4 = *(const float4*)&Q[n * 64 + dl * 4];
  int s     = __builtin_amdgcn_readfirstlane(row_ptr[n]);
  int e_end = __builtin_amdgcn_readfirstlane(row_ptr[n + 1]);
  int cnt = e_end - s;
  int li = s + lane;
  int cv = (int)epack[li < NEDGE ? li : NEDGE - 1].x;
  float den = 0.f;
  float4 acc = make_float4(0.f, 0.f, 0.f, 0.f);
  int base = 0;
  for (; base + 4 <= cnt; base += 4) {      // unguarded: all slots valid
    int i = base + es;
    int cc;
    if (base < 64) cc = __shfl(cv, i & 63);  // i <= 63 here (base <= 60)
    else           cc = (int)epack[s + i].x;
    uint4 w = *(const uint4*)&KVb[cc * 64 + dl * 4];
    float x = q4.x * bf_lo(w.x) + q4.y * bf_hi(w.x)
            + q4.z * bf_lo(w.y) + q4.w * bf_hi(w.y);
    x += __shfl_xor(x, 1);
    x += __shfl_xor(x, 2);
    x = fminf(fmaxf(x, -10.f), 10.f);
    float ex = __expf(x);
    den += ex;
    acc.x = fmaf(ex, bf_lo(w.z), acc.x);
    acc.y = fmaf(ex, bf_hi(w.z), acc.y);
    acc.z = fmaf(ex, bf_lo(w.w), acc.z);
    acc.w = fmaf(ex, bf_hi(w.w), acc.w);
  }
  if (base < cnt) {                          // guarded tail (1-3 live slots)
    int i = base + es;
    int cc;
    if (base < 64) cc = __shfl(cv, i & 63);
    else           cc = (i < cnt) ? (int)epack[s + i].x : 0;
    float ex = 0.f;
    float4 v4 = make_float4(0.f, 0.f, 0.f, 0.f);
    if (i < cnt) {
      uint4 w = *(const uint4*)&KVb[cc * 64 + dl * 4];
      float x = q4.x * bf_lo(w.x) + q4.y * bf_hi(w.x)
              + q4.z * bf_lo(w.y) + q4.w * bf_hi(w.y);
      v4.x = bf_lo(w.z); v4.y = bf_hi(w.z);
      v4.z = bf_lo(w.w); v4.w = bf_hi(w.w);
      x += __shfl_xor(x, 1);
      x += __shfl_xor(x, 2);
      x = fminf(fmaxf(x, -10.f), 10.f);
      ex = __expf(x);
    } else {
      float x = 0.f;
      x += __shfl_xor(x, 1);   // keep shuffle pattern wave-uniform
      x += __shfl_xor(x, 2);
    }
    den += ex;
    acc.x = fmaf(ex, v4.x, acc.x);
    acc.y = fmaf(ex, v4.y, acc.y);
    acc.z = fmaf(ex, v4.z, acc.z);
    acc.w = fmaf(ex, v4.w, acc.w);
  }
  #pragma unroll
  for (int off = 16; off <= 32; off <<= 1) {
    den  += __shfl_xor(den, off);
    acc.x += __shfl_xor(acc.x, off);
    acc.y += __shfl_xor(acc.y, off);
    acc.z += __shfl_xor(acc.z, off);
    acc.w += __shfl_xor(acc.w, off);
  }
  float inv = 1.f / (den + 1e-8f);
  if (es == 0) {
    uint2 pk;
    pk.x = pack2bf(acc.x * inv, acc.y * inv);
    pk.y = pack2bf(acc.z * inv, acc.w * inv);
    *(uint2*)&embb_out[n * 32 + dl * 2] = pk;
  }
}

// ---- GCN layer (spmm): wave per node, lane = dim, 8-wide body split into
// unguarded main loop + one guarded tail. bf16 ushort gather (128 B/edge).
// FINAL=0: writes bf16 out only. FINAL=1: fused 5-term final sum. ----
template<int FINAL>
__global__ void __launch_bounds__(256) k_gcn(const bf16u* __restrict__ src,
    const int* __restrict__ row_ptr, const uint2* __restrict__ epack,
    bf16u* __restrict__ embb_out, float* __restrict__ out,
    const float* __restrict__ ue, const float* __restrict__ ie,
    const bf16u* __restrict__ add1, const bf16u* __restrict__ add2) {
  int t = threadIdx.x;
  int n = blockIdx.x * 4 + (t >> 6);
  if (n >= NTOT) return;
  int lane = t & 63;
  int s     = __builtin_amdgcn_readfirstlane(row_ptr[n]);
  int e_end = __builtin_amdgcn_readfirstlane(row_ptr[n + 1]);
  int base = n * 64 + lane;
  // FINAL: issue the coalesced stream loads early; they drain under the gathers.
  float sum_extra = 0.f;
  if (FINAL) {
    float b = (n < NUSERS) ? ue[base] : ie[base - NUSERS * 64];
    float t1 = bf2f(add1[base]);
    float t2 = bf2f(add2[base]);
    float t3 = bf2f(src[base]);     // GCN1's own row (same buffer we gather)
    sum_extra = (b + t1) + (t2 + t3);
  }
  float a[8];
  #pragma unroll
  for (int j = 0; j < 8; ++j) a[j] = 0.f;
  int p = s;
  for (; p + 8 <= e_end; p += 8) {           // unguarded: all 8 slots valid
    #pragma unroll
    for (int j = 0; j < 8; ++j) {
      uint2 ev = epack[p + j];
      a[j] = fmaf(__uint_as_float(ev.y), bf2f(src[(int)ev.x * 64 + lane]), a[j]);
    }
  }
  if (p < e_end) {                           // guarded tail (1-7 live slots)
    #pragma unroll
    for (int j = 0; j < 8; ++j) {
      int pj = p + j;
      int pc = (pj < e_end) ? pj : s;        // clamp: dead slots re-hit edge s (L1)
      uint2 ev = epack[pc];
      float w = (pj < e_end) ? __uint_as_float(ev.y) : 0.f;
      a[j] = fmaf(w, bf2f(src[(int)ev.x * 64 + lane]), a[j]);
    }
  }
  float acc = ((a[0] + a[1]) + (a[2] + a[3])) + ((a[4] + a[5]) + (a[6] + a[7]));
  if (FINAL) {
    out[base] = acc + sum_extra;
  } else {
    embb_out[base] = f2bf(acc);
  }
}

extern "C" void kernel_launch(void* const* d_in, const int* in_sizes, int n_in,
                              void* d_out, int out_size, void* d_ws, size_t ws_size,
                              hipStream_t stream) {
  const int*   rows = (const int*)d_in[0];
  const int*   cols = (const int*)d_in[1];
  const float* vals = (const float*)d_in[2];
  const float* ue   = (const float*)d_in[3];
  const float* ie   = (const float*)d_in[4];
  const float* Wq   = (const float*)d_in[5];
  const float* Wk   = (const float*)d_in[6];
  const float* Wv   = (const float*)d_in[7];
  float* out = (float*)d_out;

  char* p = (char*)d_ws;
  auto alloc = [&](size_t b) { char* r = p; p += (b + 255) & ~(size_t)255; return (void*)r; };
  int*   cnt     = (int*)alloc((size_t)NTOT * 4);
  int*   row_ptr = (int*)alloc((size_t)(NTOT + 1) * 4);
  int*   rank    = (int*)alloc((size_t)NEDGE * 4);
  int*   bsums   = (int*)alloc(128 * 4);
  int*   boffs   = (int*)alloc(128 * 4);
  uint2* epack   = (uint2*)alloc((size_t)NEDGE * 8);     // {col, val bits}
  uint32* Wbg  = (uint32*)alloc((size_t)12288 * 4);
  float*  Q    = (float*)alloc((size_t)NTOT * 64 * 4);   // fp32 Q (256 B/node)
  uint32* KVb  = (uint32*)alloc((size_t)NTOT * 64 * 4);  // 256 B/node packed K|V
  uint32* B0   = (uint32*)alloc((size_t)NTOT * 32 * 4);  // bf16 rows == ushort[n][64]
  uint32* B1   = (uint32*)alloc((size_t)NTOT * 32 * 4);  // GT1 out
  uint32* B2   = (uint32*)alloc((size_t)NTOT * 32 * 4);  // GT2 out
  uint32* B3   = (uint32*)alloc((size_t)NTOT * 32 * 4);  // GCN1 out

  hipMemsetAsync(cnt, 0, (size_t)NTOT * 4, stream);
  // fused init + wpack + hist(4 edges/thread): 9375 + 48 + 977 blocks
  k_combo<<<10400, 256, 0, stream>>>(ue, ie, B0, Wq, Wk, Wv, Wbg, rows, cnt, rank);
  int nblk = (NTOT + 2047) / 2048;  // 74
  k_scan1<<<nblk, 256, 0, stream>>>(cnt, row_ptr, bsums);
  k_scan2<<<1, 128, 0, stream>>>(bsums, boffs, nblk);
  k_scan3<<<(NTOT + 255) / 256, 256, 0, stream>>>(row_ptr, boffs);
  k_fill<<<(NE4 + 255) / 256, 256, 0, stream>>>(rows, cols, vals, rank, row_ptr, epack);

  // GT layer 1: B0 -> B1 (bf16 only)
  k_qkv<<<(NTILE + 3) / 4, 256, 0, stream>>>(B0, Wbg, Q, KVb);
  k_gt<<<(NTOT + 3) / 4, 256, 0, stream>>>(Q, KVb, row_ptr, epack, B1);
  // GT layer 2: B1 -> B2 (bf16 only)
  k_qkv<<<(NTILE + 3) / 4, 256, 0, stream>>>(B1, Wbg + 6144, Q, KVb);
  k_gt<<<(NTOT + 3) / 4, 256, 0, stream>>>(Q, KVb, row_ptr, epack, B2);
  // GCN1: gather B2 -> B3 (bf16 only)
  k_gcn<0><<<(NTOT + 3) / 4, 256, 0, stream>>>((const bf16u*)B2, row_ptr, epack,
                                               (bf16u*)B3, nullptr,
                                               nullptr, nullptr, nullptr, nullptr);
  // GCN2 + fused final sum: gather B3; out = cat(ue,ie)+B1+B2+B3+own
  k_gcn<1><<<(NTOT + 3) / 4, 256, 0, stream>>>((const bf16u*)B3, row_ptr, epack,
                                               nullptr, out,
                                               ue, ie, (const bf16u*)B1, (const bf16u*)B2);
}

// Round 10
// 431.834 us; speedup vs baseline: 1.3257x; 1.0137x over previous
//
#include <hip/hip_runtime.h>

#define NUSERS 100000
#define NITEMS 50000
#define NTOT   150000
#define NEDGE  1000000
#define NTILE  9375   // NTOT / 16
#define NE4    250000 // NEDGE / 4

typedef unsigned int uint32;
typedef unsigned short bf16u;
typedef __attribute__((ext_vector_type(8))) short short8;
typedef __attribute__((ext_vector_type(4))) float f32x4;

__device__ __forceinline__ unsigned short f2bf(float f) {
  unsigned int u = __float_as_uint(f);
  u += 0x7FFFu + ((u >> 16) & 1u);   // round-to-nearest-even
  return (unsigned short)(u >> 16);
}
__device__ __forceinline__ uint32 pack2bf(float a, float b) {
  return (uint32)f2bf(a) | ((uint32)f2bf(b) << 16);
}
__device__ __forceinline__ float bf_lo(uint32 u) { return __uint_as_float(u << 16); }
__device__ __forceinline__ float bf_hi(uint32 u) { return __uint_as_float(u & 0xFFFF0000u); }
__device__ __forceinline__ float bf2f(bf16u v) { return __uint_as_float((uint32)v << 16); }

// ---- combo setup: [0,9375) init embb0; [9375,9423) wpack; [9423,10400) hist ----
__global__ void k_combo(const float* __restrict__ ue, const float* __restrict__ ie,
                        uint32* __restrict__ embb,
                        const float* __restrict__ Wq, const float* __restrict__ Wk,
                        const float* __restrict__ Wv, uint32* __restrict__ Wbg,
                        const int* __restrict__ rows, int* __restrict__ cnt,
                        int* __restrict__ rank) {
  int b = blockIdx.x, t = threadIdx.x;
  if (b < 9375) {            // init: 9375*256 == NTOT*16 exactly
    int i = b * 256 + t;     // float4 index
    float4 v = (i < NUSERS * 16) ? ((const float4*)ue)[i]
                                 : ((const float4*)ie)[i - NUSERS * 16];
    uint2 pk;
    pk.x = pack2bf(v.x, v.y);
    pk.y = pack2bf(v.z, v.w);
    ((uint2*)embb)[i] = pk;
  } else if (b < 9423) {     // wpack: 48*256 == 12288 exactly
    int i = (b - 9375) * 256 + t;
    int l = i / 6144, rem = i % 6144, mat = rem / 2048, j = rem % 2048;
    int n = j >> 5, k2 = j & 31;
    const float* W = (mat == 0 ? Wq : mat == 1 ? Wk : Wv) + l * 4096;
    Wbg[i] = pack2bf(W[k2 * 128 + n], W[k2 * 128 + 64 + n]);
  } else {                   // hist: 4 edges/thread, 4 atomics in flight
    int q = (b - 9423) * 256 + t;
    if (q < NE4) {
      int4 r4 = ((const int4*)rows)[q];
      int4 k4;
      k4.x = atomicAdd(&cnt[r4.x], 1);
      k4.y = atomicAdd(&cnt[r4.y], 1);
      k4.z = atomicAdd(&cnt[r4.z], 1);
      k4.w = atomicAdd(&cnt[r4.w], 1);
      ((int4*)rank)[q] = k4;
    }
  }
}

__global__ void k_scan1(const int* __restrict__ cnt, int* __restrict__ partial,
                        int* __restrict__ blocksums) {
  __shared__ int s[256];
  int t = threadIdx.x, b = blockIdx.x;
  int base = b * 2048 + t * 8;
  int pre[8]; int sum = 0;
  #pragma unroll
  for (int j = 0; j < 8; ++j) {
    int idx = base + j;
    int x = (idx < NTOT) ? cnt[idx] : 0;
    pre[j] = sum; sum += x;
  }
  s[t] = sum; __syncthreads();
  for (int off = 1; off < 256; off <<= 1) {
    int x = (t >= off) ? s[t - off] : 0;
    __syncthreads(); s[t] += x; __syncthreads();
  }
  int excl = s[t] - sum;
  #pragma unroll
  for (int j = 0; j < 8; ++j) {
    int idx = base + j;
    if (idx < NTOT) partial[idx] = excl + pre[j];
  }
  if (t == 255) blocksums[b] = s[255];
}

__global__ void k_scan2(const int* __restrict__ blocksums, int* __restrict__ blockoffs, int nblk) {
  __shared__ int s[128];
  int t = threadIdx.x;
  int x = (t < nblk) ? blocksums[t] : 0;
  s[t] = x; __syncthreads();
  for (int off = 1; off < 128; off <<= 1) {
    int y = (t >= off) ? s[t - off] : 0;
    __syncthreads(); s[t] += y; __syncthreads();
  }
  if (t < nblk) blockoffs[t] = s[t] - x;
}

__global__ void k_scan3(int* __restrict__ row_ptr, const int* __restrict__ blockoffs) {
  int i = blockIdx.x * 256 + threadIdx.x;
  if (i < NTOT) row_ptr[i] += blockoffs[i >> 11];
  if (i == 0) row_ptr[NTOT] = NEDGE;
}

// ---- fill: 4 edges/thread, coalesced metadata loads, 4 scattered 8 B stores ----
__global__ void k_fill(const int* __restrict__ rows, const int* __restrict__ cols,
                       const float* __restrict__ vals, const int* __restrict__ rank,
                       const int* __restrict__ row_ptr, uint2* __restrict__ epack) {
  int q = blockIdx.x * 256 + threadIdx.x;
  if (q >= NE4) return;
  int4   r4 = ((const int4*)rows)[q];
  int4   k4 = ((const int4*)rank)[q];
  int4   c4 = ((const int4*)cols)[q];
  float4 v4 = ((const float4*)vals)[q];
  uint2 pk;
  pk.x = (uint32)c4.x; pk.y = __float_as_uint(v4.x);
  epack[row_ptr[r4.x] + k4.x] = pk;
  pk.x = (uint32)c4.y; pk.y = __float_as_uint(v4.y);
  epack[row_ptr[r4.y] + k4.y] = pk;
  pk.x = (uint32)c4.z; pk.y = __float_as_uint(v4.z);
  epack[row_ptr[r4.z] + k4.z] = pk;
  pk.x = (uint32)c4.w; pk.y = __float_as_uint(v4.w);
  epack[row_ptr[r4.w] + k4.w] = pk;
}

// ---- QKV: MFMA. wave = 16-node tile. Q stays fp32 (R6 lesson). ----
__global__ void __launch_bounds__(256) k_qkv(const uint32* __restrict__ embb,
    const uint32* __restrict__ Wbg, float* __restrict__ Q, uint32* __restrict__ KVb) {
  __shared__ float scr[4][2][16][68];  // [wave][K/V][node][dim(+pad)] = 34816 B
  int t = threadIdx.x;
  int wave = t >> 6, lane = t & 63;
  int tile = blockIdx.x * 4 + wave;
  if (tile >= NTILE) return;
  int c = lane & 15, quad = lane >> 4;
  int nodeBase = tile * 16;
  const uint32* arow = embb + (nodeBase + c) * 32 + quad * 4;
  uint4 a0u = *(const uint4*)arow;          // dims quad*8 .. +7
  uint4 a1u = *(const uint4*)(arow + 16);   // dims 32+quad*8 .. +7
  short8 a0 = *(short8*)&a0u;
  short8 a1 = *(short8*)&a1u;
  float (*SK)[68] = scr[wave][0];
  float (*SV)[68] = scr[wave][1];
  const uint32* wbase = Wbg + c * 32 + quad * 4;
  #pragma unroll
  for (int mat = 0; mat < 3; ++mat) {
    f32x4 acc[4];
    #pragma unroll
    for (int nt = 0; nt < 4; ++nt) acc[nt] = (f32x4){0.f, 0.f, 0.f, 0.f};
    const uint32* wb = wbase + mat * 2048;
    #pragma unroll
    for (int nt = 0; nt < 4; ++nt) {
      uint4 b0u = *(const uint4*)(wb + nt * 512);        // kh=0
      uint4 b1u = *(const uint4*)(wb + nt * 512 + 16);   // kh=1
      short8 b0 = *(short8*)&b0u;
      short8 b1 = *(short8*)&b1u;
      acc[nt] = __builtin_amdgcn_mfma_f32_16x16x32_bf16(a0, b0, acc[nt], 0, 0, 0);
      acc[nt] = __builtin_amdgcn_mfma_f32_16x16x32_bf16(a1, b1, acc[nt], 0, 0, 0);
    }
    float (*S)[68] = (mat == 2) ? SV : SK;   // Q and K reuse SK
    #pragma unroll
    for (int nt = 0; nt < 4; ++nt)
      #pragma unroll
      for (int r = 0; r < 4; ++r)
        S[quad * 4 + r][nt * 16 + c] = acc[nt][r];
    if (mat == 0) {
      #pragma unroll
      for (int i = 0; i < 4; ++i) {
        int node = i * 4 + quad;
        f32x4 q4 = *(f32x4*)&SK[node][c * 4];
        *(f32x4*)&Q[(nodeBase + node) * 64 + c * 4] = q4;
      }
    } else if (mat == 2) {
      #pragma unroll
      for (int i = 0; i < 4; ++i) {
        int node = i * 4 + quad;
        f32x4 K4 = *(f32x4*)&SK[node][c * 4];
        f32x4 V4 = *(f32x4*)&SV[node][c * 4];
        uint4 o;
        o.x = pack2bf(K4[0], K4[1]);
        o.y = pack2bf(K4[2], K4[3]);
        o.z = pack2bf(V4[0], V4[1]);
        o.w = pack2bf(V4[2], V4[3]);
        *(uint4*)&KVb[(nodeBase + node) * 64 + c * 4] = o;
      }
    }
  }
}

// ---- GT layer: R8-proven 4 edge-slots x 16 lanes, with the main loop
// manually unrolled x2 and BOTH rounds' KVb gathers issued before either is
// consumed (8 edges in flight for deg>=8 rows; halves serial gather rounds).
// Accumulation order A-then-B == two sequential iterations: bit-identical. ----
__global__ void __launch_bounds__(256) k_gt(const float* __restrict__ Q,
    const uint32* __restrict__ KVb, const int* __restrict__ row_ptr,
    const uint2* __restrict__ epack, uint32* __restrict__ embb_out) {
  int t = threadIdx.x;
  int n = blockIdx.x * 4 + (t >> 6);
  if (n >= NTOT) return;
  int lane = t & 63;
  int es = lane >> 4;
  int dl = lane & 15;
  float4 q4 = *(const float4*)&Q[n * 64 + dl * 4];
  int s     = __builtin_amdgcn_readfirstlane(row_ptr[n]);
  int e_end = __builtin_amdgcn_readfirstlane(row_ptr[n + 1]);
  int cnt = e_end - s;
  int li = s + lane;
  int cv = (int)epack[li < NEDGE ? li : NEDGE - 1].x;
  float den = 0.f;
  float4 acc = make_float4(0.f, 0.f, 0.f, 0.f);
  int base = 0;
  for (; base + 8 <= cnt; base += 8) {       // dual round: 8 gathers in flight
    int i0 = base + es, i1 = i0 + 4;
    int cc0, cc1;
    if (base < 57) {                         // i1 <= base+7 <= 63
      cc0 = __shfl(cv, i0 & 63);
      cc1 = __shfl(cv, i1 & 63);
    } else {
      cc0 = (int)epack[s + i0].x;
      cc1 = (int)epack[s + i1].x;
    }
    uint4 wA = *(const uint4*)&KVb[cc0 * 64 + dl * 4];
    uint4 wB = *(const uint4*)&KVb[cc1 * 64 + dl * 4];
    // round A (edges base..base+3)
    float xA = q4.x * bf_lo(wA.x) + q4.y * bf_hi(wA.x)
             + q4.z * bf_lo(wA.y) + q4.w * bf_hi(wA.y);
    xA += __shfl_xor(xA, 1);
    xA += __shfl_xor(xA, 2);
    xA = fminf(fmaxf(xA, -10.f), 10.f);
    float exA = __expf(xA);
    den += exA;
    acc.x = fmaf(exA, bf_lo(wA.z), acc.x);
    acc.y = fmaf(exA, bf_hi(wA.z), acc.y);
    acc.z = fmaf(exA, bf_lo(wA.w), acc.z);
    acc.w = fmaf(exA, bf_hi(wA.w), acc.w);
    // round B (edges base+4..base+7)
    float xB = q4.x * bf_lo(wB.x) + q4.y * bf_hi(wB.x)
             + q4.z * bf_lo(wB.y) + q4.w * bf_hi(wB.y);
    xB += __shfl_xor(xB, 1);
    xB += __shfl_xor(xB, 2);
    xB = fminf(fmaxf(xB, -10.f), 10.f);
    float exB = __expf(xB);
    den += exB;
    acc.x = fmaf(exB, bf_lo(wB.z), acc.x);
    acc.y = fmaf(exB, bf_hi(wB.z), acc.y);
    acc.z = fmaf(exB, bf_lo(wB.w), acc.z);
    acc.w = fmaf(exB, bf_hi(wB.w), acc.w);
  }
  for (; base + 4 <= cnt; base += 4) {      // single round (at most once)
    int i = base + es;
    int cc;
    if (base < 61) cc = __shfl(cv, i & 63);  // i <= base+3 <= 63
    else           cc = (int)epack[s + i].x;
    uint4 w = *(const uint4*)&KVb[cc * 64 + dl * 4];
    float x = q4.x * bf_lo(w.x) + q4.y * bf_hi(w.x)
            + q4.z * bf_lo(w.y) + q4.w * bf_hi(w.y);
    x += __shfl_xor(x, 1);
    x += __shfl_xor(x, 2);
    x = fminf(fmaxf(x, -10.f), 10.f);
    float ex = __expf(x);
    den += ex;
    acc.x = fmaf(ex, bf_lo(w.z), acc.x);
    acc.y = fmaf(ex, bf_hi(w.z), acc.y);
    acc.z = fmaf(ex, bf_lo(w.w), acc.z);
    acc.w = fmaf(ex, bf_hi(w.w), acc.w);
  }
  if (base < cnt) {                          // guarded tail (1-3 live slots)
    int i = base + es;
    int cc;
    if (base < 61) cc = __shfl(cv, i & 63);
    else           cc = (i < cnt) ? (int)epack[s + i].x : 0;
    float ex = 0.f;
    float4 v4 = make_float4(0.f, 0.f, 0.f, 0.f);
    if (i < cnt) {
      uint4 w = *(const uint4*)&KVb[cc * 64 + dl * 4];
      float x = q4.x * bf_lo(w.x) + q4.y * bf_hi(w.x)
              + q4.z * bf_lo(w.y) + q4.w * bf_hi(w.y);
      v4.x = bf_lo(w.z); v4.y = bf_hi(w.z);
      v4.z = bf_lo(w.w); v4.w = bf_hi(w.w);
      x += __shfl_xor(x, 1);
      x += __shfl_xor(x, 2);
      x = fminf(fmaxf(x, -10.f), 10.f);
      ex = __expf(x);
    } else {
      float x = 0.f;
      x += __shfl_xor(x, 1);   // keep shuffle pattern wave-uniform
      x += __shfl_xor(x, 2);
    }
    den += ex;
    acc.x = fmaf(ex, v4.x, acc.x);
    acc.y = fmaf(ex, v4.y, acc.y);
    acc.z = fmaf(ex, v4.z, acc.z);
    acc.w = fmaf(ex, v4.w, acc.w);
  }
  #pragma unroll
  for (int off = 16; off <= 32; off <<= 1) {
    den  += __shfl_xor(den, off);
    acc.x += __shfl_xor(acc.x, off);
    acc.y += __shfl_xor(acc.y, off);
    acc.z += __shfl_xor(acc.z, off);
    acc.w += __shfl_xor(acc.w, off);
  }
  float inv = 1.f / (den + 1e-8f);
  if (es == 0) {
    uint2 pk;
    pk.x = pack2bf(acc.x * inv, acc.y * inv);
    pk.y = pack2bf(acc.z * inv, acc.w * inv);
    *(uint2*)&embb_out[n * 32 + dl * 2] = pk;
  }
}

// ---- GCN layer (spmm): wave per node, lane = dim, 8-wide body split into
// unguarded main loop + one guarded tail. bf16 ushort gather (128 B/edge).
// FINAL=0: writes bf16 out only. FINAL=1: fused 5-term final sum. ----
template<int FINAL>
__global__ void __launch_bounds__(256) k_gcn(const bf16u* __restrict__ src,
    const int* __restrict__ row_ptr, const uint2* __restrict__ epack,
    bf16u* __restrict__ embb_out, float* __restrict__ out,
    const float* __restrict__ ue, const float* __restrict__ ie,
    const bf16u* __restrict__ add1, const bf16u* __restrict__ add2) {
  int t = threadIdx.x;
  int n = blockIdx.x * 4 + (t >> 6);
  if (n >= NTOT) return;
  int lane = t & 63;
  int s     = __builtin_amdgcn_readfirstlane(row_ptr[n]);
  int e_end = __builtin_amdgcn_readfirstlane(row_ptr[n + 1]);
  int base = n * 64 + lane;
  // FINAL: issue the coalesced stream loads early; they drain under the gathers.
  float sum_extra = 0.f;
  if (FINAL) {
    float b = (n < NUSERS) ? ue[base] : ie[base - NUSERS * 64];
    float t1 = bf2f(add1[base]);
    float t2 = bf2f(add2[base]);
    float t3 = bf2f(src[base]);     // GCN1's own row (same buffer we gather)
    sum_extra = (b + t1) + (t2 + t3);
  }
  float a[8];
  #pragma unroll
  for (int j = 0; j < 8; ++j) a[j] = 0.f;
  int p = s;
  for (; p + 8 <= e_end; p += 8) {           // unguarded: all 8 slots valid
    #pragma unroll
    for (int j = 0; j < 8; ++j) {
      uint2 ev = epack[p + j];
      a[j] = fmaf(__uint_as_float(ev.y), bf2f(src[(int)ev.x * 64 + lane]), a[j]);
    }
  }
  if (p < e_end) {                           // guarded tail (1-7 live slots)
    #pragma unroll
    for (int j = 0; j < 8; ++j) {
      int pj = p + j;
      int pc = (pj < e_end) ? pj : s;        // clamp: dead slots re-hit edge s (L1)
      uint2 ev = epack[pc];
      float w = (pj < e_end) ? __uint_as_float(ev.y) : 0.f;
      a[j] = fmaf(w, bf2f(src[(int)ev.x * 64 + lane]), a[j]);
    }
  }
  float acc = ((a[0] + a[1]) + (a[2] + a[3])) + ((a[4] + a[5]) + (a[6] + a[7]));
  if (FINAL) {
    out[base] = acc + sum_extra;
  } else {
    embb_out[base] = f2bf(acc);
  }
}

extern "C" void kernel_launch(void* const* d_in, const int* in_sizes, int n_in,
                              void* d_out, int out_size, void* d_ws, size_t ws_size,
                              hipStream_t stream) {
  const int*   rows = (const int*)d_in[0];
  const int*   cols = (const int*)d_in[1];
  const float* vals = (const float*)d_in[2];
  const float* ue   = (const float*)d_in[3];
  const float* ie   = (const float*)d_in[4];
  const float* Wq   = (const float*)d_in[5];
  const float* Wk   = (const float*)d_in[6];
  const float* Wv   = (const float*)d_in[7];
  float* out = (float*)d_out;

  char* p = (char*)d_ws;
  auto alloc = [&](size_t b) { char* r = p; p += (b + 255) & ~(size_t)255; return (void*)r; };
  int*   cnt     = (int*)alloc((size_t)NTOT * 4);
  int*   row_ptr = (int*)alloc((size_t)(NTOT + 1) * 4);
  int*   rank    = (int*)alloc((size_t)NEDGE * 4);
  int*   bsums   = (int*)alloc(128 * 4);
  int*   boffs   = (int*)alloc(128 * 4);
  uint2* epack   = (uint2*)alloc((size_t)NEDGE * 8);     // {col, val bits}
  uint32* Wbg  = (uint32*)alloc((size_t)12288 * 4);
  float*  Q    = (float*)alloc((size_t)NTOT * 64 * 4);   // fp32 Q (256 B/node)
  uint32* KVb  = (uint32*)alloc((size_t)NTOT * 64 * 4);  // 256 B/node packed K|V
  uint32* B0   = (uint32*)alloc((size_t)NTOT * 32 * 4);  // bf16 rows == ushort[n][64]
  uint32* B1   = (uint32*)alloc((size_t)NTOT * 32 * 4);  // GT1 out
  uint32* B2   = (uint32*)alloc((size_t)NTOT * 32 * 4);  // GT2 out
  uint32* B3   = (uint32*)alloc((size_t)NTOT * 32 * 4);  // GCN1 out

  hipMemsetAsync(cnt, 0, (size_t)NTOT * 4, stream);
  // fused init + wpack + hist(4 edges/thread): 9375 + 48 + 977 blocks
  k_combo<<<10400, 256, 0, stream>>>(ue, ie, B0, Wq, Wk, Wv, Wbg, rows, cnt, rank);
  int nblk = (NTOT + 2047) / 2048;  // 74
  k_scan1<<<nblk, 256, 0, stream>>>(cnt, row_ptr, bsums);
  k_scan2<<<1, 128, 0, stream>>>(bsums, boffs, nblk);
  k_scan3<<<(NTOT + 255) / 256, 256, 0, stream>>>(row_ptr, boffs);
  k_fill<<<(NE4 + 255) / 256, 256, 0, stream>>>(rows, cols, vals, rank, row_ptr, epack);

  // GT layer 1: B0 -> B1 (bf16 only)
  k_qkv<<<(NTILE + 3) / 4, 256, 0, stream>>>(B0, Wbg, Q, KVb);
  k_gt<<<(NTOT + 3) / 4, 256, 0, stream>>>(Q, KVb, row_ptr, epack, B1);
  // GT layer 2: B1 -> B2 (bf16 only)
  k_qkv<<<(NTILE + 3) / 4, 256, 0, stream>>>(B1, Wbg + 6144, Q, KVb);
  k_gt<<<(NTOT + 3) / 4, 256, 0, stream>>>(Q, KVb, row_ptr, epack, B2);
  // GCN1: gather B2 -> B3 (bf16 only)
  k_gcn<0><<<(NTOT + 3) / 4, 256, 0, stream>>>((const bf16u*)B2, row_ptr, epack,
                                               (bf16u*)B3, nullptr,
                                               nullptr, nullptr, nullptr, nullptr);
  // GCN2 + fused final sum: gather B3; out = cat(ue,ie)+B1+B2+B3+own
  k_gcn<1><<<(NTOT + 3) / 4, 256, 0, stream>>>((const bf16u*)B3, row_ptr, epack,
                                               nullptr, out,
                                               ue, ie, (const bf16u*)B1, (const bf16u*)B2);
}

// Round 12
// 430.672 us; speedup vs baseline: 1.3292x; 1.0027x over previous
//
#include <hip/hip_runtime.h>

#define NUSERS 100000
#define NITEMS 50000
#define NTOT   150000
#define NEDGE  1000000
#define NTILE  9375   // NTOT / 16
#define NE4    250000 // NEDGE / 4
#define NE8    125000 // NEDGE / 8

typedef unsigned int uint32;
typedef unsigned short bf16u;
typedef __attribute__((ext_vector_type(8))) short short8;
typedef __attribute__((ext_vector_type(4))) float f32x4;

__device__ __forceinline__ unsigned short f2bf(float f) {
  unsigned int u = __float_as_uint(f);
  u += 0x7FFFu + ((u >> 16) & 1u);   // round-to-nearest-even
  return (unsigned short)(u >> 16);
}
__device__ __forceinline__ uint32 pack2bf(float a, float b) {
  return (uint32)f2bf(a) | ((uint32)f2bf(b) << 16);
}
__device__ __forceinline__ float bf_lo(uint32 u) { return __uint_as_float(u << 16); }
__device__ __forceinline__ float bf_hi(uint32 u) { return __uint_as_float(u & 0xFFFF0000u); }
__device__ __forceinline__ float bf2f(bf16u v) { return __uint_as_float((uint32)v << 16); }

// ---- combo setup, REORDERED: hist blocks FIRST so the latency-bound atomic
// phase starts at t=0 and the init/wpack streams execute underneath it.
// [0,489) hist (8 edges/thread, 8 atomics in flight); [489,537) wpack;
// [537,9912) init. ----
__global__ void k_combo(const float* __restrict__ ue, const float* __restrict__ ie,
                        uint32* __restrict__ embb,
                        const float* __restrict__ Wq, const float* __restrict__ Wk,
                        const float* __restrict__ Wv, uint32* __restrict__ Wbg,
                        const int* __restrict__ rows, int* __restrict__ cnt,
                        int* __restrict__ rank) {
  int b = blockIdx.x, t = threadIdx.x;
  if (b < 489) {             // hist: 8 edges/thread, NE8 = 125000
    int q = b * 256 + t;
    if (q < NE8) {
      int4 rA = ((const int4*)rows)[q * 2];
      int4 rB = ((const int4*)rows)[q * 2 + 1];
      int4 kA, kB;
      kA.x = atomicAdd(&cnt[rA.x], 1);
      kA.y = atomicAdd(&cnt[rA.y], 1);
      kA.z = atomicAdd(&cnt[rA.z], 1);
      kA.w = atomicAdd(&cnt[rA.w], 1);
      kB.x = atomicAdd(&cnt[rB.x], 1);
      kB.y = atomicAdd(&cnt[rB.y], 1);
      kB.z = atomicAdd(&cnt[rB.z], 1);
      kB.w = atomicAdd(&cnt[rB.w], 1);
      ((int4*)rank)[q * 2]     = kA;
      ((int4*)rank)[q * 2 + 1] = kB;
    }
  } else if (b < 537) {      // wpack: 48*256 == 12288 exactly
    int i = (b - 489) * 256 + t;
    int l = i / 6144, rem = i % 6144, mat = rem / 2048, j = rem % 2048;
    int n = j >> 5, k2 = j & 31;
    const float* W = (mat == 0 ? Wq : mat == 1 ? Wk : Wv) + l * 4096;
    Wbg[i] = pack2bf(W[k2 * 128 + n], W[k2 * 128 + 64 + n]);
  } else {                   // init: 9375*256 == NTOT*16 exactly
    int i = (b - 537) * 256 + t;   // float4 index
    float4 v = (i < NUSERS * 16) ? ((const float4*)ue)[i]
                                 : ((const float4*)ie)[i - NUSERS * 16];
    uint2 pk;
    pk.x = pack2bf(v.x, v.y);
    pk.y = pack2bf(v.z, v.w);
    ((uint2*)embb)[i] = pk;
  }
}

__global__ void k_scan1(const int* __restrict__ cnt, int* __restrict__ partial,
                        int* __restrict__ blocksums) {
  __shared__ int s[256];
  int t = threadIdx.x, b = blockIdx.x;
  int base = b * 2048 + t * 8;
  int pre[8]; int sum = 0;
  #pragma unroll
  for (int j = 0; j < 8; ++j) {
    int idx = base + j;
    int x = (idx < NTOT) ? cnt[idx] : 0;
    pre[j] = sum; sum += x;
  }
  s[t] = sum; __syncthreads();
  for (int off = 1; off < 256; off <<= 1) {
    int x = (t >= off) ? s[t - off] : 0;
    __syncthreads(); s[t] += x; __syncthreads();
  }
  int excl = s[t] - sum;
  #pragma unroll
  for (int j = 0; j < 8; ++j) {
    int idx = base + j;
    if (idx < NTOT) partial[idx] = excl + pre[j];
  }
  if (t == 255) blocksums[b] = s[255];
}

// ---- scan3 with scan2 folded in: each block derives its global offset as a
// masked 74-element wave reduce over blocksums (K = b>>3 chunks precede it). ----
__global__ void k_scan3(int* __restrict__ row_ptr, const int* __restrict__ bsums) {
  int b = blockIdx.x, t = threadIdx.x;
  int i = b * 256 + t;
  int K = b >> 3;            // i>>11 is constant over the block
  int lane = t & 63;
  int v = 0;
  if (lane < K) v = bsums[lane];
  if (lane + 64 < K) v += bsums[lane + 64];
  #pragma unroll
  for (int off = 1; off <= 32; off <<= 1) v += __shfl_xor(v, off);
  if (i < NTOT) row_ptr[i] += v;
  if (i == 0) row_ptr[NTOT] = NEDGE;
}

// ---- fill: 4 edges/thread, coalesced metadata loads, 4 scattered 8 B stores ----
__global__ void k_fill(const int* __restrict__ rows, const int* __restrict__ cols,
                       const float* __restrict__ vals, const int* __restrict__ rank,
                       const int* __restrict__ row_ptr, uint2* __restrict__ epack) {
  int q = blockIdx.x * 256 + threadIdx.x;
  if (q >= NE4) return;
  int4   r4 = ((const int4*)rows)[q];
  int4   k4 = ((const int4*)rank)[q];
  int4   c4 = ((const int4*)cols)[q];
  float4 v4 = ((const float4*)vals)[q];
  uint2 pk;
  pk.x = (uint32)c4.x; pk.y = __float_as_uint(v4.x);
  epack[row_ptr[r4.x] + k4.x] = pk;
  pk.x = (uint32)c4.y; pk.y = __float_as_uint(v4.y);
  epack[row_ptr[r4.y] + k4.y] = pk;
  pk.x = (uint32)c4.z; pk.y = __float_as_uint(v4.z);
  epack[row_ptr[r4.z] + k4.z] = pk;
  pk.x = (uint32)c4.w; pk.y = __float_as_uint(v4.w);
  epack[row_ptr[r4.w] + k4.w] = pk;
}

// ---- QKV: MFMA. wave = 16-node tile. Q stays fp32 (R6 lesson). ----
__global__ void __launch_bounds__(256) k_qkv(const uint32* __restrict__ embb,
    const uint32* __restrict__ Wbg, float* __restrict__ Q, uint32* __restrict__ KVb) {
  __shared__ float scr[4][2][16][68];  // [wave][K/V][node][dim(+pad)] = 34816 B
  int t = threadIdx.x;
  int wave = t >> 6, lane = t & 63;
  int tile = blockIdx.x * 4 + wave;
  if (tile >= NTILE) return;
  int c = lane & 15, quad = lane >> 4;
  int nodeBase = tile * 16;
  const uint32* arow = embb + (nodeBase + c) * 32 + quad * 4;
  uint4 a0u = *(const uint4*)arow;          // dims quad*8 .. +7
  uint4 a1u = *(const uint4*)(arow + 16);   // dims 32+quad*8 .. +7
  short8 a0 = *(short8*)&a0u;
  short8 a1 = *(short8*)&a1u;
  float (*SK)[68] = scr[wave][0];
  float (*SV)[68] = scr[wave][1];
  const uint32* wbase = Wbg + c * 32 + quad * 4;
  #pragma unroll
  for (int mat = 0; mat < 3; ++mat) {
    f32x4 acc[4];
    #pragma unroll
    for (int nt = 0; nt < 4; ++nt) acc[nt] = (f32x4){0.f, 0.f, 0.f, 0.f};
    const uint32* wb = wbase + mat * 2048;
    #pragma unroll
    for (int nt = 0; nt < 4; ++nt) {
      uint4 b0u = *(const uint4*)(wb + nt * 512);        // kh=0
      uint4 b1u = *(const uint4*)(wb + nt * 512 + 16);   // kh=1
      short8 b0 = *(short8*)&b0u;
      short8 b1 = *(short8*)&b1u;
      acc[nt] = __builtin_amdgcn_mfma_f32_16x16x32_bf16(a0, b0, acc[nt], 0, 0, 0);
      acc[nt] = __builtin_amdgcn_mfma_f32_16x16x32_bf16(a1, b1, acc[nt], 0, 0, 0);
    }
    float (*S)[68] = (mat == 2) ? SV : SK;   // Q and K reuse SK
    #pragma unroll
    for (int nt = 0; nt < 4; ++nt)
      #pragma unroll
      for (int r = 0; r < 4; ++r)
        S[quad * 4 + r][nt * 16 + c] = acc[nt][r];
    if (mat == 0) {
      #pragma unroll
      for (int i = 0; i < 4; ++i) {
        int node = i * 4 + quad;
        f32x4 q4 = *(f32x4*)&SK[node][c * 4];
        *(f32x4*)&Q[(nodeBase + node) * 64 + c * 4] = q4;
      }
    } else if (mat == 2) {
      #pragma unroll
      for (int i = 0; i < 4; ++i) {
        int node = i * 4 + quad;
        f32x4 K4 = *(f32x4*)&SK[node][c * 4];
        f32x4 V4 = *(f32x4*)&SV[node][c * 4];
        uint4 o;
        o.x = pack2bf(K4[0], K4[1]);
        o.y = pack2bf(K4[2], K4[3]);
        o.z = pack2bf(V4[0], V4[1]);
        o.w = pack2bf(V4[2], V4[3]);
        *(uint4*)&KVb[(nodeBase + node) * 64 + c * 4] = o;
      }
    }
  }
}

// ---- GT layer: 4 edge-slots x 16 lanes, main loop unrolled x2 with both
// rounds' gathers issued before either is consumed (R10-proven). ----
__global__ void __launch_bounds__(256) k_gt(const float* __restrict__ Q,
    const uint32* __restrict__ KVb, const int* __restrict__ row_ptr,
    const uint2* __restrict__ epack, uint32* __restrict__ embb_out) {
  int t = threadIdx.x;
  int n = blockIdx.x * 4 + (t >> 6);
  if (n >= NTOT) return;
  int lane = t & 63;
  int es = lane >> 4;
  int dl = lane & 15;
  float4 q4 = *(const float4*)&Q[n * 64 + dl * 4];
  int s     = __builtin_amdgcn_readfirstlane(row_ptr[n]);
  int e_end = __builtin_amdgcn_readfirstlane(row_ptr[n + 1]);
  int cnt = e_end - s;
  int li = s + lane;
  int cv = (int)epack[li < NEDGE ? li : NEDGE - 1].x;
  float den = 0.f;
  float4 acc = make_float4(0.f, 0.f, 0.f, 0.f);
  int base = 0;
  for (; base + 8 <= cnt; base += 8) {       // dual round: 8 gathers in flight
    int i0 = base + es, i1 = i0 + 4;
    int cc0, cc1;
    if (base < 57) {                         // i1 <= base+7 <= 63
      cc0 = __shfl(cv, i0 & 63);
      cc1 = __shfl(cv, i1 & 63);
    } else {
      cc0 = (int)epack[s + i0].x;
      cc1 = (int)epack[s + i1].x;
    }
    uint4 wA = *(const uint4*)&KVb[cc0 * 64 + dl * 4];
    uint4 wB = *(const uint4*)&KVb[cc1 * 64 + dl * 4];
    // round A (edges base..base+3)
    float xA = q4.x * bf_lo(wA.x) + q4.y * bf_hi(wA.x)
             + q4.z * bf_lo(wA.y) + q4.w * bf_hi(wA.y);
    xA += __shfl_xor(xA, 1);
    xA += __shfl_xor(xA, 2);
    xA = fminf(fmaxf(xA, -10.f), 10.f);
    float exA = __expf(xA);
    den += exA;
    acc.x = fmaf(exA, bf_lo(wA.z), acc.x);
    acc.y = fmaf(exA, bf_hi(wA.z), acc.y);
    acc.z = fmaf(exA, bf_lo(wA.w), acc.z);
    acc.w = fmaf(exA, bf_hi(wA.w), acc.w);
    // round B (edges base+4..base+7)
    float xB = q4.x * bf_lo(wB.x) + q4.y * bf_hi(wB.x)
             + q4.z * bf_lo(wB.y) + q4.w * bf_hi(wB.y);
    xB += __shfl_xor(xB, 1);
    xB += __shfl_xor(xB, 2);
    xB = fminf(fmaxf(xB, -10.f), 10.f);
    float exB = __expf(xB);
    den += exB;
    acc.x = fmaf(exB, bf_lo(wB.z), acc.x);
    acc.y = fmaf(exB, bf_hi(wB.z), acc.y);
    acc.z = fmaf(exB, bf_lo(wB.w), acc.z);
    acc.w = fmaf(exB, bf_hi(wB.w), acc.w);
  }
  for (; base + 4 <= cnt; base += 4) {      // single round (at most once)
    int i = base + es;
    int cc;
    if (base < 61) cc = __shfl(cv, i & 63);  // i <= base+3 <= 63
    else           cc = (int)epack[s + i].x;
    uint4 w = *(const uint4*)&KVb[cc * 64 + dl * 4];
    float x = q4.x * bf_lo(w.x) + q4.y * bf_hi(w.x)
            + q4.z * bf_lo(w.y) + q4.w * bf_hi(w.y);
    x += __shfl_xor(x, 1);
    x += __shfl_xor(x, 2);
    x = fminf(fmaxf(x, -10.f), 10.f);
    float ex = __expf(x);
    den += ex;
    acc.x = fmaf(ex, bf_lo(w.z), acc.x);
    acc.y = fmaf(ex, bf_hi(w.z), acc.y);
    acc.z = fmaf(ex, bf_lo(w.w), acc.z);
    acc.w = fmaf(ex, bf_hi(w.w), acc.w);
  }
  if (base < cnt) {                          // guarded tail (1-3 live slots)
    int i = base + es;
    int cc;
    if (base < 61) cc = __shfl(cv, i & 63);
    else           cc = (i < cnt) ? (int)epack[s + i].x : 0;
    float ex = 0.f;
    float4 v4 = make_float4(0.f, 0.f, 0.f, 0.f);
    if (i < cnt) {
      uint4 w = *(const uint4*)&KVb[cc * 64 + dl * 4];
      float x = q4.x * bf_lo(w.x) + q4.y * bf_hi(w.x)
              + q4.z * bf_lo(w.y) + q4.w * bf_hi(w.y);
      v4.x = bf_lo(w.z); v4.y = bf_hi(w.z);
      v4.z = bf_lo(w.w); v4.w = bf_hi(w.w);
      x += __shfl_xor(x, 1);
      x += __shfl_xor(x, 2);
      x = fminf(fmaxf(x, -10.f), 10.f);
      ex = __expf(x);
    } else {
      float x = 0.f;
      x += __shfl_xor(x, 1);   // keep shuffle pattern wave-uniform
      x += __shfl_xor(x, 2);
    }
    den += ex;
    acc.x = fmaf(ex, v4.x, acc.x);
    acc.y = fmaf(ex, v4.y, acc.y);
    acc.z = fmaf(ex, v4.z, acc.z);
    acc.w = fmaf(ex, v4.w, acc.w);
  }
  #pragma unroll
  for (int off = 16; off <= 32; off <<= 1) {
    den  += __shfl_xor(den, off);
    acc.x += __shfl_xor(acc.x, off);
    acc.y += __shfl_xor(acc.y, off);
    acc.z += __shfl_xor(acc.z, off);
    acc.w += __shfl_xor(acc.w, off);
  }
  float inv = 1.f / (den + 1e-8f);
  if (es == 0) {
    uint2 pk;
    pk.x = pack2bf(acc.x * inv, acc.y * inv);
    pk.y = pack2bf(acc.z * inv, acc.w * inv);
    *(uint2*)&embb_out[n * 32 + dl * 2] = pk;
  }
}

// ---- GCN layer (spmm): wave per node, lane = dim, 8-wide body split into
// unguarded main loop + one guarded tail. bf16 ushort gather (128 B/edge).
// FINAL=0: writes bf16 out only. FINAL=1: fused 5-term final sum. ----
template<int FINAL>
__global__ void __launch_bounds__(256) k_gcn(const bf16u* __restrict__ src,
    const int* __restrict__ row_ptr, const uint2* __restrict__ epack,
    bf16u* __restrict__ embb_out, float* __restrict__ out,
    const float* __restrict__ ue, const float* __restrict__ ie,
    const bf16u* __restrict__ add1, const bf16u* __restrict__ add2) {
  int t = threadIdx.x;
  int n = blockIdx.x * 4 + (t >> 6);
  if (n >= NTOT) return;
  int lane = t & 63;
  int s     = __builtin_amdgcn_readfirstlane(row_ptr[n]);
  int e_end = __builtin_amdgcn_readfirstlane(row_ptr[n + 1]);
  int base = n * 64 + lane;
  // FINAL: issue the coalesced stream loads early; they drain under the gathers.
  float sum_extra = 0.f;
  if (FINAL) {
    float b = (n < NUSERS) ? ue[base] : ie[base - NUSERS * 64];
    float t1 = bf2f(add1[base]);
    float t2 = bf2f(add2[base]);
    float t3 = bf2f(src[base]);     // GCN1's own row (same buffer we gather)
    sum_extra = (b + t1) + (t2 + t3);
  }
  float a[8];
  #pragma unroll
  for (int j = 0; j < 8; ++j) a[j] = 0.f;
  int p = s;
  for (; p + 8 <= e_end; p += 8) {           // unguarded: all 8 slots valid
    #pragma unroll
    for (int j = 0; j < 8; ++j) {
      uint2 ev = epack[p + j];
      a[j] = fmaf(__uint_as_float(ev.y), bf2f(src[(int)ev.x * 64 + lane]), a[j]);
    }
  }
  if (p < e_end) {                           // guarded tail (1-7 live slots)
    #pragma unroll
    for (int j = 0; j < 8; ++j) {
      int pj = p + j;
      int pc = (pj < e_end) ? pj : s;        // clamp: dead slots re-hit edge s (L1)
      uint2 ev = epack[pc];
      float w = (pj < e_end) ? __uint_as_float(ev.y) : 0.f;
      a[j] = fmaf(w, bf2f(src[(int)ev.x * 64 + lane]), a[j]);
    }
  }
  float acc = ((a[0] + a[1]) + (a[2] + a[3])) + ((a[4] + a[5]) + (a[6] + a[7]));
  if (FINAL) {
    out[base] = acc + sum_extra;
  } else {
    embb_out[base] = f2bf(acc);
  }
}

extern "C" void kernel_launch(void* const* d_in, const int* in_sizes, int n_in,
                              void* d_out, int out_size, void* d_ws, size_t ws_size,
                              hipStream_t stream) {
  const int*   rows = (const int*)d_in[0];
  const int*   cols = (const int*)d_in[1];
  const float* vals = (const float*)d_in[2];
  const float* ue   = (const float*)d_in[3];
  const float* ie   = (const float*)d_in[4];
  const float* Wq   = (const float*)d_in[5];
  const float* Wk   = (const float*)d_in[6];
  const float* Wv   = (const float*)d_in[7];
  float* out = (float*)d_out;

  char* p = (char*)d_ws;
  auto alloc = [&](size_t b) { char* r = p; p += (b + 255) & ~(size_t)255; return (void*)r; };
  int*   cnt     = (int*)alloc((size_t)NTOT * 4);
  int*   row_ptr = (int*)alloc((size_t)(NTOT + 1) * 4);
  int*   rank    = (int*)alloc((size_t)NEDGE * 4);
  int*   bsums   = (int*)alloc(128 * 4);
  uint2* epack   = (uint2*)alloc((size_t)NEDGE * 8);     // {col, val bits}
  uint32* Wbg  = (uint32*)alloc((size_t)12288 * 4);
  float*  Q    = (float*)alloc((size_t)NTOT * 64 * 4);   // fp32 Q (256 B/node)
  uint32* KVb  = (uint32*)alloc((size_t)NTOT * 64 * 4);  // 256 B/node packed K|V
  uint32* B0   = (uint32*)alloc((size_t)NTOT * 32 * 4);  // bf16 rows == ushort[n][64]
  uint32* B1   = (uint32*)alloc((size_t)NTOT * 32 * 4);  // GT1 out
  uint32* B2   = (uint32*)alloc((size_t)NTOT * 32 * 4);  // GT2 out
  uint32* B3   = (uint32*)alloc((size_t)NTOT * 32 * 4);  // GCN1 out

  hipMemsetAsync(cnt, 0, (size_t)NTOT * 4, stream);
  // fused hist(8/thread, FIRST) + wpack + init: 489 + 48 + 9375 blocks
  k_combo<<<9912, 256, 0, stream>>>(ue, ie, B0, Wq, Wk, Wv, Wbg, rows, cnt, rank);
  int nblk = (NTOT + 2047) / 2048;  // 74
  k_scan1<<<nblk, 256, 0, stream>>>(cnt, row_ptr, bsums);
  k_scan3<<<(NTOT + 255) / 256, 256, 0, stream>>>(row_ptr, bsums);  // scan2 folded in
  k_fill<<<(NE4 + 255) / 256, 256, 0, stream>>>(rows, cols, vals, rank, row_ptr, epack);

  // GT layer 1: B0 -> B1 (bf16 only)
  k_qkv<<<(NTILE + 3) / 4, 256, 0, stream>>>(B0, Wbg, Q, KVb);
  k_gt<<<(NTOT + 3) / 4, 256, 0, stream>>>(Q, KVb, row_ptr, epack, B1);
  // GT layer 2: B1 -> B2 (bf16 only)
  k_qkv<<<(NTILE + 3) / 4, 256, 0, stream>>>(B1, Wbg + 6144, Q, KVb);
  k_gt<<<(NTOT + 3) / 4, 256, 0, stream>>>(Q, KVb, row_ptr, epack, B2);
  // GCN1: gather B2 -> B3 (bf16 only)
  k_gcn<0><<<(NTOT + 3) / 4, 256, 0, stream>>>((const bf16u*)B2, row_ptr, epack,
                                               (bf16u*)B3, nullptr,
                                               nullptr, nullptr, nullptr, nullptr);
  // GCN2 + fused final sum: gather B3; out = cat(ue,ie)+B1+B2+B3+own
  k_gcn<1><<<(NTOT + 3) / 4, 256, 0, stream>>>((const bf16u*)B3, row_ptr, epack,
                                               nullptr, out,
                                               ue, ie, (const bf16u*)B1, (const bf16u*)B2);
}

// Round 13
// 425.274 us; speedup vs baseline: 1.3461x; 1.0127x over previous
//
#include <hip/hip_runtime.h>

#define NUSERS 100000
#define NITEMS 50000
#define NTOT   150000
#define NEDGE  1000000
#define NTILE  9375   // NTOT / 16
#define NE4    250000 // NEDGE / 4
#define NE8    125000 // NEDGE / 8

typedef unsigned int uint32;
typedef unsigned short bf16u;
typedef __attribute__((ext_vector_type(8))) short short8;
typedef __attribute__((ext_vector_type(4))) float f32x4;

__device__ __forceinline__ unsigned short f2bf(float f) {
  unsigned int u = __float_as_uint(f);
  u += 0x7FFFu + ((u >> 16) & 1u);   // round-to-nearest-even
  return (unsigned short)(u >> 16);
}
__device__ __forceinline__ uint32 pack2bf(float a, float b) {
  return (uint32)f2bf(a) | ((uint32)f2bf(b) << 16);
}
__device__ __forceinline__ float bf_lo(uint32 u) { return __uint_as_float(u << 16); }
__device__ __forceinline__ float bf_hi(uint32 u) { return __uint_as_float(u & 0xFFFF0000u); }
__device__ __forceinline__ float bf2f(bf16u v) { return __uint_as_float((uint32)v << 16); }

// ---- combo setup: [0,489) hist (8 edges/thread); [489,537) wpack; [537,9912) init ----
__global__ void k_combo(const float* __restrict__ ue, const float* __restrict__ ie,
                        uint32* __restrict__ embb,
                        const float* __restrict__ Wq, const float* __restrict__ Wk,
                        const float* __restrict__ Wv, uint32* __restrict__ Wbg,
                        const int* __restrict__ rows, int* __restrict__ cnt,
                        int* __restrict__ rank) {
  int b = blockIdx.x, t = threadIdx.x;
  if (b < 489) {             // hist: 8 edges/thread, NE8 = 125000
    int q = b * 256 + t;
    if (q < NE8) {
      int4 rA = ((const int4*)rows)[q * 2];
      int4 rB = ((const int4*)rows)[q * 2 + 1];
      int4 kA, kB;
      kA.x = atomicAdd(&cnt[rA.x], 1);
      kA.y = atomicAdd(&cnt[rA.y], 1);
      kA.z = atomicAdd(&cnt[rA.z], 1);
      kA.w = atomicAdd(&cnt[rA.w], 1);
      kB.x = atomicAdd(&cnt[rB.x], 1);
      kB.y = atomicAdd(&cnt[rB.y], 1);
      kB.z = atomicAdd(&cnt[rB.z], 1);
      kB.w = atomicAdd(&cnt[rB.w], 1);
      ((int4*)rank)[q * 2]     = kA;
      ((int4*)rank)[q * 2 + 1] = kB;
    }
  } else if (b < 537) {      // wpack: 48*256 == 12288 exactly
    int i = (b - 489) * 256 + t;
    int l = i / 6144, rem = i % 6144, mat = rem / 2048, j = rem % 2048;
    int n = j >> 5, k2 = j & 31;
    const float* W = (mat == 0 ? Wq : mat == 1 ? Wk : Wv) + l * 4096;
    Wbg[i] = pack2bf(W[k2 * 128 + n], W[k2 * 128 + 64 + n]);
  } else {                   // init: 9375*256 == NTOT*16 exactly
    int i = (b - 537) * 256 + t;   // float4 index
    float4 v = (i < NUSERS * 16) ? ((const float4*)ue)[i]
                                 : ((const float4*)ie)[i - NUSERS * 16];
    uint2 pk;
    pk.x = pack2bf(v.x, v.y);
    pk.y = pack2bf(v.z, v.w);
    ((uint2*)embb)[i] = pk;
  }
}

__global__ void k_scan1(const int* __restrict__ cnt, int* __restrict__ partial,
                        int* __restrict__ blocksums) {
  __shared__ int s[256];
  int t = threadIdx.x, b = blockIdx.x;
  int base = b * 2048 + t * 8;
  int pre[8]; int sum = 0;
  #pragma unroll
  for (int j = 0; j < 8; ++j) {
    int idx = base + j;
    int x = (idx < NTOT) ? cnt[idx] : 0;
    pre[j] = sum; sum += x;
  }
  s[t] = sum; __syncthreads();
  for (int off = 1; off < 256; off <<= 1) {
    int x = (t >= off) ? s[t - off] : 0;
    __syncthreads(); s[t] += x; __syncthreads();
  }
  int excl = s[t] - sum;
  #pragma unroll
  for (int j = 0; j < 8; ++j) {
    int idx = base + j;
    if (idx < NTOT) partial[idx] = excl + pre[j];
  }
  if (t == 255) blocksums[b] = s[255];
}

// ---- scan3 with scan2 folded in: masked 74-element wave reduce over bsums ----
__global__ void k_scan3(int* __restrict__ row_ptr, const int* __restrict__ bsums) {
  int b = blockIdx.x, t = threadIdx.x;
  int i = b * 256 + t;
  int K = b >> 3;            // i>>11 is constant over the block
  int lane = t & 63;
  int v = 0;
  if (lane < K) v = bsums[lane];
  if (lane + 64 < K) v += bsums[lane + 64];
  #pragma unroll
  for (int off = 1; off <= 32; off <<= 1) v += __shfl_xor(v, off);
  if (i < NTOT) row_ptr[i] += v;
  if (i == 0) row_ptr[NTOT] = NEDGE;
}

// ---- fill: 4 edges/thread, coalesced metadata loads, 4 scattered 8 B stores ----
__global__ void k_fill(const int* __restrict__ rows, const int* __restrict__ cols,
                       const float* __restrict__ vals, const int* __restrict__ rank,
                       const int* __restrict__ row_ptr, uint2* __restrict__ epack) {
  int q = blockIdx.x * 256 + threadIdx.x;
  if (q >= NE4) return;
  int4   r4 = ((const int4*)rows)[q];
  int4   k4 = ((const int4*)rank)[q];
  int4   c4 = ((const int4*)cols)[q];
  float4 v4 = ((const float4*)vals)[q];
  uint2 pk;
  pk.x = (uint32)c4.x; pk.y = __float_as_uint(v4.x);
  epack[row_ptr[r4.x] + k4.x] = pk;
  pk.x = (uint32)c4.y; pk.y = __float_as_uint(v4.y);
  epack[row_ptr[r4.y] + k4.y] = pk;
  pk.x = (uint32)c4.z; pk.y = __float_as_uint(v4.z);
  epack[row_ptr[r4.z] + k4.z] = pk;
  pk.x = (uint32)c4.w; pk.y = __float_as_uint(v4.w);
  epack[row_ptr[r4.w] + k4.w] = pk;
}

// ---- QKV: MFMA. wave = 16-node tile. Q stays fp32 (R6 lesson). ----
__global__ void __launch_bounds__(256) k_qkv(const uint32* __restrict__ embb,
    const uint32* __restrict__ Wbg, float* __restrict__ Q, uint32* __restrict__ KVb) {
  __shared__ float scr[4][2][16][68];  // [wave][K/V][node][dim(+pad)] = 34816 B
  int t = threadIdx.x;
  int wave = t >> 6, lane = t & 63;
  int tile = blockIdx.x * 4 + wave;
  if (tile >= NTILE) return;
  int c = lane & 15, quad = lane >> 4;
  int nodeBase = tile * 16;
  const uint32* arow = embb + (nodeBase + c) * 32 + quad * 4;
  uint4 a0u = *(const uint4*)arow;          // dims quad*8 .. +7
  uint4 a1u = *(const uint4*)(arow + 16);   // dims 32+quad*8 .. +7
  short8 a0 = *(short8*)&a0u;
  short8 a1 = *(short8*)&a1u;
  float (*SK)[68] = scr[wave][0];
  float (*SV)[68] = scr[wave][1];
  const uint32* wbase = Wbg + c * 32 + quad * 4;
  #pragma unroll
  for (int mat = 0; mat < 3; ++mat) {
    f32x4 acc[4];
    #pragma unroll
    for (int nt = 0; nt < 4; ++nt) acc[nt] = (f32x4){0.f, 0.f, 0.f, 0.f};
    const uint32* wb = wbase + mat * 2048;
    #pragma unroll
    for (int nt = 0; nt < 4; ++nt) {
      uint4 b0u = *(const uint4*)(wb + nt * 512);        // kh=0
      uint4 b1u = *(const uint4*)(wb + nt * 512 + 16);   // kh=1
      short8 b0 = *(short8*)&b0u;
      short8 b1 = *(short8*)&b1u;
      acc[nt] = __builtin_amdgcn_mfma_f32_16x16x32_bf16(a0, b0, acc[nt], 0, 0, 0);
      acc[nt] = __builtin_amdgcn_mfma_f32_16x16x32_bf16(a1, b1, acc[nt], 0, 0, 0);
    }
    float (*S)[68] = (mat == 2) ? SV : SK;   // Q and K reuse SK
    #pragma unroll
    for (int nt = 0; nt < 4; ++nt)
      #pragma unroll
      for (int r = 0; r < 4; ++r)
        S[quad * 4 + r][nt * 16 + c] = acc[nt][r];
    if (mat == 0) {
      #pragma unroll
      for (int i = 0; i < 4; ++i) {
        int node = i * 4 + quad;
        f32x4 q4 = *(f32x4*)&SK[node][c * 4];
        *(f32x4*)&Q[(nodeBase + node) * 64 + c * 4] = q4;
      }
    } else if (mat == 2) {
      #pragma unroll
      for (int i = 0; i < 4; ++i) {
        int node = i * 4 + quad;
        f32x4 K4 = *(f32x4*)&SK[node][c * 4];
        f32x4 V4 = *(f32x4*)&SV[node][c * 4];
        uint4 o;
        o.x = pack2bf(K4[0], K4[1]);
        o.y = pack2bf(K4[2], K4[3]);
        o.z = pack2bf(V4[0], V4[1]);
        o.w = pack2bf(V4[2], V4[3]);
        *(uint4*)&KVb[(nodeBase + node) * 64 + c * 4] = o;
      }
    }
  }
}

// ---- GT layer: 4 edge-slots x 16 lanes, dual-round unroll (R10-proven).
// R13: (a) dead preload lanes clamp to s (same line as lane 0) instead of
// NEDGE-1 -> preload lines/wave drop 8 -> ~2 (was ~70 MB of wasted FETCH);
// (b) bijective XCD swizzle so consecutive nodes share an XCD's L2 (their
// preload windows overlap ~90%). Arithmetic identical to R12. ----
__global__ void __launch_bounds__(256) k_gt(const float* __restrict__ Q,
    const uint32* __restrict__ KVb, const int* __restrict__ row_ptr,
    const uint2* __restrict__ epack, uint32* __restrict__ embb_out) {
  // bijective XCD swizzle: nwg = 37500 = 4 chunks of 4688 + 4 of 4687 (m204)
  int orig = blockIdx.x;
  int xcd = orig & 7, pos = orig >> 3;
  const int qq = 4687, rr = 4;
  int swz = (xcd < rr ? xcd * (qq + 1) : rr * (qq + 1) + (xcd - rr) * qq) + pos;
  int t = threadIdx.x;
  int n = swz * 4 + (t >> 6);
  if (n >= NTOT) return;
  int lane = t & 63;
  int es = lane >> 4;
  int dl = lane & 15;
  float4 q4 = *(const float4*)&Q[n * 64 + dl * 4];
  int s     = __builtin_amdgcn_readfirstlane(row_ptr[n]);
  int e_end = __builtin_amdgcn_readfirstlane(row_ptr[n + 1]);
  int cnt = e_end - s;
  int li = s + lane;
  int cv = (int)epack[li < e_end ? li : s].x;   // dead lanes re-hit lane 0's line
  float den = 0.f;
  float4 acc = make_float4(0.f, 0.f, 0.f, 0.f);
  int base = 0;
  for (; base + 8 <= cnt; base += 8) {       // dual round: 8 gathers in flight
    int i0 = base + es, i1 = i0 + 4;
    int cc0, cc1;
    if (base < 57) {                         // i1 <= base+7 <= 63
      cc0 = __shfl(cv, i0 & 63);
      cc1 = __shfl(cv, i1 & 63);
    } else {
      cc0 = (int)epack[s + i0].x;
      cc1 = (int)epack[s + i1].x;
    }
    uint4 wA = *(const uint4*)&KVb[cc0 * 64 + dl * 4];
    uint4 wB = *(const uint4*)&KVb[cc1 * 64 + dl * 4];
    // round A (edges base..base+3)
    float xA = q4.x * bf_lo(wA.x) + q4.y * bf_hi(wA.x)
             + q4.z * bf_lo(wA.y) + q4.w * bf_hi(wA.y);
    xA += __shfl_xor(xA, 1);
    xA += __shfl_xor(xA, 2);
    xA = fminf(fmaxf(xA, -10.f), 10.f);
    float exA = __expf(xA);
    den += exA;
    acc.x = fmaf(exA, bf_lo(wA.z), acc.x);
    acc.y = fmaf(exA, bf_hi(wA.z), acc.y);
    acc.z = fmaf(exA, bf_lo(wA.w), acc.z);
    acc.w = fmaf(exA, bf_hi(wA.w), acc.w);
    // round B (edges base+4..base+7)
    float xB = q4.x * bf_lo(wB.x) + q4.y * bf_hi(wB.x)
             + q4.z * bf_lo(wB.y) + q4.w * bf_hi(wB.y);
    xB += __shfl_xor(xB, 1);
    xB += __shfl_xor(xB, 2);
    xB = fminf(fmaxf(xB, -10.f), 10.f);
    float exB = __expf(xB);
    den += exB;
    acc.x = fmaf(exB, bf_lo(wB.z), acc.x);
    acc.y = fmaf(exB, bf_hi(wB.z), acc.y);
    acc.z = fmaf(exB, bf_lo(wB.w), acc.z);
    acc.w = fmaf(exB, bf_hi(wB.w), acc.w);
  }
  for (; base + 4 <= cnt; base += 4) {      // single round (at most once)
    int i = base + es;
    int cc;
    if (base < 61) cc = __shfl(cv, i & 63);  // i <= base+3 <= 63
    else           cc = (int)epack[s + i].x;
    uint4 w = *(const uint4*)&KVb[cc * 64 + dl * 4];
    float x = q4.x * bf_lo(w.x) + q4.y * bf_hi(w.x)
            + q4.z * bf_lo(w.y) + q4.w * bf_hi(w.y);
    x += __shfl_xor(x, 1);
    x += __shfl_xor(x, 2);
    x = fminf(fmaxf(x, -10.f), 10.f);
    float ex = __expf(x);
    den += ex;
    acc.x = fmaf(ex, bf_lo(w.z), acc.x);
    acc.y = fmaf(ex, bf_hi(w.z), acc.y);
    acc.z = fmaf(ex, bf_lo(w.w), acc.z);
    acc.w = fmaf(ex, bf_hi(w.w), acc.w);
  }
  if (base < cnt) {                          // guarded tail (1-3 live slots)
    int i = base + es;
    int cc;
    if (base < 61) cc = __shfl(cv, i & 63);
    else           cc = (i < cnt) ? (int)epack[s + i].x : 0;
    float ex = 0.f;
    float4 v4 = make_float4(0.f, 0.f, 0.f, 0.f);
    if (i < cnt) {
      uint4 w = *(const uint4*)&KVb[cc * 64 + dl * 4];
      float x = q4.x * bf_lo(w.x) + q4.y * bf_hi(w.x)
              + q4.z * bf_lo(w.y) + q4.w * bf_hi(w.y);
      v4.x = bf_lo(w.z); v4.y = bf_hi(w.z);
      v4.z = bf_lo(w.w); v4.w = bf_hi(w.w);
      x += __shfl_xor(x, 1);
      x += __shfl_xor(x, 2);
      x = fminf(fmaxf(x, -10.f), 10.f);
      ex = __expf(x);
    } else {
      float x = 0.f;
      x += __shfl_xor(x, 1);   // keep shuffle pattern wave-uniform
      x += __shfl_xor(x, 2);
    }
    den += ex;
    acc.x = fmaf(ex, v4.x, acc.x);
    acc.y = fmaf(ex, v4.y, acc.y);
    acc.z = fmaf(ex, v4.z, acc.z);
    acc.w = fmaf(ex, v4.w, acc.w);
  }
  #pragma unroll
  for (int off = 16; off <= 32; off <<= 1) {
    den  += __shfl_xor(den, off);
    acc.x += __shfl_xor(acc.x, off);
    acc.y += __shfl_xor(acc.y, off);
    acc.z += __shfl_xor(acc.z, off);
    acc.w += __shfl_xor(acc.w, off);
  }
  float inv = 1.f / (den + 1e-8f);
  if (es == 0) {
    uint2 pk;
    pk.x = pack2bf(acc.x * inv, acc.y * inv);
    pk.y = pack2bf(acc.z * inv, acc.w * inv);
    *(uint2*)&embb_out[n * 32 + dl * 2] = pk;
  }
}

// ---- GCN layer (spmm): wave per node, lane = dim, 8-wide body split into
// unguarded main loop + one guarded tail. bf16 ushort gather (128 B/edge).
// FINAL=0: writes bf16 out only. FINAL=1: fused 5-term final sum. ----
template<int FINAL>
__global__ void __launch_bounds__(256) k_gcn(const bf16u* __restrict__ src,
    const int* __restrict__ row_ptr, const uint2* __restrict__ epack,
    bf16u* __restrict__ embb_out, float* __restrict__ out,
    const float* __restrict__ ue, const float* __restrict__ ie,
    const bf16u* __restrict__ add1, const bf16u* __restrict__ add2) {
  int t = threadIdx.x;
  int n = blockIdx.x * 4 + (t >> 6);
  if (n >= NTOT) return;
  int lane = t & 63;
  int s     = __builtin_amdgcn_readfirstlane(row_ptr[n]);
  int e_end = __builtin_amdgcn_readfirstlane(row_ptr[n + 1]);
  int base = n * 64 + lane;
  // FINAL: issue the coalesced stream loads early; they drain under the gathers.
  float sum_extra = 0.f;
  if (FINAL) {
    float b = (n < NUSERS) ? ue[base] : ie[base - NUSERS * 64];
    float t1 = bf2f(add1[base]);
    float t2 = bf2f(add2[base]);
    float t3 = bf2f(src[base]);     // GCN1's own row (same buffer we gather)
    sum_extra = (b + t1) + (t2 + t3);
  }
  float a[8];
  #pragma unroll
  for (int j = 0; j < 8; ++j) a[j] = 0.f;
  int p = s;
  for (; p + 8 <= e_end; p += 8) {           // unguarded: all 8 slots valid
    #pragma unroll
    for (int j = 0; j < 8; ++j) {
      uint2 ev = epack[p + j];
      a[j] = fmaf(__uint_as_float(ev.y), bf2f(src[(int)ev.x * 64 + lane]), a[j]);
    }
  }
  if (p < e_end) {                           // guarded tail (1-7 live slots)
    #pragma unroll
    for (int j = 0; j < 8; ++j) {
      int pj = p + j;
      int pc = (pj < e_end) ? pj : s;        // clamp: dead slots re-hit edge s (L1)
      uint2 ev = epack[pc];
      float w = (pj < e_end) ? __uint_as_float(ev.y) : 0.f;
      a[j] = fmaf(w, bf2f(src[(int)ev.x * 64 + lane]), a[j]);
    }
  }
  float acc = ((a[0] + a[1]) + (a[2] + a[3])) + ((a[4] + a[5]) + (a[6] + a[7]));
  if (FINAL) {
    out[base] = acc + sum_extra;
  } else {
    embb_out[base] = f2bf(acc);
  }
}

extern "C" void kernel_launch(void* const* d_in, const int* in_sizes, int n_in,
                              void* d_out, int out_size, void* d_ws, size_t ws_size,
                              hipStream_t stream) {
  const int*   rows = (const int*)d_in[0];
  const int*   cols = (const int*)d_in[1];
  const float* vals = (const float*)d_in[2];
  const float* ue   = (const float*)d_in[3];
  const float* ie   = (const float*)d_in[4];
  const float* Wq   = (const float*)d_in[5];
  const float* Wk   = (const float*)d_in[6];
  const float* Wv   = (const float*)d_in[7];
  float* out = (float*)d_out;

  char* p = (char*)d_ws;
  auto alloc = [&](size_t b) { char* r = p; p += (b + 255) & ~(size_t)255; return (void*)r; };
  int*   cnt     = (int*)alloc((size_t)NTOT * 4);
  int*   row_ptr = (int*)alloc((size_t)(NTOT + 1) * 4);
  int*   rank    = (int*)alloc((size_t)NEDGE * 4);
  int*   bsums   = (int*)alloc(128 * 4);
  uint2* epack   = (uint2*)alloc((size_t)NEDGE * 8);     // {col, val bits}
  uint32* Wbg  = (uint32*)alloc((size_t)12288 * 4);
  float*  Q    = (float*)alloc((size_t)NTOT * 64 * 4);   // fp32 Q (256 B/node)
  uint32* KVb  = (uint32*)alloc((size_t)NTOT * 64 * 4);  // 256 B/node packed K|V
  uint32* B0   = (uint32*)alloc((size_t)NTOT * 32 * 4);  // bf16 rows == ushort[n][64]
  uint32* B1   = (uint32*)alloc((size_t)NTOT * 32 * 4);  // GT1 out
  uint32* B2   = (uint32*)alloc((size_t)NTOT * 32 * 4);  // GT2 out
  uint32* B3   = (uint32*)alloc((size_t)NTOT * 32 * 4);  // GCN1 out

  hipMemsetAsync(cnt, 0, (size_t)NTOT * 4, stream);
  // fused hist(8/thread, FIRST) + wpack + init: 489 + 48 + 9375 blocks
  k_combo<<<9912, 256, 0, stream>>>(ue, ie, B0, Wq, Wk, Wv, Wbg, rows, cnt, rank);
  int nblk = (NTOT + 2047) / 2048;  // 74
  k_scan1<<<nblk, 256, 0, stream>>>(cnt, row_ptr, bsums);
  k_scan3<<<(NTOT + 255) / 256, 256, 0, stream>>>(row_ptr, bsums);  // scan2 folded in
  k_fill<<<(NE4 + 255) / 256, 256, 0, stream>>>(rows, cols, vals, rank, row_ptr, epack);

  // GT layer 1: B0 -> B1 (bf16 only)
  k_qkv<<<(NTILE + 3) / 4, 256, 0, stream>>>(B0, Wbg, Q, KVb);
  k_gt<<<(NTOT + 3) / 4, 256, 0, stream>>>(Q, KVb, row_ptr, epack, B1);
  // GT layer 2: B1 -> B2 (bf16 only)
  k_qkv<<<(NTILE + 3) / 4, 256, 0, stream>>>(B1, Wbg + 6144, Q, KVb);
  k_gt<<<(NTOT + 3) / 4, 256, 0, stream>>>(Q, KVb, row_ptr, epack, B2);
  // GCN1: gather B2 -> B3 (bf16 only)
  k_gcn<0><<<(NTOT + 3) / 4, 256, 0, stream>>>((const bf16u*)B2, row_ptr, epack,
                                               (bf16u*)B3, nullptr,
                                               nullptr, nullptr, nullptr, nullptr);
  // GCN2 + fused final sum: gather B3; out = cat(ue,ie)+B1+B2+B3+own
  k_gcn<1><<<(NTOT + 3) / 4, 256, 0, stream>>>((const bf16u*)B3, row_ptr, epack,
                                               nullptr, out,
                                               ue, ie, (const bf16u*)B1, (const bf16u*)B2);
}

// Round 14
// 421.939 us; speedup vs baseline: 1.3567x; 1.0079x over previous
//
#include <hip/hip_runtime.h>

#define NUSERS 100000
#define NITEMS 50000
#define NTOT   150000
#define NEDGE  1000000
#define NTILE  9375   // NTOT / 16
#define NE4    250000 // NEDGE / 4
#define NE8    125000 // NEDGE / 8

typedef unsigned int uint32;
typedef unsigned short bf16u;
typedef __attribute__((ext_vector_type(8))) short short8;
typedef __attribute__((ext_vector_type(4))) float f32x4;
typedef __attribute__((ext_vector_type(2))) _Float16 h2;

__device__ __forceinline__ unsigned short f2bf(float f) {
  unsigned int u = __float_as_uint(f);
  u += 0x7FFFu + ((u >> 16) & 1u);   // round-to-nearest-even
  return (unsigned short)(u >> 16);
}
__device__ __forceinline__ uint32 pack2bf(float a, float b) {
  return (uint32)f2bf(a) | ((uint32)f2bf(b) << 16);
}
__device__ __forceinline__ float bf_lo(uint32 u) { return __uint_as_float(u << 16); }
__device__ __forceinline__ float bf_hi(uint32 u) { return __uint_as_float(u & 0xFFFF0000u); }
__device__ __forceinline__ float bf2f(bf16u v) { return __uint_as_float((uint32)v << 16); }

// ---- fp16 helpers (R14): Q/K/V in the attention path are fp16 now.
// fp16 (11-bit mantissa) is 8x tighter than bf16 -> R6's bf16-Q failure
// mode (score err ~0.04) becomes ~0.005; K/V actually get MORE accurate. ----
__device__ __forceinline__ h2 as_h2(uint32 u) { return *(h2*)&u; }
__device__ __forceinline__ uint32 pack2half(float a, float b) {
  h2 h; h[0] = (_Float16)a; h[1] = (_Float16)b;
  return *(uint32*)&h;
}
__device__ __forceinline__ float h_lo(uint32 u) { return (float)as_h2(u)[0]; }
__device__ __forceinline__ float h_hi(uint32 u) { return (float)as_h2(u)[1]; }
// 4-dim partial dot: q (2 packed half2) . k (2 packed half2) -> f32
__device__ __forceinline__ float score4(uint2 qp, uint32 kx, uint32 ky) {
#if __has_builtin(__builtin_amdgcn_fdot2)
  return __builtin_amdgcn_fdot2(as_h2(qp.x), as_h2(kx),
         __builtin_amdgcn_fdot2(as_h2(qp.y), as_h2(ky), 0.f, false), false);
#else
  return h_lo(qp.x) * h_lo(kx) + h_hi(qp.x) * h_hi(kx)
       + h_lo(qp.y) * h_lo(ky) + h_hi(qp.y) * h_hi(ky);
#endif
}

// ---- combo setup: [0,489) hist (8 edges/thread); [489,537) wpack; [537,9912) init ----
__global__ void k_combo(const float* __restrict__ ue, const float* __restrict__ ie,
                        uint32* __restrict__ embb,
                        const float* __restrict__ Wq, const float* __restrict__ Wk,
                        const float* __restrict__ Wv, uint32* __restrict__ Wbg,
                        const int* __restrict__ rows, int* __restrict__ cnt,
                        int* __restrict__ rank) {
  int b = blockIdx.x, t = threadIdx.x;
  if (b < 489) {             // hist: 8 edges/thread, NE8 = 125000
    int q = b * 256 + t;
    if (q < NE8) {
      int4 rA = ((const int4*)rows)[q * 2];
      int4 rB = ((const int4*)rows)[q * 2 + 1];
      int4 kA, kB;
      kA.x = atomicAdd(&cnt[rA.x], 1);
      kA.y = atomicAdd(&cnt[rA.y], 1);
      kA.z = atomicAdd(&cnt[rA.z], 1);
      kA.w = atomicAdd(&cnt[rA.w], 1);
      kB.x = atomicAdd(&cnt[rB.x], 1);
      kB.y = atomicAdd(&cnt[rB.y], 1);
      kB.z = atomicAdd(&cnt[rB.z], 1);
      kB.w = atomicAdd(&cnt[rB.w], 1);
      ((int4*)rank)[q * 2]     = kA;
      ((int4*)rank)[q * 2 + 1] = kB;
    }
  } else if (b < 537) {      // wpack: 48*256 == 12288 exactly
    int i = (b - 489) * 256 + t;
    int l = i / 6144, rem = i % 6144, mat = rem / 2048, j = rem % 2048;
    int n = j >> 5, k2 = j & 31;
    const float* W = (mat == 0 ? Wq : mat == 1 ? Wk : Wv) + l * 4096;
    Wbg[i] = pack2bf(W[k2 * 128 + n], W[k2 * 128 + 64 + n]);
  } else {                   // init: 9375*256 == NTOT*16 exactly
    int i = (b - 537) * 256 + t;   // float4 index
    float4 v = (i < NUSERS * 16) ? ((const float4*)ue)[i]
                                 : ((const float4*)ie)[i - NUSERS * 16];
    uint2 pk;
    pk.x = pack2bf(v.x, v.y);
    pk.y = pack2bf(v.z, v.w);
    ((uint2*)embb)[i] = pk;
  }
}

__global__ void k_scan1(const int* __restrict__ cnt, int* __restrict__ partial,
                        int* __restrict__ blocksums) {
  __shared__ int s[256];
  int t = threadIdx.x, b = blockIdx.x;
  int base = b * 2048 + t * 8;
  int pre[8]; int sum = 0;
  #pragma unroll
  for (int j = 0; j < 8; ++j) {
    int idx = base + j;
    int x = (idx < NTOT) ? cnt[idx] : 0;
    pre[j] = sum; sum += x;
  }
  s[t] = sum; __syncthreads();
  for (int off = 1; off < 256; off <<= 1) {
    int x = (t >= off) ? s[t - off] : 0;
    __syncthreads(); s[t] += x; __syncthreads();
  }
  int excl = s[t] - sum;
  #pragma unroll
  for (int j = 0; j < 8; ++j) {
    int idx = base + j;
    if (idx < NTOT) partial[idx] = excl + pre[j];
  }
  if (t == 255) blocksums[b] = s[255];
}

// ---- scan3 with scan2 folded in: masked 74-element wave reduce over bsums ----
__global__ void k_scan3(int* __restrict__ row_ptr, const int* __restrict__ bsums) {
  int b = blockIdx.x, t = threadIdx.x;
  int i = b * 256 + t;
  int K = b >> 3;            // i>>11 is constant over the block
  int lane = t & 63;
  int v = 0;
  if (lane < K) v = bsums[lane];
  if (lane + 64 < K) v += bsums[lane + 64];
  #pragma unroll
  for (int off = 1; off <= 32; off <<= 1) v += __shfl_xor(v, off);
  if (i < NTOT) row_ptr[i] += v;
  if (i == 0) row_ptr[NTOT] = NEDGE;
}

// ---- fill: 4 edges/thread, coalesced metadata loads, 4 scattered 8 B stores ----
__global__ void k_fill(const int* __restrict__ rows, const int* __restrict__ cols,
                       const float* __restrict__ vals, const int* __restrict__ rank,
                       const int* __restrict__ row_ptr, uint2* __restrict__ epack) {
  int q = blockIdx.x * 256 + threadIdx.x;
  if (q >= NE4) return;
  int4   r4 = ((const int4*)rows)[q];
  int4   k4 = ((const int4*)rank)[q];
  int4   c4 = ((const int4*)cols)[q];
  float4 v4 = ((const float4*)vals)[q];
  uint2 pk;
  pk.x = (uint32)c4.x; pk.y = __float_as_uint(v4.x);
  epack[row_ptr[r4.x] + k4.x] = pk;
  pk.x = (uint32)c4.y; pk.y = __float_as_uint(v4.y);
  epack[row_ptr[r4.y] + k4.y] = pk;
  pk.x = (uint32)c4.z; pk.y = __float_as_uint(v4.z);
  epack[row_ptr[r4.z] + k4.z] = pk;
  pk.x = (uint32)c4.w; pk.y = __float_as_uint(v4.w);
  epack[row_ptr[r4.w] + k4.w] = pk;
}

// ---- QKV: MFMA. wave = 16-node tile. R14: Q/K/V all packed fp16.
// Q row shrinks 256 -> 128 B (R6's bf16-Q failed on precision; fp16 is 8x
// tighter). KVb layout unchanged (uint4/lane: K half2 x2 | V half2 x2). ----
__global__ void __launch_bounds__(256) k_qkv(const uint32* __restrict__ embb,
    const uint32* __restrict__ Wbg, uint32* __restrict__ Qh, uint32* __restrict__ KVb) {
  __shared__ float scr[4][2][16][68];  // [wave][K/V][node][dim(+pad)] = 34816 B
  int t = threadIdx.x;
  int wave = t >> 6, lane = t & 63;
  int tile = blockIdx.x * 4 + wave;
  if (tile >= NTILE) return;
  int c = lane & 15, quad = lane >> 4;
  int nodeBase = tile * 16;
  const uint32* arow = embb + (nodeBase + c) * 32 + quad * 4;
  uint4 a0u = *(const uint4*)arow;          // dims quad*8 .. +7
  uint4 a1u = *(const uint4*)(arow + 16);   // dims 32+quad*8 .. +7
  short8 a0 = *(short8*)&a0u;
  short8 a1 = *(short8*)&a1u;
  float (*SK)[68] = scr[wave][0];
  float (*SV)[68] = scr[wave][1];
  const uint32* wbase = Wbg + c * 32 + quad * 4;
  #pragma unroll
  for (int mat = 0; mat < 3; ++mat) {
    f32x4 acc[4];
    #pragma unroll
    for (int nt = 0; nt < 4; ++nt) acc[nt] = (f32x4){0.f, 0.f, 0.f, 0.f};
    const uint32* wb = wbase + mat * 2048;
    #pragma unroll
    for (int nt = 0; nt < 4; ++nt) {
      uint4 b0u = *(const uint4*)(wb + nt * 512);        // kh=0
      uint4 b1u = *(const uint4*)(wb + nt * 512 + 16);   // kh=1
      short8 b0 = *(short8*)&b0u;
      short8 b1 = *(short8*)&b1u;
      acc[nt] = __builtin_amdgcn_mfma_f32_16x16x32_bf16(a0, b0, acc[nt], 0, 0, 0);
      acc[nt] = __builtin_amdgcn_mfma_f32_16x16x32_bf16(a1, b1, acc[nt], 0, 0, 0);
    }
    float (*S)[68] = (mat == 2) ? SV : SK;   // Q and K reuse SK
    #pragma unroll
    for (int nt = 0; nt < 4; ++nt)
      #pragma unroll
      for (int r = 0; r < 4; ++r)
        S[quad * 4 + r][nt * 16 + c] = acc[nt][r];
    if (mat == 0) {
      #pragma unroll
      for (int i = 0; i < 4; ++i) {
        int node = i * 4 + quad;
        f32x4 q4 = *(f32x4*)&SK[node][c * 4];
        uint2 o;
        o.x = pack2half(q4[0], q4[1]);
        o.y = pack2half(q4[2], q4[3]);
        *(uint2*)&Qh[(nodeBase + node) * 32 + c * 2] = o;
      }
    } else if (mat == 2) {
      #pragma unroll
      for (int i = 0; i < 4; ++i) {
        int node = i * 4 + quad;
        f32x4 K4 = *(f32x4*)&SK[node][c * 4];
        f32x4 V4 = *(f32x4*)&SV[node][c * 4];
        uint4 o;
        o.x = pack2half(K4[0], K4[1]);
        o.y = pack2half(K4[2], K4[3]);
        o.z = pack2half(V4[0], V4[1]);
        o.w = pack2half(V4[2], V4[3]);
        *(uint4*)&KVb[(nodeBase + node) * 64 + c * 4] = o;
      }
    }
  }
}

// ---- GT layer: 4 edge-slots x 16 lanes, dual-round unroll, XCD swizzle,
// clamp-to-s preload (R13). R14: fp16 Q (128 B/node, packed load) + fp16 K
// via v_dot2_f32_f16 (2 inst per 4-dim score vs 8 unpack + 4 fma) + fp16 V. ----
__global__ void __launch_bounds__(256) k_gt(const uint32* __restrict__ Qh,
    const uint32* __restrict__ KVb, const int* __restrict__ row_ptr,
    const uint2* __restrict__ epack, uint32* __restrict__ embb_out) {
  // bijective XCD swizzle: nwg = 37500 = 4 chunks of 4688 + 4 of 4687 (m204)
  int orig = blockIdx.x;
  int xcd = orig & 7, pos = orig >> 3;
  const int qq = 4687, rr = 4;
  int swz = (xcd < rr ? xcd * (qq + 1) : rr * (qq + 1) + (xcd - rr) * qq) + pos;
  int t = threadIdx.x;
  int n = swz * 4 + (t >> 6);
  if (n >= NTOT) return;
  int lane = t & 63;
  int es = lane >> 4;
  int dl = lane & 15;
  uint2 qp = *(const uint2*)&Qh[n * 32 + dl * 2];   // dims 4dl..4dl+3, 2x half2
  int s     = __builtin_amdgcn_readfirstlane(row_ptr[n]);
  int e_end = __builtin_amdgcn_readfirstlane(row_ptr[n + 1]);
  int cnt = e_end - s;
  int li = s + lane;
  int cv = (int)epack[li < e_end ? li : s].x;   // dead lanes re-hit lane 0's line
  float den = 0.f;
  float4 acc = make_float4(0.f, 0.f, 0.f, 0.f);
  int base = 0;
  for (; base + 8 <= cnt; base += 8) {       // dual round: 8 gathers in flight
    int i0 = base + es, i1 = i0 + 4;
    int cc0, cc1;
    if (base < 57) {                         // i1 <= base+7 <= 63
      cc0 = __shfl(cv, i0 & 63);
      cc1 = __shfl(cv, i1 & 63);
    } else {
      cc0 = (int)epack[s + i0].x;
      cc1 = (int)epack[s + i1].x;
    }
    uint4 wA = *(const uint4*)&KVb[cc0 * 64 + dl * 4];
    uint4 wB = *(const uint4*)&KVb[cc1 * 64 + dl * 4];
    // round A (edges base..base+3)
    float xA = score4(qp, wA.x, wA.y);
    xA += __shfl_xor(xA, 1);
    xA += __shfl_xor(xA, 2);
    xA = fminf(fmaxf(xA, -10.f), 10.f);
    float exA = __expf(xA);
    den += exA;
    acc.x = fmaf(exA, h_lo(wA.z), acc.x);
    acc.y = fmaf(exA, h_hi(wA.z), acc.y);
    acc.z = fmaf(exA, h_lo(wA.w), acc.z);
    acc.w = fmaf(exA, h_hi(wA.w), acc.w);
    // round B (edges base+4..base+7)
    float xB = score4(qp, wB.x, wB.y);
    xB += __shfl_xor(xB, 1);
    xB += __shfl_xor(xB, 2);
    xB = fminf(fmaxf(xB, -10.f), 10.f);
    float exB = __expf(xB);
    den += exB;
    acc.x = fmaf(exB, h_lo(wB.z), acc.x);
    acc.y = fmaf(exB, h_hi(wB.z), acc.y);
    acc.z = fmaf(exB, h_lo(wB.w), acc.z);
    acc.w = fmaf(exB, h_hi(wB.w), acc.w);
  }
  for (; base + 4 <= cnt; base += 4) {      // single round (at most once)
    int i = base + es;
    int cc;
    if (base < 61) cc = __shfl(cv, i & 63);  // i <= base+3 <= 63
    else           cc = (int)epack[s + i].x;
    uint4 w = *(const uint4*)&KVb[cc * 64 + dl * 4];
    float x = score4(qp, w.x, w.y);
    x += __shfl_xor(x, 1);
    x += __shfl_xor(x, 2);
    x = fminf(fmaxf(x, -10.f), 10.f);
    float ex = __expf(x);
    den += ex;
    acc.x = fmaf(ex, h_lo(w.z), acc.x);
    acc.y = fmaf(ex, h_hi(w.z), acc.y);
    acc.z = fmaf(ex, h_lo(w.w), acc.z);
    acc.w = fmaf(ex, h_hi(w.w), acc.w);
  }
  if (base < cnt) {                          // guarded tail (1-3 live slots)
    int i = base + es;
    int cc;
    if (base < 61) cc = __shfl(cv, i & 63);
    else           cc = (i < cnt) ? (int)epack[s + i].x : 0;
    float ex = 0.f;
    float4 v4 = make_float4(0.f, 0.f, 0.f, 0.f);
    if (i < cnt) {
      uint4 w = *(const uint4*)&KVb[cc * 64 + dl * 4];
      float x = score4(qp, w.x, w.y);
      v4.x = h_lo(w.z); v4.y = h_hi(w.z);
      v4.z = h_lo(w.w); v4.w = h_hi(w.w);
      x += __shfl_xor(x, 1);
      x += __shfl_xor(x, 2);
      x = fminf(fmaxf(x, -10.f), 10.f);
      ex = __expf(x);
    } else {
      float x = 0.f;
      x += __shfl_xor(x, 1);   // keep shuffle pattern wave-uniform
      x += __shfl_xor(x, 2);
    }
    den += ex;
    acc.x = fmaf(ex, v4.x, acc.x);
    acc.y = fmaf(ex, v4.y, acc.y);
    acc.z = fmaf(ex, v4.z, acc.z);
    acc.w = fmaf(ex, v4.w, acc.w);
  }
  #pragma unroll
  for (int off = 16; off <= 32; off <<= 1) {
    den  += __shfl_xor(den, off);
    acc.x += __shfl_xor(acc.x, off);
    acc.y += __shfl_xor(acc.y, off);
    acc.z += __shfl_xor(acc.z, off);
    acc.w += __shfl_xor(acc.w, off);
  }
  float inv = 1.f / (den + 1e-8f);
  if (es == 0) {
    uint2 pk;
    pk.x = pack2bf(acc.x * inv, acc.y * inv);
    pk.y = pack2bf(acc.z * inv, acc.w * inv);
    *(uint2*)&embb_out[n * 32 + dl * 2] = pk;
  }
}

// ---- GCN layer (spmm): wave per node, lane = dim, 8-wide body split into
// unguarded main loop + one guarded tail. bf16 ushort gather (128 B/edge).
// FINAL=0: writes bf16 out only. FINAL=1: fused 5-term final sum. ----
template<int FINAL>
__global__ void __launch_bounds__(256) k_gcn(const bf16u* __restrict__ src,
    const int* __restrict__ row_ptr, const uint2* __restrict__ epack,
    bf16u* __restrict__ embb_out, float* __restrict__ out,
    const float* __restrict__ ue, const float* __restrict__ ie,
    const bf16u* __restrict__ add1, const bf16u* __restrict__ add2) {
  int t = threadIdx.x;
  int n = blockIdx.x * 4 + (t >> 6);
  if (n >= NTOT) return;
  int lane = t & 63;
  int s     = __builtin_amdgcn_readfirstlane(row_ptr[n]);
  int e_end = __builtin_amdgcn_readfirstlane(row_ptr[n + 1]);
  int base = n * 64 + lane;
  // FINAL: issue the coalesced stream loads early; they drain under the gathers.
  float sum_extra = 0.f;
  if (FINAL) {
    float b = (n < NUSERS) ? ue[base] : ie[base - NUSERS * 64];
    float t1 = bf2f(add1[base]);
    float t2 = bf2f(add2[base]);
    float t3 = bf2f(src[base]);     // GCN1's own row (same buffer we gather)
    sum_extra = (b + t1) + (t2 + t3);
  }
  float a[8];
  #pragma unroll
  for (int j = 0; j < 8; ++j) a[j] = 0.f;
  int p = s;
  for (; p + 8 <= e_end; p += 8) {           // unguarded: all 8 slots valid
    #pragma unroll
    for (int j = 0; j < 8; ++j) {
      uint2 ev = epack[p + j];
      a[j] = fmaf(__uint_as_float(ev.y), bf2f(src[(int)ev.x * 64 + lane]), a[j]);
    }
  }
  if (p < e_end) {                           // guarded tail (1-7 live slots)
    #pragma unroll
    for (int j = 0; j < 8; ++j) {
      int pj = p + j;
      int pc = (pj < e_end) ? pj : s;        // clamp: dead slots re-hit edge s (L1)
      uint2 ev = epack[pc];
      float w = (pj < e_end) ? __uint_as_float(ev.y) : 0.f;
      a[j] = fmaf(w, bf2f(src[(int)ev.x * 64 + lane]), a[j]);
    }
  }
  float acc = ((a[0] + a[1]) + (a[2] + a[3])) + ((a[4] + a[5]) + (a[6] + a[7]));
  if (FINAL) {
    out[base] = acc + sum_extra;
  } else {
    embb_out[base] = f2bf(acc);
  }
}

extern "C" void kernel_launch(void* const* d_in, const int* in_sizes, int n_in,
                              void* d_out, int out_size, void* d_ws, size_t ws_size,
                              hipStream_t stream) {
  const int*   rows = (const int*)d_in[0];
  const int*   cols = (const int*)d_in[1];
  const float* vals = (const float*)d_in[2];
  const float* ue   = (const float*)d_in[3];
  const float* ie   = (const float*)d_in[4];
  const float* Wq   = (const float*)d_in[5];
  const float* Wk   = (const float*)d_in[6];
  const float* Wv   = (const float*)d_in[7];
  float* out = (float*)d_out;

  char* p = (char*)d_ws;
  auto alloc = [&](size_t b) { char* r = p; p += (b + 255) & ~(size_t)255; return (void*)r; };
  int*   cnt     = (int*)alloc((size_t)NTOT * 4);
  int*   row_ptr = (int*)alloc((size_t)(NTOT + 1) * 4);
  int*   rank    = (int*)alloc((size_t)NEDGE * 4);
  int*   bsums   = (int*)alloc(128 * 4);
  uint2* epack   = (uint2*)alloc((size_t)NEDGE * 8);     // {col, val bits}
  uint32* Wbg  = (uint32*)alloc((size_t)12288 * 4);
  uint32* Qh   = (uint32*)alloc((size_t)NTOT * 32 * 4);  // fp16 Q (128 B/node)
  uint32* KVb  = (uint32*)alloc((size_t)NTOT * 64 * 4);  // 256 B/node packed K|V fp16
  uint32* B0   = (uint32*)alloc((size_t)NTOT * 32 * 4);  // bf16 rows == ushort[n][64]
  uint32* B1   = (uint32*)alloc((size_t)NTOT * 32 * 4);  // GT1 out
  uint32* B2   = (uint32*)alloc((size_t)NTOT * 32 * 4);  // GT2 out
  uint32* B3   = (uint32*)alloc((size_t)NTOT * 32 * 4);  // GCN1 out

  hipMemsetAsync(cnt, 0, (size_t)NTOT * 4, stream);
  // fused hist(8/thread, FIRST) + wpack + init: 489 + 48 + 9375 blocks
  k_combo<<<9912, 256, 0, stream>>>(ue, ie, B0, Wq, Wk, Wv, Wbg, rows, cnt, rank);
  int nblk = (NTOT + 2047) / 2048;  // 74
  k_scan1<<<nblk, 256, 0, stream>>>(cnt, row_ptr, bsums);
  k_scan3<<<(NTOT + 255) / 256, 256, 0, stream>>>(row_ptr, bsums);  // scan2 folded in
  k_fill<<<(NE4 + 255) / 256, 256, 0, stream>>>(rows, cols, vals, rank, row_ptr, epack);

  // GT layer 1: B0 -> B1 (bf16 only)
  k_qkv<<<(NTILE + 3) / 4, 256, 0, stream>>>(B0, Wbg, Qh, KVb);
  k_gt<<<(NTOT + 3) / 4, 256, 0, stream>>>(Qh, KVb, row_ptr, epack, B1);
  // GT layer 2: B1 -> B2 (bf16 only)
  k_qkv<<<(NTILE + 3) / 4, 256, 0, stream>>>(B1, Wbg + 6144, Qh, KVb);
  k_gt<<<(NTOT + 3) / 4, 256, 0, stream>>>(Qh, KVb, row_ptr, epack, B2);
  // GCN1: gather B2 -> B3 (bf16 only)
  k_gcn<0><<<(NTOT + 3) / 4, 256, 0, stream>>>((const bf16u*)B2, row_ptr, epack,
                                               (bf16u*)B3, nullptr,
                                               nullptr, nullptr, nullptr, nullptr);
  // GCN2 + fused final sum: gather B3; out = cat(ue,ie)+B1+B2+B3+own
  k_gcn<1><<<(NTOT + 3) / 4, 256, 0, stream>>>((const bf16u*)B3, row_ptr, epack,
                                               nullptr, out,
                                               ue, ie, (const bf16u*)B1, (const bf16u*)B2);
}